// Round 1
// baseline (1790.065 us; speedup 1.0000x reference)
//
#include <hip/hip_runtime.h>
#include <hip/hip_bf16.h>
#include <math.h>

// ---------------- problem constants ----------------
#define B_   16
#define S_   1024
#define CIN  1280
#define D_   512
#define H_   8
#define HD_  64
#define NROW (B_ * S_)        // 16384

typedef __bf16 bf16;
typedef float  f32x4  __attribute__((ext_vector_type(4)));
typedef bf16   bf16x4 __attribute__((ext_vector_type(4)));
typedef bf16   bf16x8 __attribute__((ext_vector_type(8)));

// ---------------- f32 -> bf16 convert (vectorized) ----------------
__global__ void cvt_kernel(const float* __restrict__ in, bf16* __restrict__ out, int n4)
{
    int i = blockIdx.x * blockDim.x + threadIdx.x;
    if (i >= n4) return;
    f32x4 v = *(const f32x4*)(in + (size_t)i * 4);
    bf16x4 o;
    o[0] = (bf16)v[0]; o[1] = (bf16)v[1]; o[2] = (bf16)v[2]; o[3] = (bf16)v[3];
    *(bf16x4*)(out + (size_t)i * 4) = o;
}

// ---------------- bf16 MFMA GEMM: C = A[MxK] * W[KxN] + bias (+res,+relu) ----------------
// 128x128 tile, BK=32, 4 waves (2x2), each wave 64x64 = 4x4 frags of 16x16x32.
// LDS layout: both As and Bs stored [dim][k] with k-stride 40 (pad 8) so fragment
// reads are contiguous 16B ds_read_b128.
template<bool RELU, bool RES, bool OUTF, bool OUTB>
__global__ __launch_bounds__(256)
void gemm_kernel(const bf16* __restrict__ A, const bf16* __restrict__ W,
                 const float* __restrict__ bias, const float* __restrict__ res,
                 float* __restrict__ outf, bf16* __restrict__ outb,
                 int M, int N, int K)
{
    __shared__ bf16 As[128 * 40];
    __shared__ bf16 Bs[128 * 40];

    const int m0   = blockIdx.y << 7;
    const int n0   = blockIdx.x << 7;
    const int tid  = threadIdx.x;
    const int lane = tid & 63;
    const int wid  = tid >> 6;
    const int wr   = (wid >> 1) << 6;     // wave row offset (0/64)
    const int wc   = (wid & 1) << 6;      // wave col offset (0/64)
    const int fr   = lane & 15;
    const int fk   = (lane >> 4) << 3;    // k offset 0/8/16/24

    f32x4 acc[4][4] = {};

    for (int k0 = 0; k0 < K; k0 += 32) {
        // stage A tile 128x32 (vec8 bf16 loads, 2 per thread)
        #pragma unroll
        for (int v = 0; v < 2; v++) {
            int idx = tid + (v << 8);            // 0..511
            int row = idx >> 2;
            int seg = (idx & 3) << 3;
            *(bf16x8*)&As[row * 40 + seg] =
                *(const bf16x8*)(A + (size_t)(m0 + row) * K + k0 + seg);
        }
        // stage B tile 32x128, transposed into Bs[n][k]
        #pragma unroll
        for (int v = 0; v < 4; v++) {
            int idx = tid + (v << 8);            // 0..1023
            int kr  = idx >> 5;                  // 0..31
            int nc  = (idx & 31) << 2;           // 0..124
            bf16x4 bv = *(const bf16x4*)(W + (size_t)(k0 + kr) * N + n0 + nc);
            Bs[(nc + 0) * 40 + kr] = bv[0];
            Bs[(nc + 1) * 40 + kr] = bv[1];
            Bs[(nc + 2) * 40 + kr] = bv[2];
            Bs[(nc + 3) * 40 + kr] = bv[3];
        }
        __syncthreads();

        bf16x8 af[4], bfr[4];
        #pragma unroll
        for (int i = 0; i < 4; i++)
            af[i] = *(const bf16x8*)&As[(wr + i * 16 + fr) * 40 + fk];
        #pragma unroll
        for (int j = 0; j < 4; j++)
            bfr[j] = *(const bf16x8*)&Bs[(wc + j * 16 + fr) * 40 + fk];

        #pragma unroll
        for (int i = 0; i < 4; i++)
            #pragma unroll
            for (int j = 0; j < 4; j++)
                acc[i][j] = __builtin_amdgcn_mfma_f32_16x16x32_bf16(af[i], bfr[j], acc[i][j], 0, 0, 0);
        __syncthreads();
    }

    // epilogue: C/D layout col=lane&15, row=(lane>>4)*4+reg (guide-verified)
    const int rq = (lane >> 4) << 2;
    #pragma unroll
    for (int i = 0; i < 4; i++) {
        #pragma unroll
        for (int j = 0; j < 4; j++) {
            const int gn = n0 + wc + j * 16 + fr;
            const float bv = bias[gn];
            #pragma unroll
            for (int r = 0; r < 4; r++) {
                const int gm = m0 + wr + i * 16 + rq + r;
                float v = acc[i][j][r] + bv;
                if (RES)  v += res[(size_t)gm * N + gn];
                if (RELU) v = fmaxf(v, 0.f);
                if (OUTF) outf[(size_t)gm * N + gn] = v;
                if (OUTB) outb[(size_t)gm * N + gn] = (bf16)v;
            }
        }
    }
}

// ---------------- RoPE on q,k inside qkv (in place, bf16) ----------------
__global__ void rope_kernel(bf16* __restrict__ qkv)
{
    int idx = blockIdx.x * blockDim.x + threadIdx.x;   // (row, h, i)
    if (idx >= NROW * H_ * 32) return;
    int i   = idx & 31;
    int h   = (idx >> 5) & 7;
    int row = idx >> 8;
    int s   = row & (S_ - 1);
    float freq = expf(-(float)i * (logf(10000.f) / 32.f));
    float ang  = (float)s * freq;
    float sn, cs;
    sincosf(ang, &sn, &cs);
    size_t base = (size_t)row * (3 * D_);
    {
        bf16* p = qkv + base + h * HD_;            // q
        float x1 = (float)p[i], x2 = (float)p[i + 32];
        p[i]      = (bf16)(x1 * cs - x2 * sn);
        p[i + 32] = (bf16)(x1 * sn + x2 * cs);
    }
    {
        bf16* p = qkv + base + D_ + h * HD_;       // k
        float x1 = (float)p[i], x2 = (float)p[i + 32];
        p[i]      = (bf16)(x1 * cs - x2 * sn);
        p[i + 32] = (bf16)(x1 * sn + x2 * cs);
    }
}

// ---------------- flash attention, f32 VALU (round-0 version) ----------------
// block = 512 thr (8 waves) handles one (b,h) x 64 q-rows; wave owns 8 rows;
// lane owns key `lane` for scores and dim `lane` for the O accumulator.
#define KSTR 68   // f32 stride: 16B-aligned rows, spreads ds_read_b128 banks

__global__ __launch_bounds__(512)
void attn_kernel(const bf16* __restrict__ qkv, bf16* __restrict__ o)
{
    __shared__ float Qs[64 * KSTR];
    __shared__ float Ks[64 * KSTR];
    __shared__ float Vs[64 * KSTR];

    const int bh   = blockIdx.y;
    const int b    = bh >> 3;
    const int h    = bh & 7;
    const int q0   = blockIdx.x << 6;
    const int tid  = threadIdx.x;
    const int lane = tid & 63;
    const int w    = tid >> 6;

    const size_t rs = 3 * D_;
    const bf16* qb = qkv + (size_t)b * S_ * rs + (size_t)h * HD_;
    const bf16* kb = qb + D_;
    const bf16* vb = qb + 2 * D_;

    for (int e = tid; e < 64 * 64; e += 512) {
        int r = e >> 6, d = e & 63;
        Qs[r * KSTR + d] = (float)qb[(size_t)(q0 + r) * rs + d] * 0.125f; // 1/sqrt(64)
    }

    float m[8], lsum[8], oacc[8];
    #pragma unroll
    for (int r = 0; r < 8; r++) { m[r] = -1e30f; lsum[r] = 0.f; oacc[r] = 0.f; }

    for (int c0 = 0; c0 < S_; c0 += 64) {
        __syncthreads();                       // protect Ks/Vs from prev iter readers
        for (int e = tid; e < 64 * 64; e += 512) {
            int r = e >> 6, d = e & 63;
            Ks[r * KSTR + d] = (float)kb[(size_t)(c0 + r) * rs + d];
            Vs[r * KSTR + d] = (float)vb[(size_t)(c0 + r) * rs + d];
        }
        __syncthreads();

        // scores: lane computes key `lane` for its wave's 8 rows
        float s[8];
        #pragma unroll
        for (int r = 0; r < 8; r++) s[r] = 0.f;
        #pragma unroll
        for (int d4 = 0; d4 < 16; d4++) {
            f32x4 k4 = *(const f32x4*)&Ks[lane * KSTR + d4 * 4];
            #pragma unroll
            for (int r = 0; r < 8; r++) {
                f32x4 q4 = *(const f32x4*)&Qs[(w * 8 + r) * KSTR + d4 * 4];
                s[r] += q4[0] * k4[0] + q4[1] * k4[1] + q4[2] * k4[2] + q4[3] * k4[3];
            }
        }

        // online softmax, fully wave-parallel
        float p[8];
        #pragma unroll
        for (int r = 0; r < 8; r++) {
            float mx = s[r];
            #pragma unroll
            for (int off = 32; off; off >>= 1)
                mx = fmaxf(mx, __shfl_xor(mx, off, 64));
            float mn = fmaxf(m[r], mx);
            float sc = __expf(m[r] - mn);
            p[r] = __expf(s[r] - mn);
            float ps = p[r];
            #pragma unroll
            for (int off = 32; off; off >>= 1)
                ps += __shfl_xor(ps, off, 64);
            lsum[r] = lsum[r] * sc + ps;
            oacc[r] *= sc;
            m[r] = mn;
        }

        // PV: lane owns dim `lane`; P broadcast via readlane (keeps LDS pipe free)
        #pragma unroll 4
        for (int k = 0; k < 64; k++) {
            float v = Vs[k * KSTR + lane];
            #pragma unroll
            for (int r = 0; r < 8; r++) {
                float pk = __uint_as_float(
                    __builtin_amdgcn_readlane(__float_as_uint(p[r]), k));
                oacc[r] = fmaf(pk, v, oacc[r]);
            }
        }
    }

    #pragma unroll
    for (int r = 0; r < 8; r++) {
        int row = q0 + w * 8 + r;
        float val = oacc[r] / lsum[r];
        o[((size_t)(b * S_) + row) * D_ + h * HD_ + lane] = (bf16)val;
    }
}

// ---------------- LayerNorm over D=512, one wave per row ----------------
template<bool OUTB>
__global__ __launch_bounds__(256)
void ln_kernel(const float* __restrict__ in, const float* __restrict__ g,
               const float* __restrict__ be, float* __restrict__ outf,
               bf16* __restrict__ outb)
{
    const int row  = (blockIdx.x << 2) + (threadIdx.x >> 6);
    const int lane = threadIdx.x & 63;
    const float* p = in + (size_t)row * D_;
    f32x4 a  = *(const f32x4*)(p + lane * 4);
    f32x4 b2 = *(const f32x4*)(p + 256 + lane * 4);
    float s  = a[0] + a[1] + a[2] + a[3] + b2[0] + b2[1] + b2[2] + b2[3];
    float s2 = a[0]*a[0] + a[1]*a[1] + a[2]*a[2] + a[3]*a[3]
             + b2[0]*b2[0] + b2[1]*b2[1] + b2[2]*b2[2] + b2[3]*b2[3];
    #pragma unroll
    for (int off = 32; off; off >>= 1) {
        s  += __shfl_xor(s,  off, 64);
        s2 += __shfl_xor(s2, off, 64);
    }
    const float mean = s * (1.f / 512.f);
    const float var  = s2 * (1.f / 512.f) - mean * mean;
    const float rstd = rsqrtf(var + 1e-5f);

    f32x4 g0 = *(const f32x4*)(g + lane * 4);
    f32x4 g1 = *(const f32x4*)(g + 256 + lane * 4);
    f32x4 e0 = *(const f32x4*)(be + lane * 4);
    f32x4 e1 = *(const f32x4*)(be + 256 + lane * 4);
    f32x4 o0, o1;
    #pragma unroll
    for (int u = 0; u < 4; u++) {
        o0[u] = (a[u]  - mean) * rstd * g0[u] + e0[u];
        o1[u] = (b2[u] - mean) * rstd * g1[u] + e1[u];
    }
    float* of = outf + (size_t)row * D_;
    *(f32x4*)(of + lane * 4)       = o0;
    *(f32x4*)(of + 256 + lane * 4) = o1;
    if (OUTB) {
        bf16x4 c0, c1;
        #pragma unroll
        for (int u = 0; u < 4; u++) { c0[u] = (bf16)o0[u]; c1[u] = (bf16)o1[u]; }
        bf16* ob = outb + (size_t)row * D_;
        *(bf16x4*)(ob + lane * 4)       = c0;
        *(bf16x4*)(ob + 256 + lane * 4) = c1;
    }
}

// ---------------- host launcher ----------------
extern "C" void kernel_launch(void* const* d_in, const int* in_sizes, int n_in,
                              void* d_out, int out_size, void* d_ws, size_t ws_size,
                              hipStream_t stream)
{
    const float* x      = (const float*)d_in[0];
    const float* w_in   = (const float*)d_in[1];
    const float* b_in   = (const float*)d_in[2];
    const float* w_qkv  = (const float*)d_in[3];
    const float* b_qkv  = (const float*)d_in[4];
    const float* w_out  = (const float*)d_in[5];
    const float* b_out  = (const float*)d_in[6];
    const float* w_ffn1 = (const float*)d_in[7];
    const float* b_ffn1 = (const float*)d_in[8];
    const float* w_ffn2 = (const float*)d_in[9];
    const float* b_ffn2 = (const float*)d_in[10];
    const float* g1     = (const float*)d_in[11];
    const float* bn1    = (const float*)d_in[12];
    const float* g2     = (const float*)d_in[13];
    const float* bn2    = (const float*)d_in[14];

    char* ws = (char*)d_ws;
    // offsets (bytes); all 256B-aligned
    constexpr size_t OFF_XB   = 0;                         // x bf16        41,943,040
    constexpr size_t OFF_WIN  = OFF_XB   + 41943040ull;    // w_in bf16      1,310,720
    constexpr size_t OFF_WQKV = OFF_WIN  + 1310720ull;     // w_qkv bf16     1,572,864
    constexpr size_t OFF_WOUT = OFF_WQKV + 1572864ull;     // w_out bf16       524,288
    constexpr size_t OFF_WF1  = OFF_WOUT + 524288ull;      // w_ffn1 bf16    2,097,152
    constexpr size_t OFF_WF2  = OFF_WF1  + 2097152ull;     // w_ffn2 bf16    2,097,152
    constexpr size_t OFF_HF   = OFF_WF2  + 2097152ull;     // h f32         33,554,432
    constexpr size_t OFF_HB   = OFF_HF   + 33554432ull;    // h bf16        16,777,216
    constexpr size_t OFF_QKV  = OFF_HB   + 16777216ull;    // qkv bf16      50,331,648
    constexpr size_t OFF_OB   = OFF_QKV  + 50331648ull;    // attn o bf16   16,777,216
    constexpr size_t OFF_H2F  = OFF_OB   + 16777216ull;    // h2 f32        33,554,432
    constexpr size_t OFF_H2B  = OFF_H2F  + 33554432ull;    // h2 bf16       16,777,216
    constexpr size_t OFF_F1   = OFF_H2B  + 16777216ull;    // ffn1 bf16     67,108,864
    // aliases (dead-buffer reuse): t1 over x_bf16, t2 over qkv_bf16
    constexpr size_t OFF_T1   = OFF_XB;                    // 33.5MB <= 41.9MB
    constexpr size_t OFF_T2   = OFF_QKV;                   // 33.5MB <= 50.3MB

    bf16*  x_b   = (bf16*)(ws + OFF_XB);
    bf16*  win_b = (bf16*)(ws + OFF_WIN);
    bf16*  wqkv_b= (bf16*)(ws + OFF_WQKV);
    bf16*  wout_b= (bf16*)(ws + OFF_WOUT);
    bf16*  wf1_b = (bf16*)(ws + OFF_WF1);
    bf16*  wf2_b = (bf16*)(ws + OFF_WF2);
    float* h_f   = (float*)(ws + OFF_HF);
    bf16*  h_b   = (bf16*)(ws + OFF_HB);
    bf16*  qkv_b = (bf16*)(ws + OFF_QKV);
    bf16*  o_b   = (bf16*)(ws + OFF_OB);
    float* h2_f  = (float*)(ws + OFF_H2F);
    bf16*  h2_b  = (bf16*)(ws + OFF_H2B);
    bf16*  f1_b  = (bf16*)(ws + OFF_F1);
    float* t1_f  = (float*)(ws + OFF_T1);
    float* t2_f  = (float*)(ws + OFF_T2);

    auto cvt = [&](const float* src, bf16* dst, int n) {
        int n4 = n / 4;
        cvt_kernel<<<(n4 + 255) / 256, 256, 0, stream>>>(src, dst, n4);
    };
    // converts
    cvt(x,      x_b,    NROW * CIN);
    cvt(w_in,   win_b,  CIN * D_);
    cvt(w_qkv,  wqkv_b, D_ * 3 * D_);
    cvt(w_out,  wout_b, D_ * D_);
    cvt(w_ffn1, wf1_b,  D_ * 4 * D_);
    cvt(w_ffn2, wf2_b,  4 * D_ * D_);

    // G1: h = x @ w_in + b_in   -> h_f32, h_bf16
    gemm_kernel<false,false,true,true><<<dim3(D_/128, NROW/128), 256, 0, stream>>>(
        x_b, win_b, b_in, nullptr, h_f, h_b, NROW, D_, CIN);
    // G2: qkv = h @ w_qkv + b_qkv  -> qkv bf16
    gemm_kernel<false,false,false,true><<<dim3(3*D_/128, NROW/128), 256, 0, stream>>>(
        h_b, wqkv_b, b_qkv, nullptr, nullptr, qkv_b, NROW, 3*D_, D_);
    // RoPE in place on q,k
    rope_kernel<<<(NROW * H_ * 32 + 255) / 256, 256, 0, stream>>>(qkv_b);
    // attention -> o bf16
    attn_kernel<<<dim3(S_/64, B_*H_), 512, 0, stream>>>(qkv_b, o_b);
    // G3: t1 = o @ w_out + b_out + h  -> f32
    gemm_kernel<false,true,true,false><<<dim3(D_/128, NROW/128), 256, 0, stream>>>(
        o_b, wout_b, b_out, h_f, t1_f, nullptr, NROW, D_, D_);
    // LN1 -> h2 f32 + bf16
    ln_kernel<true><<<NROW/4, 256, 0, stream>>>(t1_f, g1, bn1, h2_f, h2_b);
    // G4: f1 = relu(h2 @ w_ffn1 + b_ffn1) -> bf16
    gemm_kernel<true,false,false,true><<<dim3(4*D_/128, NROW/128), 256, 0, stream>>>(
        h2_b, wf1_b, b_ffn1, nullptr, nullptr, f1_b, NROW, 4*D_, D_);
    // G5: t2 = f1 @ w_ffn2 + b_ffn2 + h2 -> f32
    gemm_kernel<false,true,true,false><<<dim3(D_/128, NROW/128), 256, 0, stream>>>(
        f1_b, wf2_b, b_ffn2, h2_f, t2_f, nullptr, NROW, D_, 4*D_);
    // LN2 -> d_out (f32)
    ln_kernel<false><<<NROW/4, 256, 0, stream>>>(t2_f, g2, bn2, (float*)d_out, nullptr);

    (void)in_sizes; (void)n_in; (void)out_size; (void)ws_size;
}

// Round 2
// 383.137 us; speedup vs baseline: 4.6721x; 4.6721x over previous
//
#include <hip/hip_runtime.h>
#include <hip/hip_bf16.h>
#include <math.h>

// ---------------- problem constants ----------------
#define B_   16
#define S_   1024
#define CIN  1280
#define D_   512
#define H_   8
#define HD_  64
#define NROW (B_ * S_)        // 16384

typedef __bf16 bf16;
typedef float  f32x4  __attribute__((ext_vector_type(4)));
typedef bf16   bf16x2 __attribute__((ext_vector_type(2)));
typedef bf16   bf16x4 __attribute__((ext_vector_type(4)));
typedef bf16   bf16x8 __attribute__((ext_vector_type(8)));

__device__ __forceinline__ void gload_lds16(const bf16* g, bf16* l) {
    __builtin_amdgcn_global_load_lds(
        (const __attribute__((address_space(1))) void*)g,
        (__attribute__((address_space(3))) void*)l, 16, 0, 0);
}

// ---------------- f32 -> bf16 convert (vectorized) ----------------
__global__ void cvt_kernel(const float* __restrict__ in, bf16* __restrict__ out, int n4)
{
    int i = blockIdx.x * blockDim.x + threadIdx.x;
    if (i >= n4) return;
    f32x4 v = *(const f32x4*)(in + (size_t)i * 4);
    bf16x4 o;
    o[0] = (bf16)v[0]; o[1] = (bf16)v[1]; o[2] = (bf16)v[2]; o[3] = (bf16)v[3];
    *(bf16x4*)(out + (size_t)i * 4) = o;
}

// ---------------- f32 [R][C] -> bf16 transposed [C][R] ----------------
__global__ __launch_bounds__(256)
void tr_cvt_kernel(const float* __restrict__ in, bf16* __restrict__ out, int R, int C)
{
    __shared__ float T[32][33];
    const int r0 = blockIdx.y << 5, c0 = blockIdx.x << 5;
    const int t  = threadIdx.x;
    {
        int lr = t >> 3, lc = (t & 7) << 2;
        f32x4 v = *(const f32x4*)(in + (size_t)(r0 + lr) * C + c0 + lc);
        T[lr][lc] = v[0]; T[lr][lc + 1] = v[1]; T[lr][lc + 2] = v[2]; T[lr][lc + 3] = v[3];
    }
    __syncthreads();
    {
        int oc = t >> 3, orr = (t & 7) << 2;
        bf16x4 o;
        o[0] = (bf16)T[orr][oc];     o[1] = (bf16)T[orr + 1][oc];
        o[2] = (bf16)T[orr + 2][oc]; o[3] = (bf16)T[orr + 3][oc];
        *(bf16x4*)(out + (size_t)(c0 + oc) * R + r0 + orr) = o;
    }
}

// ---------------- bf16 MFMA GEMM (m97 structure): C = A[MxK] * Wt[NxK]^T ----------------
// 128x128 tile, BK=32, 4 waves (2x2), linear LDS + global_load_lds width 16.
template<bool RELU, bool RES, bool OUTF, bool OUTB>
__global__ __launch_bounds__(256)
void gemm_kernel(const bf16* __restrict__ A, const bf16* __restrict__ Wt,
                 const float* __restrict__ bias, const float* __restrict__ res,
                 float* __restrict__ outf, bf16* __restrict__ outb,
                 int M, int N, int K)
{
    __shared__ bf16 As[128 * 32];
    __shared__ bf16 Bs[128 * 32];

    const int m0   = blockIdx.y << 7;
    const int n0   = blockIdx.x << 7;
    const int tid  = threadIdx.x;
    const int lane = tid & 63;
    const int wid  = tid >> 6;
    const int wr   = (wid >> 1) << 6;
    const int wc   = (wid & 1) << 6;
    const int c    = lane & 15;
    const int g    = lane >> 4;
    const int srow = lane >> 2;          // row within a 16-row staging chunk
    const int scol = (lane & 3) << 3;    // k-element offset (16B granules)

    f32x4 acc[4][4] = {};

    for (int k0 = 0; k0 < K; k0 += 32) {
        __syncthreads();                 // prev iter's LDS readers done
        #pragma unroll
        for (int t = 0; t < 2; t++) {
            const int ch  = wid * 2 + t;           // 0..7, wave-uniform
            const int row = ch * 16 + srow;
            gload_lds16(A  + (size_t)(m0 + row) * K + k0 + scol, As + ch * 512);
            gload_lds16(Wt + (size_t)(n0 + row) * K + k0 + scol, Bs + ch * 512);
        }
        __syncthreads();                 // barrier drains vmcnt -> tiles ready

        bf16x8 af[4], bfr[4];
        #pragma unroll
        for (int i = 0; i < 4; i++)
            af[i] = *(const bf16x8*)&As[(wr + i * 16 + c) * 32 + g * 8];
        #pragma unroll
        for (int j = 0; j < 4; j++)
            bfr[j] = *(const bf16x8*)&Bs[(wc + j * 16 + c) * 32 + g * 8];

        #pragma unroll
        for (int i = 0; i < 4; i++)
            #pragma unroll
            for (int j = 0; j < 4; j++)
                acc[i][j] = __builtin_amdgcn_mfma_f32_16x16x32_bf16(af[i], bfr[j], acc[i][j], 0, 0, 0);
    }

    // epilogue: C/D layout col=lane&15, row=(lane>>4)*4+reg (guide-verified)
    const int rq = g << 2;
    #pragma unroll
    for (int i = 0; i < 4; i++) {
        #pragma unroll
        for (int j = 0; j < 4; j++) {
            const int gn = n0 + wc + j * 16 + c;
            const float bv = bias[gn];
            #pragma unroll
            for (int r = 0; r < 4; r++) {
                const int gm = m0 + wr + i * 16 + rq + r;
                float v = acc[i][j][r] + bv;
                if (RES)  v += res[(size_t)gm * N + gn];
                if (RELU) v = fmaxf(v, 0.f);
                if (OUTF) outf[(size_t)gm * N + gn] = v;
                if (OUTB) outb[(size_t)gm * N + gn] = (bf16)v;
            }
        }
    }
    (void)M;
}

// ---------------- RoPE on q,k inside qkv (in place, bf16) ----------------
__global__ void rope_kernel(bf16* __restrict__ qkv)
{
    int idx = blockIdx.x * blockDim.x + threadIdx.x;   // (row, h, i)
    if (idx >= NROW * H_ * 32) return;
    int i   = idx & 31;
    int h   = (idx >> 5) & 7;
    int row = idx >> 8;
    int s   = row & (S_ - 1);
    float freq = expf(-(float)i * (logf(10000.f) / 32.f));
    float ang  = (float)s * freq;
    float sn, cs;
    sincosf(ang, &sn, &cs);
    size_t base = (size_t)row * (3 * D_);
    {
        bf16* p = qkv + base + h * HD_;            // q
        float x1 = (float)p[i], x2 = (float)p[i + 32];
        p[i]      = (bf16)(x1 * cs - x2 * sn);
        p[i + 32] = (bf16)(x1 * sn + x2 * cs);
    }
    {
        bf16* p = qkv + base + D_ + h * HD_;       // k
        float x1 = (float)p[i], x2 = (float)p[i + 32];
        p[i]      = (bf16)(x1 * cs - x2 * sn);
        p[i + 32] = (bf16)(x1 * sn + x2 * cs);
    }
}

// ---------------- MFMA flash attention ----------------
// Block = 256 thr (4 waves), QBLK=64 (16 q-rows/wave), KVBLK=64, 16 kv tiles.
// Swapped QK^T: mfma(A=K,B=Q) -> S^T with q=lane&15, key=(lane>>4)*4+r.
// P repacked to PV A-frag layout via per-wave LDS bounce. V staged transposed.
#define AST 72   // bf16 row stride (144 B = 9*16B, odd 16B multiple -> <=2-way banks)

__global__ __launch_bounds__(256)
void attn_kernel(const bf16* __restrict__ qkv, bf16* __restrict__ o)
{
    __shared__ bf16 Ks[64 * AST];
    __shared__ bf16 Vt[64 * AST];          // [d][key]
    __shared__ bf16 Ps[4][16 * AST];       // per-wave P bounce

    const int bh  = blockIdx.x;
    const int b   = bh >> 3;
    const int h   = bh & 7;
    const int q0  = blockIdx.y << 6;
    const int tid = threadIdx.x;
    const int lane = tid & 63;
    const int w    = tid >> 6;
    const int c    = lane & 15;
    const int g    = lane >> 4;

    const size_t rs = 3 * D_;
    const bf16* qb = qkv + (size_t)b * S_ * rs + h * HD_;
    const bf16* kb = qb + D_;
    const bf16* vb = qb + 2 * D_;

    // Q B-frags in registers: Q[q = q0+w*16+c][d = ch*32 + g*8 + j]
    bf16x8 qf[2];
    {
        const bf16* qrow = qb + (size_t)(q0 + w * 16 + c) * rs + g * 8;
        qf[0] = *(const bf16x8*)(qrow);
        qf[1] = *(const bf16x8*)(qrow + 32);
    }

    f32x4 oa[4] = {};                      // O acc: d-sub j; rows q=4g+r
    float m_r = -3.0e38f, l_r = 0.f;       // softmax state for q=c
    const float CE = 0.18033688011112042f; // (1/8)*log2(e)

    for (int t = 0; t < 16; ++t) {
        __syncthreads();                   // prev tile's readers done
        // stage K[key][d] (2 passes, bf16x8)
        #pragma unroll
        for (int p = 0; p < 2; ++p) {
            int i2  = tid + p * 256;
            int kr  = i2 >> 3, seg = (i2 & 7) << 3;
            *(bf16x8*)&Ks[kr * AST + seg] =
                *(const bf16x8*)(kb + (size_t)(t * 64 + kr) * rs + seg);
        }
        // stage V transposed -> Vt[d][key] (packed bf16x2 writes)
        {
            int key  = (tid & 31) * 2;
            int dblk = (tid >> 5) * 8;
            bf16x8 v0 = *(const bf16x8*)(vb + (size_t)(t * 64 + key)     * rs + dblk);
            bf16x8 v1 = *(const bf16x8*)(vb + (size_t)(t * 64 + key + 1) * rs + dblk);
            #pragma unroll
            for (int i = 0; i < 8; ++i) {
                bf16x2 pr; pr[0] = v0[i]; pr[1] = v1[i];
                *(bf16x2*)&Vt[(dblk + i) * AST + key] = pr;
            }
        }
        __syncthreads();

        // QK^T (swapped): S^T[key][q]
        f32x4 sa[4] = {};
        #pragma unroll
        for (int ch = 0; ch < 2; ++ch)
            #pragma unroll
            for (int ks = 0; ks < 4; ++ks) {
                bf16x8 kf = *(const bf16x8*)&Ks[(ks * 16 + c) * AST + ch * 32 + g * 8];
                sa[ks] = __builtin_amdgcn_mfma_f32_16x16x32_bf16(kf, qf[ch], sa[ks], 0, 0, 0);
            }

        // online softmax (scale 1/8 folded into exp2 arg; max commutes with +scale)
        float pmax = -3.0e38f;
        #pragma unroll
        for (int ks = 0; ks < 4; ++ks)
            pmax = fmaxf(pmax, fmaxf(fmaxf(sa[ks][0], sa[ks][1]), fmaxf(sa[ks][2], sa[ks][3])));
        pmax = fmaxf(pmax, __shfl_xor(pmax, 16, 64));
        pmax = fmaxf(pmax, __shfl_xor(pmax, 32, 64));
        float mnew = fmaxf(m_r, pmax);
        float sc_o = __builtin_amdgcn_exp2f((m_r - mnew) * CE);
        float psum = 0.f;
        #pragma unroll
        for (int ks = 0; ks < 4; ++ks) {
            bf16x4 pb;
            #pragma unroll
            for (int r = 0; r < 4; ++r) {
                float p = __builtin_amdgcn_exp2f((sa[ks][r] - mnew) * CE);
                psum += p;
                pb[r] = (bf16)p;
            }
            *(bf16x4*)&Ps[w][c * AST + ks * 16 + g * 4] = pb;   // keys 16ks+4g+0..3
        }
        psum += __shfl_xor(psum, 16, 64);
        psum += __shfl_xor(psum, 32, 64);
        l_r = l_r * sc_o + psum;
        m_r = mnew;

        // rescale O (lane's O rows are q=4g+r; fetch scale from lane 4g+r)
        #pragma unroll
        for (int r = 0; r < 4; ++r) {
            float sc = __shfl(sc_o, g * 4 + r, 64);
            #pragma unroll
            for (int j = 0; j < 4; ++j) oa[j][r] *= sc;
        }

        // PV: A = P[q][key] from bounce, B = Vt[d][key]
        #pragma unroll
        for (int ch = 0; ch < 2; ++ch) {
            bf16x8 pa = *(const bf16x8*)&Ps[w][c * AST + ch * 32 + g * 8];
            #pragma unroll
            for (int j = 0; j < 4; ++j) {
                bf16x8 vf = *(const bf16x8*)&Vt[(j * 16 + c) * AST + ch * 32 + g * 8];
                oa[j] = __builtin_amdgcn_mfma_f32_16x16x32_bf16(pa, vf, oa[j], 0, 0, 0);
            }
        }
    }

    // epilogue: divide by l (fetch l for q=4g+r), store O
    float linv[4];
    #pragma unroll
    for (int r = 0; r < 4; ++r)
        linv[r] = 1.f / __shfl(l_r, g * 4 + r, 64);
    #pragma unroll
    for (int j = 0; j < 4; ++j)
        #pragma unroll
        for (int r = 0; r < 4; ++r) {
            int q = q0 + w * 16 + g * 4 + r;
            o[((size_t)(b * S_) + q) * D_ + h * HD_ + j * 16 + c] = (bf16)(oa[j][r] * linv[r]);
        }
}

// ---------------- LayerNorm over D=512, one wave per row ----------------
template<bool OUTB>
__global__ __launch_bounds__(256)
void ln_kernel(const float* __restrict__ in, const float* __restrict__ g,
               const float* __restrict__ be, float* __restrict__ outf,
               bf16* __restrict__ outb)
{
    const int row  = (blockIdx.x << 2) + (threadIdx.x >> 6);
    const int lane = threadIdx.x & 63;
    const float* p = in + (size_t)row * D_;
    f32x4 a  = *(const f32x4*)(p + lane * 4);
    f32x4 b2 = *(const f32x4*)(p + 256 + lane * 4);
    float s  = a[0] + a[1] + a[2] + a[3] + b2[0] + b2[1] + b2[2] + b2[3];
    float s2 = a[0]*a[0] + a[1]*a[1] + a[2]*a[2] + a[3]*a[3]
             + b2[0]*b2[0] + b2[1]*b2[1] + b2[2]*b2[2] + b2[3]*b2[3];
    #pragma unroll
    for (int off = 32; off; off >>= 1) {
        s  += __shfl_xor(s,  off, 64);
        s2 += __shfl_xor(s2, off, 64);
    }
    const float mean = s * (1.f / 512.f);
    const float var  = s2 * (1.f / 512.f) - mean * mean;
    const float rstd = rsqrtf(var + 1e-5f);

    f32x4 g0 = *(const f32x4*)(g + lane * 4);
    f32x4 g1 = *(const f32x4*)(g + 256 + lane * 4);
    f32x4 e0 = *(const f32x4*)(be + lane * 4);
    f32x4 e1 = *(const f32x4*)(be + 256 + lane * 4);
    f32x4 o0, o1;
    #pragma unroll
    for (int u = 0; u < 4; u++) {
        o0[u] = (a[u]  - mean) * rstd * g0[u] + e0[u];
        o1[u] = (b2[u] - mean) * rstd * g1[u] + e1[u];
    }
    float* of = outf + (size_t)row * D_;
    *(f32x4*)(of + lane * 4)       = o0;
    *(f32x4*)(of + 256 + lane * 4) = o1;
    if (OUTB) {
        bf16x4 c0, c1;
        #pragma unroll
        for (int u = 0; u < 4; u++) { c0[u] = (bf16)o0[u]; c1[u] = (bf16)o1[u]; }
        bf16* ob = outb + (size_t)row * D_;
        *(bf16x4*)(ob + lane * 4)       = c0;
        *(bf16x4*)(ob + 256 + lane * 4) = c1;
    }
}

// ---------------- host launcher ----------------
extern "C" void kernel_launch(void* const* d_in, const int* in_sizes, int n_in,
                              void* d_out, int out_size, void* d_ws, size_t ws_size,
                              hipStream_t stream)
{
    const float* x      = (const float*)d_in[0];
    const float* w_in   = (const float*)d_in[1];
    const float* b_in   = (const float*)d_in[2];
    const float* w_qkv  = (const float*)d_in[3];
    const float* b_qkv  = (const float*)d_in[4];
    const float* w_out  = (const float*)d_in[5];
    const float* b_out  = (const float*)d_in[6];
    const float* w_ffn1 = (const float*)d_in[7];
    const float* b_ffn1 = (const float*)d_in[8];
    const float* w_ffn2 = (const float*)d_in[9];
    const float* b_ffn2 = (const float*)d_in[10];
    const float* g1     = (const float*)d_in[11];
    const float* bn1    = (const float*)d_in[12];
    const float* g2     = (const float*)d_in[13];
    const float* bn2    = (const float*)d_in[14];

    char* ws = (char*)d_ws;
    constexpr size_t OFF_XB   = 0;                         // x bf16        41,943,040
    constexpr size_t OFF_WIN  = OFF_XB   + 41943040ull;    // w_in^T bf16    1,310,720
    constexpr size_t OFF_WQKV = OFF_WIN  + 1310720ull;     // w_qkv^T bf16   1,572,864
    constexpr size_t OFF_WOUT = OFF_WQKV + 1572864ull;     // w_out^T bf16     524,288
    constexpr size_t OFF_WF1  = OFF_WOUT + 524288ull;      // w_ffn1^T bf16  2,097,152
    constexpr size_t OFF_WF2  = OFF_WF1  + 2097152ull;     // w_ffn2^T bf16  2,097,152
    constexpr size_t OFF_HF   = OFF_WF2  + 2097152ull;     // h f32         33,554,432
    constexpr size_t OFF_HB   = OFF_HF   + 33554432ull;    // h bf16        16,777,216
    constexpr size_t OFF_QKV  = OFF_HB   + 16777216ull;    // qkv bf16      50,331,648
    constexpr size_t OFF_OB   = OFF_QKV  + 50331648ull;    // attn o bf16   16,777,216
    constexpr size_t OFF_H2F  = OFF_OB   + 16777216ull;    // h2 f32        33,554,432
    constexpr size_t OFF_H2B  = OFF_H2F  + 33554432ull;    // h2 bf16       16,777,216
    constexpr size_t OFF_F1   = OFF_H2B  + 16777216ull;    // ffn1 bf16     67,108,864
    constexpr size_t OFF_T1   = OFF_XB;                    // t1 f32 aliases x_b
    constexpr size_t OFF_T2   = OFF_QKV;                   // t2 f32 aliases qkv_b

    bf16*  x_b    = (bf16*)(ws + OFF_XB);
    bf16*  win_t  = (bf16*)(ws + OFF_WIN);
    bf16*  wqkv_t = (bf16*)(ws + OFF_WQKV);
    bf16*  wout_t = (bf16*)(ws + OFF_WOUT);
    bf16*  wf1_t  = (bf16*)(ws + OFF_WF1);
    bf16*  wf2_t  = (bf16*)(ws + OFF_WF2);
    float* h_f    = (float*)(ws + OFF_HF);
    bf16*  h_b    = (bf16*)(ws + OFF_HB);
    bf16*  qkv_b  = (bf16*)(ws + OFF_QKV);
    bf16*  o_b    = (bf16*)(ws + OFF_OB);
    float* h2_f   = (float*)(ws + OFF_H2F);
    bf16*  h2_b   = (bf16*)(ws + OFF_H2B);
    bf16*  f1_b   = (bf16*)(ws + OFF_F1);
    float* t1_f   = (float*)(ws + OFF_T1);
    float* t2_f   = (float*)(ws + OFF_T2);

    // x -> bf16
    {
        int n4 = NROW * CIN / 4;
        cvt_kernel<<<(n4 + 255) / 256, 256, 0, stream>>>(x, x_b, n4);
    }
    // weights -> bf16 transposed [N][K]
    tr_cvt_kernel<<<dim3(512/32, 1280/32), 256, 0, stream>>>(w_in,   win_t,  1280, 512);
    tr_cvt_kernel<<<dim3(1536/32, 512/32), 256, 0, stream>>>(w_qkv,  wqkv_t, 512, 1536);
    tr_cvt_kernel<<<dim3(512/32,  512/32), 256, 0, stream>>>(w_out,  wout_t, 512, 512);
    tr_cvt_kernel<<<dim3(2048/32, 512/32), 256, 0, stream>>>(w_ffn1, wf1_t,  512, 2048);
    tr_cvt_kernel<<<dim3(512/32, 2048/32), 256, 0, stream>>>(w_ffn2, wf2_t,  2048, 512);

    // G1: h = x @ w_in + b_in -> f32 + bf16
    gemm_kernel<false,false,true,true><<<dim3(D_/128, NROW/128), 256, 0, stream>>>(
        x_b, win_t, b_in, nullptr, h_f, h_b, NROW, D_, CIN);
    // G2: qkv = h @ w_qkv + b_qkv -> bf16
    gemm_kernel<false,false,false,true><<<dim3(3*D_/128, NROW/128), 256, 0, stream>>>(
        h_b, wqkv_t, b_qkv, nullptr, nullptr, qkv_b, NROW, 3*D_, D_);
    // RoPE in place on q,k
    rope_kernel<<<(NROW * H_ * 32 + 255) / 256, 256, 0, stream>>>(qkv_b);
    // attention -> o bf16   (grid.x = bh for XCD L2 locality of K/V)
    attn_kernel<<<dim3(B_*H_, S_/64), 256, 0, stream>>>(qkv_b, o_b);
    // G3: t1 = o @ w_out + b_out + h -> f32
    gemm_kernel<false,true,true,false><<<dim3(D_/128, NROW/128), 256, 0, stream>>>(
        o_b, wout_t, b_out, h_f, t1_f, nullptr, NROW, D_, D_);
    // LN1 -> h2 f32 + bf16
    ln_kernel<true><<<NROW/4, 256, 0, stream>>>(t1_f, g1, bn1, h2_f, h2_b);
    // G4: f1 = relu(h2 @ w_ffn1 + b_ffn1) -> bf16
    gemm_kernel<true,false,false,true><<<dim3(4*D_/128, NROW/128), 256, 0, stream>>>(
        h2_b, wf1_t, b_ffn1, nullptr, nullptr, f1_b, NROW, 4*D_, D_);
    // G5: t2 = f1 @ w_ffn2 + b_ffn2 + h2 -> f32
    gemm_kernel<false,true,true,false><<<dim3(D_/128, NROW/128), 256, 0, stream>>>(
        f1_b, wf2_t, b_ffn2, h2_f, t2_f, nullptr, NROW, D_, 4*D_);
    // LN2 -> d_out (f32)
    ln_kernel<false><<<NROW/4, 256, 0, stream>>>(t2_f, g2, bn2, (float*)d_out, nullptr);

    (void)in_sizes; (void)n_in; (void)out_size; (void)ws_size;
}

// Round 3
// 382.204 us; speedup vs baseline: 4.6835x; 1.0024x over previous
//
#include <hip/hip_runtime.h>
#include <hip/hip_bf16.h>
#include <math.h>

// ---------------- problem constants ----------------
#define B_   16
#define S_   1024
#define CIN  1280
#define D_   512
#define H_   8
#define HD_  64
#define NROW (B_ * S_)        // 16384

typedef __bf16 bf16;
typedef float  f32x4  __attribute__((ext_vector_type(4)));
typedef bf16   bf16x2 __attribute__((ext_vector_type(2)));
typedef bf16   bf16x4 __attribute__((ext_vector_type(4)));
typedef bf16   bf16x8 __attribute__((ext_vector_type(8)));

__device__ __forceinline__ void gload_lds16(const bf16* g, bf16* l) {
    __builtin_amdgcn_global_load_lds(
        (const __attribute__((address_space(1))) void*)g,
        (__attribute__((address_space(3))) void*)l, 16, 0, 0);
}

#define SBAR()   __builtin_amdgcn_s_barrier()
#define SCHED0() __builtin_amdgcn_sched_barrier(0)
#define VMCNT8() asm volatile("s_waitcnt vmcnt(8)" ::: "memory")
#define VMCNT0() asm volatile("s_waitcnt vmcnt(0)" ::: "memory")

// ---------------- f32 -> bf16 convert (vectorized) ----------------
__global__ void cvt_kernel(const float* __restrict__ in, bf16* __restrict__ out, int n4)
{
    int i = blockIdx.x * blockDim.x + threadIdx.x;
    if (i >= n4) return;
    f32x4 v = *(const f32x4*)(in + (size_t)i * 4);
    bf16x4 o;
    o[0] = (bf16)v[0]; o[1] = (bf16)v[1]; o[2] = (bf16)v[2]; o[3] = (bf16)v[3];
    *(bf16x4*)(out + (size_t)i * 4) = o;
}

// ---------------- f32 [R][C] -> bf16 transposed [C][R] ----------------
__global__ __launch_bounds__(256)
void tr_cvt_kernel(const float* __restrict__ in, bf16* __restrict__ out, int R, int C)
{
    __shared__ float T[32][33];
    const int r0 = blockIdx.y << 5, c0 = blockIdx.x << 5;
    const int t  = threadIdx.x;
    {
        int lr = t >> 3, lc = (t & 7) << 2;
        f32x4 v = *(const f32x4*)(in + (size_t)(r0 + lr) * C + c0 + lc);
        T[lr][lc] = v[0]; T[lr][lc + 1] = v[1]; T[lr][lc + 2] = v[2]; T[lr][lc + 3] = v[3];
    }
    __syncthreads();
    {
        int oc = t >> 3, orr = (t & 7) << 2;
        bf16x4 o;
        o[0] = (bf16)T[orr][oc];     o[1] = (bf16)T[orr + 1][oc];
        o[2] = (bf16)T[orr + 2][oc]; o[3] = (bf16)T[orr + 3][oc];
        *(bf16x4*)(out + (size_t)(c0 + oc) * R + r0 + orr) = o;
    }
}

// ---------------- 128x128 bf16 MFMA GEMM (m97 structure) ----------------
template<bool RELU, bool RES, bool OUTF, bool OUTB>
__global__ __launch_bounds__(256)
void gemm_kernel(const bf16* __restrict__ A, const bf16* __restrict__ Wt,
                 const float* __restrict__ bias, const float* __restrict__ res,
                 float* __restrict__ outf, bf16* __restrict__ outb,
                 int M, int N, int K)
{
    __shared__ bf16 As[128 * 32];
    __shared__ bf16 Bs[128 * 32];

    const int m0   = blockIdx.y << 7;
    const int n0   = blockIdx.x << 7;
    const int tid  = threadIdx.x;
    const int lane = tid & 63;
    const int wid  = tid >> 6;
    const int wr   = (wid >> 1) << 6;
    const int wc   = (wid & 1) << 6;
    const int c    = lane & 15;
    const int g    = lane >> 4;
    const int srow = lane >> 2;
    const int scol = (lane & 3) << 3;

    f32x4 acc[4][4] = {};

    for (int k0 = 0; k0 < K; k0 += 32) {
        __syncthreads();
        #pragma unroll
        for (int t = 0; t < 2; t++) {
            const int ch  = wid * 2 + t;
            const int row = ch * 16 + srow;
            gload_lds16(A  + (size_t)(m0 + row) * K + k0 + scol, As + ch * 512);
            gload_lds16(Wt + (size_t)(n0 + row) * K + k0 + scol, Bs + ch * 512);
        }
        __syncthreads();

        bf16x8 af[4], bfr[4];
        #pragma unroll
        for (int i = 0; i < 4; i++)
            af[i] = *(const bf16x8*)&As[(wr + i * 16 + c) * 32 + g * 8];
        #pragma unroll
        for (int j = 0; j < 4; j++)
            bfr[j] = *(const bf16x8*)&Bs[(wc + j * 16 + c) * 32 + g * 8];

        #pragma unroll
        for (int i = 0; i < 4; i++)
            #pragma unroll
            for (int j = 0; j < 4; j++)
                acc[i][j] = __builtin_amdgcn_mfma_f32_16x16x32_bf16(af[i], bfr[j], acc[i][j], 0, 0, 0);
    }

    const int rq = g << 2;
    #pragma unroll
    for (int i = 0; i < 4; i++) {
        #pragma unroll
        for (int j = 0; j < 4; j++) {
            const int gn = n0 + wc + j * 16 + c;
            const float bv = bias[gn];
            #pragma unroll
            for (int r = 0; r < 4; r++) {
                const int gm = m0 + wr + i * 16 + rq + r;
                float v = acc[i][j][r] + bv;
                if (RES)  v += res[(size_t)gm * N + gn];
                if (RELU) v = fmaxf(v, 0.f);
                if (OUTF) outf[(size_t)gm * N + gn] = v;
                if (OUTB) outb[(size_t)gm * N + gn] = (bf16)v;
            }
        }
    }
    (void)M;
}

// ---------------- 256x256 BK=64 deep-pipelined GEMM (T2+T3+T4+T5) ----------------
// 8 waves (2M x 4N), per-wave 128x64 out. Double-buffered 128KB LDS.
// Raw s_barrier + counted vmcnt(8): tile t+1 loads stay in flight across
// barriers (never drained to 0 in steady state). st_16x32 swizzle
// (byte ^= ((byte>>9)&1)<<5) applied via pre-swizzled global source
// (gload_lds dest must be linear) + swizzled ds_read addresses.
#define SZ256 (256 * 64)   // elems per 32KB tile panel

template<bool RELU>
__global__ __launch_bounds__(512, 2)
void gemm256_kernel(const bf16* __restrict__ A, const bf16* __restrict__ Wt,
                    const float* __restrict__ bias, bf16* __restrict__ outb,
                    int M, int N, int K)
{
    __shared__ bf16 lds[4 * SZ256];   // [buf][A|B][256][64]  = 128 KiB

    const int tid  = threadIdx.x;
    const int lane = tid & 63;
    const int wid  = tid >> 6;

    // XCD-bijective block decode: xcd = lin&7 owns 8 consecutive m-tiles
    const int mTiles = M >> 8;                 // 64
    const int perX   = mTiles >> 3;            // 8
    const int lin    = blockIdx.x;
    const int idx    = lin >> 3;
    const int my     = (lin & 7) * perX + (idx & (perX - 1));
    const int nx     = idx / perX;
    const int m0     = my << 8, n0 = nx << 8;

    // staging: source pre-swizzle (involution: flip byte-bit5 when bit9 set;
    // for off = chunk*1024 + lane*16, bit9 = lane>>5, bit5 = lane bit1)
    const int swzlane = lane ^ (((lane >> 5) & 1) << 1);
    const int srcRow  = swzlane >> 3;          // + chunk*8
    const int srcK    = (swzlane & 7) << 3;    // element offset in k

    const int r2 = wid >> 2;                   // wave M half (0/1)
    const int c4 = wid & 3;                    // wave N quarter
    const int cc = lane & 15;
    const int g  = (lane >> 4) & 3;

    f32x4 acc[8][4] = {};

    auto stage = [&](int t, int b) {
        const bf16* gA = A  + (size_t)m0 * K + t * 64;
        const bf16* gB = Wt + (size_t)n0 * K + t * 64;
        bf16* lA = lds + b * 2 * SZ256;
        bf16* lB = lA + SZ256;
        #pragma unroll
        for (int v = 0; v < 4; ++v) {
            const int chunk = v * 8 + wid;               // wave-uniform
            const int r = chunk * 8 + srcRow;
            gload_lds16(gA + (size_t)r * K + srcK, lA + chunk * 512);
            gload_lds16(gB + (size_t)r * K + srcK, lB + chunk * 512);
        }
    };

    const int T = K >> 6;
    stage(0, 0);
    stage(1, 1);
    VMCNT8();                 // tile 0 landed (8 of 16 outstanding remain)
    SCHED0();
    SBAR();

    for (int t = 0; t < T; ++t) {
        const int b = t & 1;
        const char* lA = (const char*)(lds + b * 2 * SZ256);
        const char* lB = lA + SZ256 * 2;

        #pragma unroll
        for (int ks = 0; ks < 2; ++ks) {
            bf16x8 af[8], bfr[4];
            #pragma unroll
            for (int i = 0; i < 8; ++i) {
                const int row = r2 * 128 + i * 16 + cc;
                const int cb  = (ks * 64 + g * 16) ^ (((row >> 2) & 1) << 5);
                af[i] = *(const bf16x8*)(lA + row * 128 + cb);
            }
            #pragma unroll
            for (int j = 0; j < 4; ++j) {
                const int row = c4 * 64 + j * 16 + cc;
                const int cb  = (ks * 64 + g * 16) ^ (((row >> 2) & 1) << 5);
                bfr[j] = *(const bf16x8*)(lB + row * 128 + cb);
            }
            __builtin_amdgcn_s_setprio(1);
            #pragma unroll
            for (int i = 0; i < 8; ++i)
                #pragma unroll
                for (int j = 0; j < 4; ++j)
                    acc[i][j] = __builtin_amdgcn_mfma_f32_16x16x32_bf16(af[i], bfr[j], acc[i][j], 0, 0, 0);
            __builtin_amdgcn_s_setprio(0);
        }
        SCHED0();
        SBAR();                          // all waves done reading buf b
        if (t + 2 < T) {
            stage(t + 2, b);             // overwrite now safe; 8 new loads
            VMCNT8();                    // wait tile t+1 only (t+2 stays in flight)
        } else if (t + 1 < T) {
            VMCNT0();                    // drain last tile
        }
        if (t + 1 < T) { SCHED0(); SBAR(); }   // buf[(t+1)&1] ready for all
    }

    const int rq = g << 2;
    #pragma unroll
    for (int i = 0; i < 8; ++i) {
        #pragma unroll
        for (int j = 0; j < 4; ++j) {
            const int gn = n0 + c4 * 64 + j * 16 + cc;
            const float bv = bias[gn];
            #pragma unroll
            for (int r = 0; r < 4; ++r) {
                const int gm = m0 + r2 * 128 + i * 16 + rq + r;
                float v = acc[i][j][r] + bv;
                if (RELU) v = fmaxf(v, 0.f);
                outb[(size_t)gm * N + gn] = (bf16)v;
            }
        }
    }
}

// ---------------- RoPE on q,k inside qkv (in place, bf16) ----------------
__global__ void rope_kernel(bf16* __restrict__ qkv)
{
    int idx = blockIdx.x * blockDim.x + threadIdx.x;   // (row, h, i)
    if (idx >= NROW * H_ * 32) return;
    int i   = idx & 31;
    int h   = (idx >> 5) & 7;
    int row = idx >> 8;
    int s   = row & (S_ - 1);
    float freq = expf(-(float)i * (logf(10000.f) / 32.f));
    float ang  = (float)s * freq;
    float sn, cs;
    sincosf(ang, &sn, &cs);
    size_t base = (size_t)row * (3 * D_);
    {
        bf16* p = qkv + base + h * HD_;            // q
        float x1 = (float)p[i], x2 = (float)p[i + 32];
        p[i]      = (bf16)(x1 * cs - x2 * sn);
        p[i + 32] = (bf16)(x1 * sn + x2 * cs);
    }
    {
        bf16* p = qkv + base + D_ + h * HD_;       // k
        float x1 = (float)p[i], x2 = (float)p[i + 32];
        p[i]      = (bf16)(x1 * cs - x2 * sn);
        p[i + 32] = (bf16)(x1 * sn + x2 * cs);
    }
}

// ---------------- MFMA flash attention (round-2 version, unchanged) ----------------
#define AST 72

__global__ __launch_bounds__(256)
void attn_kernel(const bf16* __restrict__ qkv, bf16* __restrict__ o)
{
    __shared__ bf16 Ks[64 * AST];
    __shared__ bf16 Vt[64 * AST];
    __shared__ bf16 Ps[4][16 * AST];

    const int bh  = blockIdx.x;
    const int b   = bh >> 3;
    const int h   = bh & 7;
    const int q0  = blockIdx.y << 6;
    const int tid = threadIdx.x;
    const int lane = tid & 63;
    const int w    = tid >> 6;
    const int c    = lane & 15;
    const int g    = lane >> 4;

    const size_t rs = 3 * D_;
    const bf16* qb = qkv + (size_t)b * S_ * rs + h * HD_;
    const bf16* kb = qb + D_;
    const bf16* vb = qb + 2 * D_;

    bf16x8 qf[2];
    {
        const bf16* qrow = qb + (size_t)(q0 + w * 16 + c) * rs + g * 8;
        qf[0] = *(const bf16x8*)(qrow);
        qf[1] = *(const bf16x8*)(qrow + 32);
    }

    f32x4 oa[4] = {};
    float m_r = -3.0e38f, l_r = 0.f;
    const float CE = 0.18033688011112042f;

    for (int t = 0; t < 16; ++t) {
        __syncthreads();
        #pragma unroll
        for (int p = 0; p < 2; ++p) {
            int i2  = tid + p * 256;
            int kr  = i2 >> 3, seg = (i2 & 7) << 3;
            *(bf16x8*)&Ks[kr * AST + seg] =
                *(const bf16x8*)(kb + (size_t)(t * 64 + kr) * rs + seg);
        }
        {
            int key  = (tid & 31) * 2;
            int dblk = (tid >> 5) * 8;
            bf16x8 v0 = *(const bf16x8*)(vb + (size_t)(t * 64 + key)     * rs + dblk);
            bf16x8 v1 = *(const bf16x8*)(vb + (size_t)(t * 64 + key + 1) * rs + dblk);
            #pragma unroll
            for (int i = 0; i < 8; ++i) {
                bf16x2 pr; pr[0] = v0[i]; pr[1] = v1[i];
                *(bf16x2*)&Vt[(dblk + i) * AST + key] = pr;
            }
        }
        __syncthreads();

        f32x4 sa[4] = {};
        #pragma unroll
        for (int ch = 0; ch < 2; ++ch)
            #pragma unroll
            for (int ks = 0; ks < 4; ++ks) {
                bf16x8 kf = *(const bf16x8*)&Ks[(ks * 16 + c) * AST + ch * 32 + g * 8];
                sa[ks] = __builtin_amdgcn_mfma_f32_16x16x32_bf16(kf, qf[ch], sa[ks], 0, 0, 0);
            }

        float pmax = -3.0e38f;
        #pragma unroll
        for (int ks = 0; ks < 4; ++ks)
            pmax = fmaxf(pmax, fmaxf(fmaxf(sa[ks][0], sa[ks][1]), fmaxf(sa[ks][2], sa[ks][3])));
        pmax = fmaxf(pmax, __shfl_xor(pmax, 16, 64));
        pmax = fmaxf(pmax, __shfl_xor(pmax, 32, 64));
        float mnew = fmaxf(m_r, pmax);
        float sc_o = __builtin_amdgcn_exp2f((m_r - mnew) * CE);
        float psum = 0.f;
        #pragma unroll
        for (int ks = 0; ks < 4; ++ks) {
            bf16x4 pb;
            #pragma unroll
            for (int r = 0; r < 4; ++r) {
                float p = __builtin_amdgcn_exp2f((sa[ks][r] - mnew) * CE);
                psum += p;
                pb[r] = (bf16)p;
            }
            *(bf16x4*)&Ps[w][c * AST + ks * 16 + g * 4] = pb;
        }
        psum += __shfl_xor(psum, 16, 64);
        psum += __shfl_xor(psum, 32, 64);
        l_r = l_r * sc_o + psum;
        m_r = mnew;

        #pragma unroll
        for (int r = 0; r < 4; ++r) {
            float sc = __shfl(sc_o, g * 4 + r, 64);
            #pragma unroll
            for (int j = 0; j < 4; ++j) oa[j][r] *= sc;
        }

        #pragma unroll
        for (int ch = 0; ch < 2; ++ch) {
            bf16x8 pa = *(const bf16x8*)&Ps[w][c * AST + ch * 32 + g * 8];
            #pragma unroll
            for (int j = 0; j < 4; ++j) {
                bf16x8 vf = *(const bf16x8*)&Vt[(j * 16 + c) * AST + ch * 32 + g * 8];
                oa[j] = __builtin_amdgcn_mfma_f32_16x16x32_bf16(pa, vf, oa[j], 0, 0, 0);
            }
        }
    }

    float linv[4];
    #pragma unroll
    for (int r = 0; r < 4; ++r)
        linv[r] = 1.f / __shfl(l_r, g * 4 + r, 64);
    #pragma unroll
    for (int j = 0; j < 4; ++j)
        #pragma unroll
        for (int r = 0; r < 4; ++r) {
            int q = q0 + w * 16 + g * 4 + r;
            o[((size_t)(b * S_) + q) * D_ + h * HD_ + j * 16 + c] = (bf16)(oa[j][r] * linv[r]);
        }
}

// ---------------- LayerNorm over D=512, one wave per row ----------------
template<bool OUTB>
__global__ __launch_bounds__(256)
void ln_kernel(const float* __restrict__ in, const float* __restrict__ g,
               const float* __restrict__ be, float* __restrict__ outf,
               bf16* __restrict__ outb)
{
    const int row  = (blockIdx.x << 2) + (threadIdx.x >> 6);
    const int lane = threadIdx.x & 63;
    const float* p = in + (size_t)row * D_;
    f32x4 a  = *(const f32x4*)(p + lane * 4);
    f32x4 b2 = *(const f32x4*)(p + 256 + lane * 4);
    float s  = a[0] + a[1] + a[2] + a[3] + b2[0] + b2[1] + b2[2] + b2[3];
    float s2 = a[0]*a[0] + a[1]*a[1] + a[2]*a[2] + a[3]*a[3]
             + b2[0]*b2[0] + b2[1]*b2[1] + b2[2]*b2[2] + b2[3]*b2[3];
    #pragma unroll
    for (int off = 32; off; off >>= 1) {
        s  += __shfl_xor(s,  off, 64);
        s2 += __shfl_xor(s2, off, 64);
    }
    const float mean = s * (1.f / 512.f);
    const float var  = s2 * (1.f / 512.f) - mean * mean;
    const float rstd = rsqrtf(var + 1e-5f);

    f32x4 g0 = *(const f32x4*)(g + lane * 4);
    f32x4 g1 = *(const f32x4*)(g + 256 + lane * 4);
    f32x4 e0 = *(const f32x4*)(be + lane * 4);
    f32x4 e1 = *(const f32x4*)(be + 256 + lane * 4);
    f32x4 o0, o1;
    #pragma unroll
    for (int u = 0; u < 4; u++) {
        o0[u] = (a[u]  - mean) * rstd * g0[u] + e0[u];
        o1[u] = (b2[u] - mean) * rstd * g1[u] + e1[u];
    }
    float* of = outf + (size_t)row * D_;
    *(f32x4*)(of + lane * 4)       = o0;
    *(f32x4*)(of + 256 + lane * 4) = o1;
    if (OUTB) {
        bf16x4 c0, c1;
        #pragma unroll
        for (int u = 0; u < 4; u++) { c0[u] = (bf16)o0[u]; c1[u] = (bf16)o1[u]; }
        bf16* ob = outb + (size_t)row * D_;
        *(bf16x4*)(ob + lane * 4)       = c0;
        *(bf16x4*)(ob + 256 + lane * 4) = c1;
    }
}

// ---------------- host launcher ----------------
extern "C" void kernel_launch(void* const* d_in, const int* in_sizes, int n_in,
                              void* d_out, int out_size, void* d_ws, size_t ws_size,
                              hipStream_t stream)
{
    const float* x      = (const float*)d_in[0];
    const float* w_in   = (const float*)d_in[1];
    const float* b_in   = (const float*)d_in[2];
    const float* w_qkv  = (const float*)d_in[3];
    const float* b_qkv  = (const float*)d_in[4];
    const float* w_out  = (const float*)d_in[5];
    const float* b_out  = (const float*)d_in[6];
    const float* w_ffn1 = (const float*)d_in[7];
    const float* b_ffn1 = (const float*)d_in[8];
    const float* w_ffn2 = (const float*)d_in[9];
    const float* b_ffn2 = (const float*)d_in[10];
    const float* g1     = (const float*)d_in[11];
    const float* bn1    = (const float*)d_in[12];
    const float* g2     = (const float*)d_in[13];
    const float* bn2    = (const float*)d_in[14];

    char* ws = (char*)d_ws;
    constexpr size_t OFF_XB   = 0;
    constexpr size_t OFF_WIN  = OFF_XB   + 41943040ull;
    constexpr size_t OFF_WQKV = OFF_WIN  + 1310720ull;
    constexpr size_t OFF_WOUT = OFF_WQKV + 1572864ull;
    constexpr size_t OFF_WF1  = OFF_WOUT + 524288ull;
    constexpr size_t OFF_WF2  = OFF_WF1  + 2097152ull;
    constexpr size_t OFF_HF   = OFF_WF2  + 2097152ull;
    constexpr size_t OFF_HB   = OFF_HF   + 33554432ull;
    constexpr size_t OFF_QKV  = OFF_HB   + 16777216ull;
    constexpr size_t OFF_OB   = OFF_QKV  + 50331648ull;
    constexpr size_t OFF_H2F  = OFF_OB   + 16777216ull;
    constexpr size_t OFF_H2B  = OFF_H2F  + 33554432ull;
    constexpr size_t OFF_F1   = OFF_H2B  + 16777216ull;
    constexpr size_t OFF_T1   = OFF_XB;
    constexpr size_t OFF_T2   = OFF_QKV;

    bf16*  x_b    = (bf16*)(ws + OFF_XB);
    bf16*  win_t  = (bf16*)(ws + OFF_WIN);
    bf16*  wqkv_t = (bf16*)(ws + OFF_WQKV);
    bf16*  wout_t = (bf16*)(ws + OFF_WOUT);
    bf16*  wf1_t  = (bf16*)(ws + OFF_WF1);
    bf16*  wf2_t  = (bf16*)(ws + OFF_WF2);
    float* h_f    = (float*)(ws + OFF_HF);
    bf16*  h_b    = (bf16*)(ws + OFF_HB);
    bf16*  qkv_b  = (bf16*)(ws + OFF_QKV);
    bf16*  o_b    = (bf16*)(ws + OFF_OB);
    float* h2_f   = (float*)(ws + OFF_H2F);
    bf16*  h2_b   = (bf16*)(ws + OFF_H2B);
    bf16*  f1_b   = (bf16*)(ws + OFF_F1);
    float* t1_f   = (float*)(ws + OFF_T1);
    float* t2_f   = (float*)(ws + OFF_T2);

    {
        int n4 = NROW * CIN / 4;
        cvt_kernel<<<(n4 + 255) / 256, 256, 0, stream>>>(x, x_b, n4);
    }
    tr_cvt_kernel<<<dim3(512/32, 1280/32), 256, 0, stream>>>(w_in,   win_t,  1280, 512);
    tr_cvt_kernel<<<dim3(1536/32, 512/32), 256, 0, stream>>>(w_qkv,  wqkv_t, 512, 1536);
    tr_cvt_kernel<<<dim3(512/32,  512/32), 256, 0, stream>>>(w_out,  wout_t, 512, 512);
    tr_cvt_kernel<<<dim3(2048/32, 512/32), 256, 0, stream>>>(w_ffn1, wf1_t,  512, 2048);
    tr_cvt_kernel<<<dim3(512/32, 2048/32), 256, 0, stream>>>(w_ffn2, wf2_t,  2048, 512);

    // G1: h = x @ w_in + b_in -> f32 + bf16   (128^2 kernel, N=512)
    gemm_kernel<false,false,true,true><<<dim3(D_/128, NROW/128), 256, 0, stream>>>(
        x_b, win_t, b_in, nullptr, h_f, h_b, NROW, D_, CIN);
    // G2: qkv = h @ w_qkv + b_qkv -> bf16   (256^2 pipelined, N=1536)
    gemm256_kernel<false><<<(NROW/256) * (3*D_/256), 512, 0, stream>>>(
        h_b, wqkv_t, b_qkv, qkv_b, NROW, 3*D_, D_);
    // RoPE in place on q,k
    rope_kernel<<<(NROW * H_ * 32 + 255) / 256, 256, 0, stream>>>(qkv_b);
    // attention -> o bf16
    attn_kernel<<<dim3(B_*H_, S_/64), 256, 0, stream>>>(qkv_b, o_b);
    // G3: t1 = o @ w_out + b_out + h -> f32   (128^2, N=512)
    gemm_kernel<false,true,true,false><<<dim3(D_/128, NROW/128), 256, 0, stream>>>(
        o_b, wout_t, b_out, h_f, t1_f, nullptr, NROW, D_, D_);
    // LN1 -> h2 f32 + bf16
    ln_kernel<true><<<NROW/4, 256, 0, stream>>>(t1_f, g1, bn1, h2_f, h2_b);
    // G4: f1 = relu(h2 @ w_ffn1 + b_ffn1) -> bf16   (256^2 pipelined, N=2048)
    gemm256_kernel<true><<<(NROW/256) * (4*D_/256), 512, 0, stream>>>(
        h2_b, wf1_t, b_ffn1, f1_b, NROW, 4*D_, D_);
    // G5: t2 = f1 @ w_ffn2 + b_ffn2 + h2 -> f32   (128^2, N=512, K=2048)
    gemm_kernel<false,true,true,false><<<dim3(D_/128, NROW/128), 256, 0, stream>>>(
        f1_b, wf2_t, b_ffn2, h2_f, t2_f, nullptr, NROW, D_, 4*D_);
    // LN2 -> d_out (f32)
    ln_kernel<false><<<NROW/4, 256, 0, stream>>>(t2_f, g2, bn2, (float*)d_out, nullptr);

    (void)in_sizes; (void)n_in; (void)out_size; (void)ws_size;
}

// Round 4
// 349.347 us; speedup vs baseline: 5.1240x; 1.0941x over previous
//
#include <hip/hip_runtime.h>
#include <hip/hip_bf16.h>
#include <math.h>

// ---------------- problem constants ----------------
#define B_   16
#define S_   1024
#define CIN  1280
#define D_   512
#define H_   8
#define HD_  64
#define NROW (B_ * S_)        // 16384

typedef __bf16 bf16;
typedef float  f32x4  __attribute__((ext_vector_type(4)));
typedef bf16   bf16x2 __attribute__((ext_vector_type(2)));
typedef bf16   bf16x4 __attribute__((ext_vector_type(4)));
typedef bf16   bf16x8 __attribute__((ext_vector_type(8)));

__device__ __forceinline__ void gload_lds16(const bf16* g, bf16* l) {
    __builtin_amdgcn_global_load_lds(
        (const __attribute__((address_space(1))) void*)g,
        (__attribute__((address_space(3))) void*)l, 16, 0, 0);
}

#define SBAR()   __builtin_amdgcn_s_barrier()
#define SCHED0() __builtin_amdgcn_sched_barrier(0)
#define VMCNT8() asm volatile("s_waitcnt vmcnt(8)" ::: "memory")
#define VMCNT6() asm volatile("s_waitcnt vmcnt(6)" ::: "memory")
#define VMCNT4() asm volatile("s_waitcnt vmcnt(4)" ::: "memory")
#define VMCNT0() asm volatile("s_waitcnt vmcnt(0)" ::: "memory")

// ---------------- f32 -> bf16 convert (vectorized) ----------------
__global__ void cvt_kernel(const float* __restrict__ in, bf16* __restrict__ out, int n4)
{
    int i = blockIdx.x * blockDim.x + threadIdx.x;
    if (i >= n4) return;
    f32x4 v = *(const f32x4*)(in + (size_t)i * 4);
    bf16x4 o;
    o[0] = (bf16)v[0]; o[1] = (bf16)v[1]; o[2] = (bf16)v[2]; o[3] = (bf16)v[3];
    *(bf16x4*)(out + (size_t)i * 4) = o;
}

// ---------------- f32 [R][C] -> bf16 transposed [C][R] ----------------
__global__ __launch_bounds__(256)
void tr_cvt_kernel(const float* __restrict__ in, bf16* __restrict__ out, int R, int C)
{
    __shared__ float T[32][33];
    const int r0 = blockIdx.y << 5, c0 = blockIdx.x << 5;
    const int t  = threadIdx.x;
    {
        int lr = t >> 3, lc = (t & 7) << 2;
        f32x4 v = *(const f32x4*)(in + (size_t)(r0 + lr) * C + c0 + lc);
        T[lr][lc] = v[0]; T[lr][lc + 1] = v[1]; T[lr][lc + 2] = v[2]; T[lr][lc + 3] = v[3];
    }
    __syncthreads();
    {
        int oc = t >> 3, orr = (t & 7) << 2;
        bf16x4 o;
        o[0] = (bf16)T[orr][oc];     o[1] = (bf16)T[orr + 1][oc];
        o[2] = (bf16)T[orr + 2][oc]; o[3] = (bf16)T[orr + 3][oc];
        *(bf16x4*)(out + (size_t)(c0 + oc) * R + r0 + orr) = o;
    }
}

// ---------------- 128x128 bf16 MFMA GEMM (m97 structure, used for G3) ----------------
template<bool RELU, bool RES, bool OUTF, bool OUTB>
__global__ __launch_bounds__(256)
void gemm_kernel(const bf16* __restrict__ A, const bf16* __restrict__ Wt,
                 const float* __restrict__ bias, const float* __restrict__ res,
                 float* __restrict__ outf, bf16* __restrict__ outb,
                 int M, int N, int K)
{
    __shared__ bf16 As[128 * 32];
    __shared__ bf16 Bs[128 * 32];

    const int m0   = blockIdx.y << 7;
    const int n0   = blockIdx.x << 7;
    const int tid  = threadIdx.x;
    const int lane = tid & 63;
    const int wid  = tid >> 6;
    const int wr   = (wid >> 1) << 6;
    const int wc   = (wid & 1) << 6;
    const int c    = lane & 15;
    const int g    = lane >> 4;
    const int srow = lane >> 2;
    const int scol = (lane & 3) << 3;

    f32x4 acc[4][4] = {};

    for (int k0 = 0; k0 < K; k0 += 32) {
        __syncthreads();
        #pragma unroll
        for (int t = 0; t < 2; t++) {
            const int ch  = wid * 2 + t;
            const int row = ch * 16 + srow;
            gload_lds16(A  + (size_t)(m0 + row) * K + k0 + scol, As + ch * 512);
            gload_lds16(Wt + (size_t)(n0 + row) * K + k0 + scol, Bs + ch * 512);
        }
        __syncthreads();

        bf16x8 af[4], bfr[4];
        #pragma unroll
        for (int i = 0; i < 4; i++)
            af[i] = *(const bf16x8*)&As[(wr + i * 16 + c) * 32 + g * 8];
        #pragma unroll
        for (int j = 0; j < 4; j++)
            bfr[j] = *(const bf16x8*)&Bs[(wc + j * 16 + c) * 32 + g * 8];

        #pragma unroll
        for (int i = 0; i < 4; i++)
            #pragma unroll
            for (int j = 0; j < 4; j++)
                acc[i][j] = __builtin_amdgcn_mfma_f32_16x16x32_bf16(af[i], bfr[j], acc[i][j], 0, 0, 0);
    }

    const int rq = g << 2;
    #pragma unroll
    for (int i = 0; i < 4; i++) {
        #pragma unroll
        for (int j = 0; j < 4; j++) {
            const int gn = n0 + wc + j * 16 + c;
            const float bv = bias[gn];
            #pragma unroll
            for (int r = 0; r < 4; r++) {
                const int gm = m0 + wr + i * 16 + rq + r;
                float v = acc[i][j][r] + bv;
                if (RES)  v += res[(size_t)gm * N + gn];
                if (RELU) v = fmaxf(v, 0.f);
                if (OUTF) outf[(size_t)gm * N + gn] = v;
                if (OUTB) outb[(size_t)gm * N + gn] = (bf16)v;
            }
        }
    }
    (void)M;
}

// ---------------- 256xBN BK=64 deep-pipelined GEMM (T2-fixed + T3+T4+T5) ----------------
// 8 waves (2M x (BN/64? no: 4N)), per-wave 128 x BN/4 out. Double-buffered LDS.
// Counted vmcnt (never 0 in steady state). T2 swizzle: byte ^= (row&7)<<4,
// applied via pre-swizzled global source (linear gload_lds dest) + swizzled
// ds_read addrs. Read pattern check: 16-lane groups hit each 16B column 2x.
#define ASZ (256 * 64)

template<int BN, bool RELU, bool RES, bool OUTF, bool OUTB>
__global__ __launch_bounds__(512, 2)
void gemm256_kernel(const bf16* __restrict__ A, const bf16* __restrict__ Wt,
                    const float* __restrict__ bias, const float* __restrict__ res,
                    float* __restrict__ outf, bf16* __restrict__ outb,
                    int M, int N, int K)
{
    constexpr int BSZ = BN * 64;
    constexpr int NJ  = BN / 64;           // B-frag blocks per wave (4 or 2)
    constexpr int BCHV = (BN / 8) / 8;     // B stage passes (4 or 2)
    __shared__ bf16 lds[2 * ASZ + 2 * BSZ];

    const int tid  = threadIdx.x;
    const int lane = tid & 63;
    const int wid  = tid >> 6;

    // XCD-bijective decode: xcd = lin&7 owns 8 consecutive m-tiles
    const int mTiles = M >> 8;
    const int perX   = mTiles >> 3;
    const int lin    = blockIdx.x;
    const int idx    = lin >> 3;
    const int my     = (lin & 7) * perX + (idx & (perX - 1));
    const int nx     = idx / perX;
    const int m0     = my << 8, n0 = nx * BN;

    // pre-swizzled source for linear gload_lds dest (involution of the read swz)
    const int sRow = lane >> 3;
    const int sK   = ((lane & 7) ^ (lane >> 3)) << 3;

    const int r2 = wid >> 2;
    const int c4 = wid & 3;
    const int cc = lane & 15;
    const int g  = (lane >> 4) & 3;
    const int swz = (cc & 7) << 4;

    f32x4 acc[8][NJ] = {};

    auto stage = [&](int t, int b) {
        const bf16* gA = A  + (size_t)m0 * K + t * 64;
        const bf16* gB = Wt + (size_t)n0 * K + t * 64;
        bf16* lA = lds + b * ASZ;
        bf16* lB = lds + 2 * ASZ + b * BSZ;
        #pragma unroll
        for (int v = 0; v < 4; ++v) {
            const int ch = v * 8 + wid;          // wave-uniform
            gload_lds16(gA + (size_t)(ch * 8 + sRow) * K + sK, lA + ch * 512);
        }
        #pragma unroll
        for (int v = 0; v < BCHV; ++v) {
            const int ch = v * 8 + wid;
            gload_lds16(gB + (size_t)(ch * 8 + sRow) * K + sK, lB + ch * 512);
        }
    };

    const int T = K >> 6;
    stage(0, 0);
    stage(1, 1);
    if constexpr (BN == 256) VMCNT8(); else VMCNT6();
    SCHED0();
    SBAR();

    for (int t = 0; t < T; ++t) {
        const int b = t & 1;
        const char* lA = (const char*)(lds + b * ASZ);
        const char* lB = (const char*)(lds + 2 * ASZ + b * BSZ);

        #pragma unroll
        for (int ks = 0; ks < 2; ++ks) {
            bf16x8 af[8], bfr[NJ];
            #pragma unroll
            for (int i = 0; i < 8; ++i) {
                const int row = r2 * 128 + i * 16 + cc;
                af[i] = *(const bf16x8*)(lA + row * 128 + ((ks * 64 + g * 16) ^ swz));
            }
            #pragma unroll
            for (int j = 0; j < NJ; ++j) {
                const int row = c4 * (BN / 4) + j * 16 + cc;
                bfr[j] = *(const bf16x8*)(lB + row * 128 + ((ks * 64 + g * 16) ^ swz));
            }
            __builtin_amdgcn_s_setprio(1);
            #pragma unroll
            for (int i = 0; i < 8; ++i)
                #pragma unroll
                for (int j = 0; j < NJ; ++j)
                    acc[i][j] = __builtin_amdgcn_mfma_f32_16x16x32_bf16(af[i], bfr[j], acc[i][j], 0, 0, 0);
            __builtin_amdgcn_s_setprio(0);
        }
        SCHED0();
        SBAR();
        if (t + 2 < T) {
            stage(t + 2, b);
            if constexpr (BN == 256) VMCNT8(); else VMCNT6();
        } else if (t + 1 < T) {
            VMCNT0();
        }
        if (t + 1 < T) { SCHED0(); SBAR(); }
    }

    const int rq = g << 2;
    #pragma unroll
    for (int i = 0; i < 8; ++i) {
        #pragma unroll
        for (int j = 0; j < NJ; ++j) {
            const int gn = n0 + c4 * (BN / 4) + j * 16 + cc;
            const float bv = bias[gn];
            #pragma unroll
            for (int r = 0; r < 4; ++r) {
                const int gm = m0 + r2 * 128 + i * 16 + rq + r;
                float v = acc[i][j][r] + bv;
                if (RES)  v += res[(size_t)gm * N + gn];
                if (RELU) v = fmaxf(v, 0.f);
                if (OUTF) outf[(size_t)gm * N + gn] = v;
                if (OUTB) outb[(size_t)gm * N + gn] = (bf16)v;
            }
        }
    }
}

// ---------------- RoPE on q,k inside qkv (in place, bf16) ----------------
__global__ void rope_kernel(bf16* __restrict__ qkv)
{
    int idx = blockIdx.x * blockDim.x + threadIdx.x;   // (row, h, i)
    if (idx >= NROW * H_ * 32) return;
    int i   = idx & 31;
    int h   = (idx >> 5) & 7;
    int row = idx >> 8;
    int s   = row & (S_ - 1);
    float freq = expf(-(float)i * (logf(10000.f) / 32.f));
    float ang  = (float)s * freq;
    float sn, cs;
    sincosf(ang, &sn, &cs);
    size_t base = (size_t)row * (3 * D_);
    {
        bf16* p = qkv + base + h * HD_;            // q
        float x1 = (float)p[i], x2 = (float)p[i + 32];
        p[i]      = (bf16)(x1 * cs - x2 * sn);
        p[i + 32] = (bf16)(x1 * sn + x2 * cs);
    }
    {
        bf16* p = qkv + base + D_ + h * HD_;       // k
        float x1 = (float)p[i], x2 = (float)p[i + 32];
        p[i]      = (bf16)(x1 * cs - x2 * sn);
        p[i + 32] = (bf16)(x1 * sn + x2 * cs);
    }
}

// ---------------- V transpose: qkv V-part -> vt[bh][d][s] bf16 ----------------
__global__ __launch_bounds__(256)
void vtr_kernel(const bf16* __restrict__ qkv, bf16* __restrict__ vtg)
{
    __shared__ bf16 T[64][72];
    const int bh = blockIdx.y;
    const int b  = bh >> 3, h = bh & 7;
    const int s0 = blockIdx.x << 6;
    const int t  = threadIdx.x;
    const bf16* vb = qkv + (size_t)b * S_ * (3 * D_) + 2 * D_ + h * HD_;
    #pragma unroll
    for (int p = 0; p < 2; ++p) {
        int i2 = t + p * 256;
        int s = i2 >> 3, dseg = (i2 & 7) << 3;
        *(bf16x8*)&T[s][dseg] = *(const bf16x8*)(vb + (size_t)(s0 + s) * (3 * D_) + dseg);
    }
    __syncthreads();
    bf16* out = vtg + (size_t)bh * HD_ * S_ + s0;
    #pragma unroll
    for (int p = 0; p < 2; ++p) {
        int i2 = t + p * 256;
        int d = i2 >> 3, sseg = (i2 & 7) << 3;
        bf16x8 v;
        #pragma unroll
        for (int u = 0; u < 8; ++u) v[u] = T[sseg + u][d];
        *(bf16x8*)(out + (size_t)d * S_ + sseg) = v;
    }
}

// ---------------- MFMA flash attention v2 ----------------
// 4 waves x 16 q-rows, KVBLK=64. K and V^T staged via gload_lds (XOR-swizzled),
// double-buffered, counted vmcnt(4). Swapped QK^T; P via per-wave LDS bounce;
// defer-max (T13): skip O-rescale while pmax-m <= 8 exp2-units (P <= 256).
#define AST 72

__global__ __launch_bounds__(256)
void attn_kernel(const bf16* __restrict__ qkv, const bf16* __restrict__ vtg,
                 bf16* __restrict__ o)
{
    __shared__ bf16 Ks[2][4096];
    __shared__ bf16 Vs[2][4096];
    __shared__ bf16 Ps[4][16 * AST];

    const int bh  = blockIdx.x;
    const int b   = bh >> 3;
    const int h   = bh & 7;
    const int q0  = blockIdx.y << 6;
    const int tid = threadIdx.x;
    const int lane = tid & 63;
    const int w    = tid >> 6;
    const int c    = lane & 15;
    const int g    = lane >> 4;
    const int swz  = (c & 7) << 4;

    const size_t rs = 3 * D_;
    const bf16* qb = qkv + (size_t)b * S_ * rs + h * HD_;
    const bf16* kb = qb + D_;
    const bf16* vt = vtg + (size_t)bh * HD_ * S_;

    const int sRow = lane >> 3;
    const int sK   = ((lane & 7) ^ (lane >> 3)) << 3;

    bf16x8 qf[2];
    {
        const bf16* qrow = qb + (size_t)(q0 + w * 16 + c) * rs + g * 8;
        qf[0] = *(const bf16x8*)(qrow);
        qf[1] = *(const bf16x8*)(qrow + 32);
    }
    SCHED0();   // keep q-loads issued before staging (vmcnt accounting)

    auto stage = [&](int t, int buf) {
        #pragma unroll
        for (int p = 0; p < 2; ++p) {
            const int ch = w * 2 + p;      // wave-uniform
            gload_lds16(kb + (size_t)(t * 64 + ch * 8 + sRow) * rs + sK, &Ks[buf][ch * 512]);
        }
        #pragma unroll
        for (int p = 0; p < 2; ++p) {
            const int ch = w * 2 + p;
            gload_lds16(vt + (size_t)(ch * 8 + sRow) * S_ + t * 64 + sK, &Vs[buf][ch * 512]);
        }
    };

    f32x4 oa[4] = {};
    float m_r = -3.0e38f, l_r = 0.f;
    const float CE = 0.18033688011112042f;   // (1/8)*log2(e)

    stage(0, 0);
    stage(1, 1);
    VMCNT4();        // q(2)+tile0(4) retired; tile1's 4 in flight
    SCHED0();
    SBAR();

    for (int t = 0; t < 16; ++t) {
        const int buf = t & 1;
        const char* kB = (const char*)Ks[buf];
        const char* vB = (const char*)Vs[buf];

        // QK^T (swapped): S^T[key][q]
        f32x4 sa[4] = {};
        #pragma unroll
        for (int ch = 0; ch < 2; ++ch)
            #pragma unroll
            for (int ks = 0; ks < 4; ++ks) {
                bf16x8 kf = *(const bf16x8*)(kB + (ks * 16 + c) * 128 + ((ch * 64 + g * 16) ^ swz));
                sa[ks] = __builtin_amdgcn_mfma_f32_16x16x32_bf16(kf, qf[ch], sa[ks], 0, 0, 0);
            }

        float pmax = -3.0e38f;
        #pragma unroll
        for (int ks = 0; ks < 4; ++ks)
            pmax = fmaxf(pmax, fmaxf(fmaxf(sa[ks][0], sa[ks][1]), fmaxf(sa[ks][2], sa[ks][3])));
        pmax = fmaxf(pmax, __shfl_xor(pmax, 16, 64));
        pmax = fmaxf(pmax, __shfl_xor(pmax, 32, 64));

        // defer-max: rescale only when max grew past threshold (wave-uniform)
        if (!__all((pmax - m_r) * CE <= 8.0f)) {
            float mnew = fmaxf(m_r, pmax);
            float sc = __builtin_amdgcn_exp2f((m_r - mnew) * CE);
            l_r *= sc;
            #pragma unroll
            for (int r = 0; r < 4; ++r) {
                float scr = __shfl(sc, g * 4 + r, 64);
                #pragma unroll
                for (int j = 0; j < 4; ++j) oa[j][r] *= scr;
            }
            m_r = mnew;
        }

        float psum = 0.f;
        #pragma unroll
        for (int ks = 0; ks < 4; ++ks) {
            bf16x4 pb;
            #pragma unroll
            for (int r = 0; r < 4; ++r) {
                float p = __builtin_amdgcn_exp2f((sa[ks][r] - m_r) * CE);
                psum += p;
                pb[r] = (bf16)p;
            }
            *(bf16x4*)&Ps[w][c * AST + ks * 16 + g * 4] = pb;
        }
        psum += __shfl_xor(psum, 16, 64);
        psum += __shfl_xor(psum, 32, 64);
        l_r += psum;

        // PV: A = P[q][key], B = V^T[d][key]
        #pragma unroll
        for (int ch = 0; ch < 2; ++ch) {
            bf16x8 pa = *(const bf16x8*)&Ps[w][c * AST + ch * 32 + g * 8];
            #pragma unroll
            for (int j = 0; j < 4; ++j) {
                bf16x8 vf = *(const bf16x8*)(vB + (j * 16 + c) * 128 + ((ch * 64 + g * 16) ^ swz));
                oa[j] = __builtin_amdgcn_mfma_f32_16x16x32_bf16(pa, vf, oa[j], 0, 0, 0);
            }
        }

        SCHED0();
        SBAR();                              // all waves done reading buf
        if (t + 2 < 16) {
            stage(t + 2, buf);
            VMCNT4();                        // tile t+1 landed; t+2 in flight
        } else if (t + 1 < 16) {
            VMCNT0();
        }
        if (t + 1 < 16) { SCHED0(); SBAR(); }
    }

    float linv[4];
    #pragma unroll
    for (int r = 0; r < 4; ++r)
        linv[r] = 1.f / __shfl(l_r, g * 4 + r, 64);
    #pragma unroll
    for (int j = 0; j < 4; ++j)
        #pragma unroll
        for (int r = 0; r < 4; ++r) {
            int q = q0 + w * 16 + g * 4 + r;
            o[((size_t)(b * S_) + q) * D_ + h * HD_ + j * 16 + c] = (bf16)(oa[j][r] * linv[r]);
        }
}

// ---------------- LayerNorm over D=512, one wave per row ----------------
template<bool OUTB>
__global__ __launch_bounds__(256)
void ln_kernel(const float* __restrict__ in, const float* __restrict__ g,
               const float* __restrict__ be, float* __restrict__ outf,
               bf16* __restrict__ outb)
{
    const int row  = (blockIdx.x << 2) + (threadIdx.x >> 6);
    const int lane = threadIdx.x & 63;
    const float* p = in + (size_t)row * D_;
    f32x4 a  = *(const f32x4*)(p + lane * 4);
    f32x4 b2 = *(const f32x4*)(p + 256 + lane * 4);
    float s  = a[0] + a[1] + a[2] + a[3] + b2[0] + b2[1] + b2[2] + b2[3];
    float s2 = a[0]*a[0] + a[1]*a[1] + a[2]*a[2] + a[3]*a[3]
             + b2[0]*b2[0] + b2[1]*b2[1] + b2[2]*b2[2] + b2[3]*b2[3];
    #pragma unroll
    for (int off = 32; off; off >>= 1) {
        s  += __shfl_xor(s,  off, 64);
        s2 += __shfl_xor(s2, off, 64);
    }
    const float mean = s * (1.f / 512.f);
    const float var  = s2 * (1.f / 512.f) - mean * mean;
    const float rstd = rsqrtf(var + 1e-5f);

    f32x4 g0 = *(const f32x4*)(g + lane * 4);
    f32x4 g1 = *(const f32x4*)(g + 256 + lane * 4);
    f32x4 e0 = *(const f32x4*)(be + lane * 4);
    f32x4 e1 = *(const f32x4*)(be + 256 + lane * 4);
    f32x4 o0, o1;
    #pragma unroll
    for (int u = 0; u < 4; u++) {
        o0[u] = (a[u]  - mean) * rstd * g0[u] + e0[u];
        o1[u] = (b2[u] - mean) * rstd * g1[u] + e1[u];
    }
    float* of = outf + (size_t)row * D_;
    *(f32x4*)(of + lane * 4)       = o0;
    *(f32x4*)(of + 256 + lane * 4) = o1;
    if (OUTB) {
        bf16x4 c0, c1;
        #pragma unroll
        for (int u = 0; u < 4; u++) { c0[u] = (bf16)o0[u]; c1[u] = (bf16)o1[u]; }
        bf16* ob = outb + (size_t)row * D_;
        *(bf16x4*)(ob + lane * 4)       = c0;
        *(bf16x4*)(ob + 256 + lane * 4) = c1;
    }
}

// ---------------- host launcher ----------------
extern "C" void kernel_launch(void* const* d_in, const int* in_sizes, int n_in,
                              void* d_out, int out_size, void* d_ws, size_t ws_size,
                              hipStream_t stream)
{
    const float* x      = (const float*)d_in[0];
    const float* w_in   = (const float*)d_in[1];
    const float* b_in   = (const float*)d_in[2];
    const float* w_qkv  = (const float*)d_in[3];
    const float* b_qkv  = (const float*)d_in[4];
    const float* w_out  = (const float*)d_in[5];
    const float* b_out  = (const float*)d_in[6];
    const float* w_ffn1 = (const float*)d_in[7];
    const float* b_ffn1 = (const float*)d_in[8];
    const float* w_ffn2 = (const float*)d_in[9];
    const float* b_ffn2 = (const float*)d_in[10];
    const float* g1     = (const float*)d_in[11];
    const float* bn1    = (const float*)d_in[12];
    const float* g2     = (const float*)d_in[13];
    const float* bn2    = (const float*)d_in[14];

    char* ws = (char*)d_ws;
    constexpr size_t OFF_XB   = 0;
    constexpr size_t OFF_WIN  = OFF_XB   + 41943040ull;
    constexpr size_t OFF_WQKV = OFF_WIN  + 1310720ull;
    constexpr size_t OFF_WOUT = OFF_WQKV + 1572864ull;
    constexpr size_t OFF_WF1  = OFF_WOUT + 524288ull;
    constexpr size_t OFF_WF2  = OFF_WF1  + 2097152ull;
    constexpr size_t OFF_HF   = OFF_WF2  + 2097152ull;
    constexpr size_t OFF_HB   = OFF_HF   + 33554432ull;   // h bf16; dead after G2 -> reused as vt
    constexpr size_t OFF_QKV  = OFF_HB   + 16777216ull;
    constexpr size_t OFF_OB   = OFF_QKV  + 50331648ull;
    constexpr size_t OFF_H2F  = OFF_OB   + 16777216ull;
    constexpr size_t OFF_H2B  = OFF_H2F  + 33554432ull;
    constexpr size_t OFF_F1   = OFF_H2B  + 16777216ull;
    constexpr size_t OFF_T1   = OFF_XB;                   // t1 f32 aliases x_b (dead after G1)
    constexpr size_t OFF_T2   = OFF_QKV;                  // t2 f32 aliases qkv_b (dead after attn)
    constexpr size_t OFF_VT   = OFF_HB;                   // vt bf16 aliases h_b (dead after G2)

    bf16*  x_b    = (bf16*)(ws + OFF_XB);
    bf16*  win_t  = (bf16*)(ws + OFF_WIN);
    bf16*  wqkv_t = (bf16*)(ws + OFF_WQKV);
    bf16*  wout_t = (bf16*)(ws + OFF_WOUT);
    bf16*  wf1_t  = (bf16*)(ws + OFF_WF1);
    bf16*  wf2_t  = (bf16*)(ws + OFF_WF2);
    float* h_f    = (float*)(ws + OFF_HF);
    bf16*  h_b    = (bf16*)(ws + OFF_HB);
    bf16*  qkv_b  = (bf16*)(ws + OFF_QKV);
    bf16*  o_b    = (bf16*)(ws + OFF_OB);
    float* h2_f   = (float*)(ws + OFF_H2F);
    bf16*  h2_b   = (bf16*)(ws + OFF_H2B);
    bf16*  f1_b   = (bf16*)(ws + OFF_F1);
    float* t1_f   = (float*)(ws + OFF_T1);
    float* t2_f   = (float*)(ws + OFF_T2);
    bf16*  vt_g   = (bf16*)(ws + OFF_VT);

    {
        int n4 = NROW * CIN / 4;
        cvt_kernel<<<(n4 + 255) / 256, 256, 0, stream>>>(x, x_b, n4);
    }
    tr_cvt_kernel<<<dim3(512/32, 1280/32), 256, 0, stream>>>(w_in,   win_t,  1280, 512);
    tr_cvt_kernel<<<dim3(1536/32, 512/32), 256, 0, stream>>>(w_qkv,  wqkv_t, 512, 1536);
    tr_cvt_kernel<<<dim3(512/32,  512/32), 256, 0, stream>>>(w_out,  wout_t, 512, 512);
    tr_cvt_kernel<<<dim3(2048/32, 512/32), 256, 0, stream>>>(w_ffn1, wf1_t,  512, 2048);
    tr_cvt_kernel<<<dim3(512/32, 2048/32), 256, 0, stream>>>(w_ffn2, wf2_t,  2048, 512);

    // G1: h = x @ w_in + b_in -> f32 + bf16   (256x128 pipelined)
    gemm256_kernel<128,false,false,true,true><<<(NROW/256) * (D_/128), 512, 0, stream>>>(
        x_b, win_t, b_in, nullptr, h_f, h_b, NROW, D_, CIN);
    // G2: qkv = h @ w_qkv + b_qkv -> bf16   (256x256 pipelined)
    gemm256_kernel<256,false,false,false,true><<<(NROW/256) * (3*D_/256), 512, 0, stream>>>(
        h_b, wqkv_t, b_qkv, nullptr, nullptr, qkv_b, NROW, 3*D_, D_);
    // RoPE in place on q,k
    rope_kernel<<<(NROW * H_ * 32 + 255) / 256, 256, 0, stream>>>(qkv_b);
    // V transpose (h_b is dead now; vt_g aliases it)
    vtr_kernel<<<dim3(S_/64, B_*H_), 256, 0, stream>>>(qkv_b, vt_g);
    // attention -> o bf16
    attn_kernel<<<dim3(B_*H_, S_/64), 256, 0, stream>>>(qkv_b, vt_g, o_b);
    // G3: t1 = o @ w_out + b_out + h -> f32   (128^2, N=512, K=512)
    gemm_kernel<false,true,true,false><<<dim3(D_/128, NROW/128), 256, 0, stream>>>(
        o_b, wout_t, b_out, h_f, t1_f, nullptr, NROW, D_, D_);
    // LN1 -> h2 f32 + bf16
    ln_kernel<true><<<NROW/4, 256, 0, stream>>>(t1_f, g1, bn1, h2_f, h2_b);
    // G4: f1 = relu(h2 @ w_ffn1 + b_ffn1) -> bf16   (256x256 pipelined)
    gemm256_kernel<256,true,false,false,true><<<(NROW/256) * (4*D_/256), 512, 0, stream>>>(
        h2_b, wf1_t, b_ffn1, nullptr, nullptr, f1_b, NROW, 4*D_, D_);
    // G5: t2 = f1 @ w_ffn2 + b_ffn2 + h2 -> f32   (256x128 pipelined, K=2048)
    gemm256_kernel<128,false,true,true,false><<<(NROW/256) * (D_/128), 512, 0, stream>>>(
        f1_b, wf2_t, b_ffn2, h2_f, t2_f, nullptr, NROW, D_, 4*D_);
    // LN2 -> d_out (f32)
    ln_kernel<false><<<NROW/4, 256, 0, stream>>>(t2_f, g2, bn2, (float*)d_out, nullptr);

    (void)in_sizes; (void)n_in; (void)out_size; (void)ws_size;
}

// Round 5
// 336.803 us; speedup vs baseline: 5.3149x; 1.0372x over previous
//
#include <hip/hip_runtime.h>
#include <hip/hip_bf16.h>
#include <math.h>

// ---------------- problem constants ----------------
#define B_   16
#define S_   1024
#define CIN  1280
#define D_   512
#define H_   8
#define HD_  64
#define NROW (B_ * S_)        // 16384

typedef __bf16 bf16;
typedef float  f32x4  __attribute__((ext_vector_type(4)));
typedef bf16   bf16x2 __attribute__((ext_vector_type(2)));
typedef bf16   bf16x4 __attribute__((ext_vector_type(4)));
typedef bf16   bf16x8 __attribute__((ext_vector_type(8)));

__device__ __forceinline__ void gload_lds16(const bf16* g, bf16* l) {
    __builtin_amdgcn_global_load_lds(
        (const __attribute__((address_space(1))) void*)g,
        (__attribute__((address_space(3))) void*)l, 16, 0, 0);
}

#define SBAR()   __builtin_amdgcn_s_barrier()
#define SCHED0() __builtin_amdgcn_sched_barrier(0)
#define VMCNT8() asm volatile("s_waitcnt vmcnt(8)" ::: "memory")
#define VMCNT6() asm volatile("s_waitcnt vmcnt(6)" ::: "memory")
#define VMCNT2() asm volatile("s_waitcnt vmcnt(2)" ::: "memory")
#define VMCNT0() asm volatile("s_waitcnt vmcnt(0)" ::: "memory")
#define LGKM0()  asm volatile("s_waitcnt lgkmcnt(0)" ::: "memory")

// ---------------- f32 -> bf16 convert (vectorized) ----------------
__global__ void cvt_kernel(const float* __restrict__ in, bf16* __restrict__ out, int n4)
{
    int i = blockIdx.x * blockDim.x + threadIdx.x;
    if (i >= n4) return;
    f32x4 v = *(const f32x4*)(in + (size_t)i * 4);
    bf16x4 o;
    o[0] = (bf16)v[0]; o[1] = (bf16)v[1]; o[2] = (bf16)v[2]; o[3] = (bf16)v[3];
    *(bf16x4*)(out + (size_t)i * 4) = o;
}

// ---------------- f32 [R][C] -> bf16 transposed [C][R] ----------------
__global__ __launch_bounds__(256)
void tr_cvt_kernel(const float* __restrict__ in, bf16* __restrict__ out, int R, int C)
{
    __shared__ float T[32][33];
    const int r0 = blockIdx.y << 5, c0 = blockIdx.x << 5;
    const int t  = threadIdx.x;
    {
        int lr = t >> 3, lc = (t & 7) << 2;
        f32x4 v = *(const f32x4*)(in + (size_t)(r0 + lr) * C + c0 + lc);
        T[lr][lc] = v[0]; T[lr][lc + 1] = v[1]; T[lr][lc + 2] = v[2]; T[lr][lc + 3] = v[3];
    }
    __syncthreads();
    {
        int oc = t >> 3, orr = (t & 7) << 2;
        bf16x4 o;
        o[0] = (bf16)T[orr][oc];     o[1] = (bf16)T[orr + 1][oc];
        o[2] = (bf16)T[orr + 2][oc]; o[3] = (bf16)T[orr + 3][oc];
        *(bf16x4*)(out + (size_t)(c0 + oc) * R + r0 + orr) = o;
    }
}

// ---------------- 128x128 bf16 MFMA GEMM (m97 structure, used for G3) ----------------
template<bool RELU, bool RES, bool OUTF, bool OUTB>
__global__ __launch_bounds__(256)
void gemm_kernel(const bf16* __restrict__ A, const bf16* __restrict__ Wt,
                 const float* __restrict__ bias, const float* __restrict__ res,
                 float* __restrict__ outf, bf16* __restrict__ outb,
                 int M, int N, int K)
{
    __shared__ bf16 As[128 * 32];
    __shared__ bf16 Bs[128 * 32];

    const int m0   = blockIdx.y << 7;
    const int n0   = blockIdx.x << 7;
    const int tid  = threadIdx.x;
    const int lane = tid & 63;
    const int wid  = tid >> 6;
    const int wr   = (wid >> 1) << 6;
    const int wc   = (wid & 1) << 6;
    const int c    = lane & 15;
    const int g    = lane >> 4;
    const int srow = lane >> 2;
    const int scol = (lane & 3) << 3;

    f32x4 acc[4][4] = {};

    for (int k0 = 0; k0 < K; k0 += 32) {
        __syncthreads();
        #pragma unroll
        for (int t = 0; t < 2; t++) {
            const int ch  = wid * 2 + t;
            const int row = ch * 16 + srow;
            gload_lds16(A  + (size_t)(m0 + row) * K + k0 + scol, As + ch * 512);
            gload_lds16(Wt + (size_t)(n0 + row) * K + k0 + scol, Bs + ch * 512);
        }
        __syncthreads();

        bf16x8 af[4], bfr[4];
        #pragma unroll
        for (int i = 0; i < 4; i++)
            af[i] = *(const bf16x8*)&As[(wr + i * 16 + c) * 32 + g * 8];
        #pragma unroll
        for (int j = 0; j < 4; j++)
            bfr[j] = *(const bf16x8*)&Bs[(wc + j * 16 + c) * 32 + g * 8];

        #pragma unroll
        for (int i = 0; i < 4; i++)
            #pragma unroll
            for (int j = 0; j < 4; j++)
                acc[i][j] = __builtin_amdgcn_mfma_f32_16x16x32_bf16(af[i], bfr[j], acc[i][j], 0, 0, 0);
    }

    const int rq = g << 2;
    #pragma unroll
    for (int i = 0; i < 4; i++) {
        #pragma unroll
        for (int j = 0; j < 4; j++) {
            const int gn = n0 + wc + j * 16 + c;
            const float bv = bias[gn];
            #pragma unroll
            for (int r = 0; r < 4; r++) {
                const int gm = m0 + wr + i * 16 + rq + r;
                float v = acc[i][j][r] + bv;
                if (RES)  v += res[(size_t)gm * N + gn];
                if (RELU) v = fmaxf(v, 0.f);
                if (OUTF) outf[(size_t)gm * N + gn] = v;
                if (OUTB) outb[(size_t)gm * N + gn] = (bf16)v;
            }
        }
    }
    (void)M;
}

// ---------------- 256x128 BK=64 pipelined GEMM (round-3 schedule, G1/G5) ----------------
#define ASZ (256 * 64)

template<int BN, bool RELU, bool RES, bool OUTF, bool OUTB>
__global__ __launch_bounds__(512, 2)
void gemm256_kernel(const bf16* __restrict__ A, const bf16* __restrict__ Wt,
                    const float* __restrict__ bias, const float* __restrict__ res,
                    float* __restrict__ outf, bf16* __restrict__ outb,
                    int M, int N, int K)
{
    constexpr int BSZ = BN * 64;
    constexpr int NJ  = BN / 64;
    constexpr int BCHV = (BN / 8) / 8;
    __shared__ bf16 lds[2 * ASZ + 2 * BSZ];

    const int tid  = threadIdx.x;
    const int lane = tid & 63;
    const int wid  = tid >> 6;

    const int mTiles = M >> 8;
    const int perX   = mTiles >> 3;
    const int lin    = blockIdx.x;
    const int idx    = lin >> 3;
    const int my     = (lin & 7) * perX + (idx & (perX - 1));
    const int nx     = idx / perX;
    const int m0     = my << 8, n0 = nx * BN;

    const int sRow = lane >> 3;
    const int sK   = ((lane & 7) ^ (lane >> 3)) << 3;

    const int r2 = wid >> 2;
    const int c4 = wid & 3;
    const int cc = lane & 15;
    const int g  = (lane >> 4) & 3;
    const int swz = (cc & 7) << 4;

    f32x4 acc[8][NJ] = {};

    auto stage = [&](int t, int b) {
        const bf16* gA = A  + (size_t)m0 * K + t * 64;
        const bf16* gB = Wt + (size_t)n0 * K + t * 64;
        bf16* lA = lds + b * ASZ;
        bf16* lB = lds + 2 * ASZ + b * BSZ;
        #pragma unroll
        for (int v = 0; v < 4; ++v) {
            const int ch = v * 8 + wid;
            gload_lds16(gA + (size_t)(ch * 8 + sRow) * K + sK, lA + ch * 512);
        }
        #pragma unroll
        for (int v = 0; v < BCHV; ++v) {
            const int ch = v * 8 + wid;
            gload_lds16(gB + (size_t)(ch * 8 + sRow) * K + sK, lB + ch * 512);
        }
    };

    const int T = K >> 6;
    stage(0, 0);
    stage(1, 1);
    if constexpr (BN == 256) VMCNT8(); else VMCNT6();
    SCHED0();
    SBAR();

    for (int t = 0; t < T; ++t) {
        const int b = t & 1;
        const char* lA = (const char*)(lds + b * ASZ);
        const char* lB = (const char*)(lds + 2 * ASZ + b * BSZ);

        #pragma unroll
        for (int ks = 0; ks < 2; ++ks) {
            bf16x8 af[8], bfr[NJ];
            #pragma unroll
            for (int i = 0; i < 8; ++i) {
                const int row = r2 * 128 + i * 16 + cc;
                af[i] = *(const bf16x8*)(lA + row * 128 + ((ks * 64 + g * 16) ^ swz));
            }
            #pragma unroll
            for (int j = 0; j < NJ; ++j) {
                const int row = c4 * (BN / 4) + j * 16 + cc;
                bfr[j] = *(const bf16x8*)(lB + row * 128 + ((ks * 64 + g * 16) ^ swz));
            }
            __builtin_amdgcn_s_setprio(1);
            #pragma unroll
            for (int i = 0; i < 8; ++i)
                #pragma unroll
                for (int j = 0; j < NJ; ++j)
                    acc[i][j] = __builtin_amdgcn_mfma_f32_16x16x32_bf16(af[i], bfr[j], acc[i][j], 0, 0, 0);
            __builtin_amdgcn_s_setprio(0);
        }
        SCHED0();
        SBAR();
        if (t + 2 < T) {
            stage(t + 2, b);
            if constexpr (BN == 256) VMCNT8(); else VMCNT6();
        } else if (t + 1 < T) {
            VMCNT0();
        }
        if (t + 1 < T) { SCHED0(); SBAR(); }
    }

    const int rq = g << 2;
    #pragma unroll
    for (int i = 0; i < 8; ++i) {
        #pragma unroll
        for (int j = 0; j < NJ; ++j) {
            const int gn = n0 + c4 * (BN / 4) + j * 16 + cc;
            const float bv = bias[gn];
            #pragma unroll
            for (int r = 0; r < 4; ++r) {
                const int gm = m0 + r2 * 128 + i * 16 + rq + r;
                float v = acc[i][j][r] + bv;
                if (RES)  v += res[(size_t)gm * N + gn];
                if (RELU) v = fmaxf(v, 0.f);
                if (OUTF) outf[(size_t)gm * N + gn] = v;
                if (OUTB) outb[(size_t)gm * N + gn] = (bf16)v;
            }
        }
    }
}

// ---------------- 256x256 8-phase GEMM (T2+T3+T4+T5 full stack, G2/G4) ----------------
// 8 waves 2Mx4N, wave out 128x64. LDS: A,B each [2 buf][256][64] = 128 KiB.
// Per K-tile 4 phases; each: {ds_read quad frags | stage 1 half-tile} barrier
// lgkm(0) 16xMFMA barrier. Half-slot ring: a slot is restaged in the phase
// after its last read (Ah0:P1r->P2s, Bh1:P2r->P3s, Ah1:P3r->P4s, Bh0:P4r->
// next P1s). One vmcnt(6)=3 half-tiles in flight per K-tile at P4.
// A-half0 = frag-rows 0-3 of both wave-halves = rows {0-63,128-191};
// B-half0 = frag-cols 0-1 of all quarters = rows {q*64+0..31}.
#define LDA8(I0, BUF) do {                                                         \
    const char* _p = (const char*)ldsA + (BUF) * 32768;                            \
    _Pragma("unroll")                                                              \
    for (int _i = 0; _i < 4; ++_i) {                                               \
        const int _row = r2 * 128 + ((I0) + _i) * 16 + cc;                         \
        _Pragma("unroll")                                                          \
        for (int _k = 0; _k < 2; ++_k)                                             \
            aF[_i][_k] = *(const bf16x8*)(_p + _row * 128 + ((_k * 64 + g16) ^ swz)); \
    }                                                                              \
} while (0)

#define LDB8(J0, BUF) do {                                                         \
    const char* _p = (const char*)ldsB + (BUF) * 32768;                            \
    _Pragma("unroll")                                                              \
    for (int _j = 0; _j < 2; ++_j) {                                               \
        const int _row = c4 * 64 + ((J0) + _j) * 16 + cc;                          \
        _Pragma("unroll")                                                          \
        for (int _k = 0; _k < 2; ++_k)                                             \
            bF[_j][_k] = *(const bf16x8*)(_p + _row * 128 + ((_k * 64 + g16) ^ swz)); \
    }                                                                              \
} while (0)

#define MM8(I0, J0) do {                                                           \
    __builtin_amdgcn_s_setprio(1);                                                 \
    _Pragma("unroll")                                                              \
    for (int _i = 0; _i < 4; ++_i)                                                 \
        _Pragma("unroll")                                                          \
        for (int _j = 0; _j < 2; ++_j)                                             \
            _Pragma("unroll")                                                      \
            for (int _k = 0; _k < 2; ++_k)                                         \
                acc[(I0) + _i][(J0) + _j] = __builtin_amdgcn_mfma_f32_16x16x32_bf16( \
                    aF[_i][_k], bF[_j][_k], acc[(I0) + _i][(J0) + _j], 0, 0, 0);   \
    __builtin_amdgcn_s_setprio(0);                                                 \
} while (0)

template<bool RELU>
__global__ __launch_bounds__(512, 2)
void gemm8p_kernel(const bf16* __restrict__ A, const bf16* __restrict__ Wt,
                   const float* __restrict__ bias, bf16* __restrict__ outb,
                   int M, int N, int K)
{
    __shared__ bf16 ldsA[2 * 256 * 64];
    __shared__ bf16 ldsB[2 * 256 * 64];

    const int tid  = threadIdx.x;
    const int lane = tid & 63;
    const int wid  = tid >> 6;

    const int mTiles = M >> 8;
    const int perX   = mTiles >> 3;
    const int lin    = blockIdx.x;
    const int idx    = lin >> 3;
    const int my     = (lin & 7) * perX + (idx & (perX - 1));
    const int nx     = idx / perX;
    const int m0     = my << 8, n0 = nx << 8;

    const int sRow8 = lane >> 3;
    const int sOff  = ((lane & 7) ^ sRow8) << 3;   // pre-swizzled source k col

    const int r2  = wid >> 2;
    const int c4  = wid & 3;
    const int cc  = lane & 15;
    const int g16 = ((lane >> 4) & 3) << 4;
    const int swz = (cc & 7) << 4;

    f32x4 acc[8][4] = {};
    bf16x8 aF[4][2], bF[2][2];

    const int T = K >> 6;

    auto stA = [&](int t, int half) {   // one A half-tile: 2 gloads/thread
        const bf16* gp = A + (size_t)m0 * K + t * 64;
        bf16* lp = ldsA + (t & 1) * 16384;
        #pragma unroll
        for (int ld = 0; ld < 2; ++ld) {
            const int rb = ld * 128 + half * 64 + wid * 8;
            gload_lds16(gp + (size_t)(rb + sRow8) * K + sOff, lp + rb * 64 + lane * 8);
        }
    };
    auto stB = [&](int t, int half) {   // one B half-tile (32-row quarters)
        const bf16* gp = Wt + (size_t)n0 * K + t * 64;
        bf16* lp = ldsB + (t & 1) * 16384;
        #pragma unroll
        for (int ld = 0; ld < 2; ++ld) {
            const int q  = ld * 2 + (wid >> 2);
            const int rb = q * 64 + half * 32 + (wid & 3) * 8;
            gload_lds16(gp + (size_t)(rb + sRow8) * K + sOff, lp + rb * 64 + lane * 8);
        }
    };

    // prologue: tile0 complete + tile1 {Ah0,Bh1,Ah1}; Bh0[1] staged at t0:P1
    stA(0, 0); stB(0, 1); stA(0, 1); stB(0, 0);
    stA(1, 0); stB(1, 1); stA(1, 1);
    VMCNT6();           // oldest 8 loads (= tile0) landed
    SCHED0();
    SBAR();
    SCHED0();

    for (int t = 0; t < T; ++t) {
        const int b = t & 1;
        // ---- P1: quad (rows0-3, cols0-1)
        LDA8(0, b); LDB8(0, b);
        if (t + 1 < T) stB(t + 1, 0);
        SBAR(); LGKM0(); SCHED0();
        MM8(0, 0);
        SCHED0(); SBAR();
        // ---- P2: quad (rows0-3, cols2-3)
        LDB8(2, b);
        if (t + 2 < T) stA(t + 2, 0);
        SBAR(); LGKM0(); SCHED0();
        MM8(0, 2);
        SCHED0(); SBAR();
        // ---- P3: quad (rows4-7, cols2-3)
        LDA8(4, b);
        if (t + 2 < T) stB(t + 2, 1);
        SBAR(); LGKM0(); SCHED0();
        MM8(4, 2);
        SCHED0(); SBAR();
        // ---- P4: quad (rows4-7, cols0-1)
        LDB8(0, b);
        if (t + 2 < T) stA(t + 2, 1);
        SBAR(); LGKM0(); SCHED0();
        MM8(4, 0);
        SCHED0();
        if (t + 2 < T) { VMCNT6(); } else { VMCNT0(); }
        SBAR();
        SCHED0();
    }

    const int rq = ((lane >> 4) & 3) << 2;
    #pragma unroll
    for (int i = 0; i < 8; ++i) {
        #pragma unroll
        for (int j = 0; j < 4; ++j) {
            const int gn = n0 + c4 * 64 + j * 16 + cc;
            const float bv = bias[gn];
            #pragma unroll
            for (int r = 0; r < 4; ++r) {
                const int gm = m0 + r2 * 128 + i * 16 + rq + r;
                float v = acc[i][j][r] + bv;
                if (RELU) v = fmaxf(v, 0.f);
                outb[(size_t)gm * N + gn] = (bf16)v;
            }
        }
    }
}

// ---------------- RoPE on q,k inside qkv (in place, bf16) ----------------
__global__ void rope_kernel(bf16* __restrict__ qkv)
{
    int idx = blockIdx.x * blockDim.x + threadIdx.x;   // (row, h, i)
    if (idx >= NROW * H_ * 32) return;
    int i   = idx & 31;
    int h   = (idx >> 5) & 7;
    int row = idx >> 8;
    int s   = row & (S_ - 1);
    float freq = expf(-(float)i * (logf(10000.f) / 32.f));
    float ang  = (float)s * freq;
    float sn, cs;
    sincosf(ang, &sn, &cs);
    size_t base = (size_t)row * (3 * D_);
    {
        bf16* p = qkv + base + h * HD_;            // q
        float x1 = (float)p[i], x2 = (float)p[i + 32];
        p[i]      = (bf16)(x1 * cs - x2 * sn);
        p[i + 32] = (bf16)(x1 * sn + x2 * cs);
    }
    {
        bf16* p = qkv + base + D_ + h * HD_;       // k
        float x1 = (float)p[i], x2 = (float)p[i + 32];
        p[i]      = (bf16)(x1 * cs - x2 * sn);
        p[i + 32] = (bf16)(x1 * sn + x2 * cs);
    }
}

// ---------------- V transpose: qkv V-part -> vt[bh][d][s] bf16 ----------------
__global__ __launch_bounds__(256)
void vtr_kernel(const bf16* __restrict__ qkv, bf16* __restrict__ vtg)
{
    __shared__ bf16 T[64][72];
    const int bh = blockIdx.y;
    const int b  = bh >> 3, h = bh & 7;
    const int s0 = blockIdx.x << 6;
    const int t  = threadIdx.x;
    const bf16* vb = qkv + (size_t)b * S_ * (3 * D_) + 2 * D_ + h * HD_;
    #pragma unroll
    for (int p = 0; p < 2; ++p) {
        int i2 = t + p * 256;
        int s = i2 >> 3, dseg = (i2 & 7) << 3;
        *(bf16x8*)&T[s][dseg] = *(const bf16x8*)(vb + (size_t)(s0 + s) * (3 * D_) + dseg);
    }
    __syncthreads();
    bf16* out = vtg + (size_t)bh * HD_ * S_ + s0;
    #pragma unroll
    for (int p = 0; p < 2; ++p) {
        int i2 = t + p * 256;
        int d = i2 >> 3, sseg = (i2 & 7) << 3;
        bf16x8 v;
        #pragma unroll
        for (int u = 0; u < 8; ++u) v[u] = T[sseg + u][d];
        *(bf16x8*)(out + (size_t)d * S_ + sseg) = v;
    }
}

// ---------------- MFMA flash attention v3: 8 waves, QBLK=128 ----------------
// Per wave 16 q-rows; KVBLK=64; K,V^T gload_lds-staged (XOR swizzle), double
// buffered, counted vmcnt(2). LDS ~50KB -> 3 blocks/CU -> 24 waves/CU so
// softmax VALU of some waves overlaps MFMA of others. Defer-max (T13, THR=8).
#define PST 68

__global__ __launch_bounds__(512)
void attn_kernel(const bf16* __restrict__ qkv, const bf16* __restrict__ vtg,
                 bf16* __restrict__ o)
{
    __shared__ bf16 Ks[2][4096];
    __shared__ bf16 Vs[2][4096];
    __shared__ bf16 Ps[8][16 * PST];

    const int bh  = blockIdx.x;
    const int b   = bh >> 3;
    const int h   = bh & 7;
    const int q0  = blockIdx.y << 7;
    const int tid = threadIdx.x;
    const int lane = tid & 63;
    const int w    = tid >> 6;
    const int c    = lane & 15;
    const int g    = lane >> 4;
    const int swz  = (c & 7) << 4;

    const size_t rs = 3 * D_;
    const bf16* qb = qkv + (size_t)b * S_ * rs + h * HD_;
    const bf16* kb = qb + D_;
    const bf16* vt = vtg + (size_t)bh * HD_ * S_;

    const int sRow = tid >> 3;                       // 0..63
    const int sOff = ((tid & 7) ^ (sRow & 7)) << 3;  // pre-swizzled col

    bf16x8 qf[2];
    {
        const bf16* qrow = qb + (size_t)(q0 + w * 16 + c) * rs + g * 8;
        qf[0] = *(const bf16x8*)(qrow);
        qf[1] = *(const bf16x8*)(qrow + 32);
    }
    SCHED0();   // q loads issued before staging (vmcnt ordering)

    auto stage = [&](int t, int buf) {
        gload_lds16(kb + (size_t)(t * 64 + sRow) * rs + sOff, &Ks[buf][0] + (size_t)tid * 8);
        gload_lds16(vt + (size_t)sRow * S_ + t * 64 + sOff,   &Vs[buf][0] + (size_t)tid * 8);
    };

    f32x4 oa[4] = {};
    float m_r = -3.0e38f, l_r = 0.f;
    const float CE = 0.18033688011112042f;   // (1/8)*log2(e)

    stage(0, 0);
    stage(1, 1);
    VMCNT2();        // q + tile0 landed; tile1's 2 in flight
    SCHED0();
    SBAR();

    for (int t = 0; t < 16; ++t) {
        const int buf = t & 1;
        const char* kB = (const char*)Ks[buf];
        const char* vB = (const char*)Vs[buf];

        // QK^T (swapped): S^T[key][q]
        f32x4 sa[4] = {};
        __builtin_amdgcn_s_setprio(1);
        #pragma unroll
        for (int ch = 0; ch < 2; ++ch)
            #pragma unroll
            for (int ks = 0; ks < 4; ++ks) {
                bf16x8 kf = *(const bf16x8*)(kB + (ks * 16 + c) * 128 + ((ch * 64 + g * 16) ^ swz));
                sa[ks] = __builtin_amdgcn_mfma_f32_16x16x32_bf16(kf, qf[ch], sa[ks], 0, 0, 0);
            }
        __builtin_amdgcn_s_setprio(0);

        float pmax = -3.0e38f;
        #pragma unroll
        for (int ks = 0; ks < 4; ++ks)
            pmax = fmaxf(pmax, fmaxf(fmaxf(sa[ks][0], sa[ks][1]), fmaxf(sa[ks][2], sa[ks][3])));
        pmax = fmaxf(pmax, __shfl_xor(pmax, 16, 64));
        pmax = fmaxf(pmax, __shfl_xor(pmax, 32, 64));

        // defer-max: rescale only when max grew past threshold (wave-uniform)
        if (!__all((pmax - m_r) * CE <= 8.0f)) {
            float mnew = fmaxf(m_r, pmax);
            float sc = __builtin_amdgcn_exp2f((m_r - mnew) * CE);
            l_r *= sc;
            #pragma unroll
            for (int r = 0; r < 4; ++r) {
                float scr = __shfl(sc, g * 4 + r, 64);
                #pragma unroll
                for (int j = 0; j < 4; ++j) oa[j][r] *= scr;
            }
            m_r = mnew;
        }

        float psum = 0.f;
        #pragma unroll
        for (int ks = 0; ks < 4; ++ks) {
            bf16x4 pb;
            #pragma unroll
            for (int r = 0; r < 4; ++r) {
                float p = __builtin_amdgcn_exp2f((sa[ks][r] - m_r) * CE);
                psum += p;
                pb[r] = (bf16)p;
            }
            *(bf16x4*)&Ps[w][c * PST + ks * 16 + g * 4] = pb;
        }
        psum += __shfl_xor(psum, 16, 64);
        psum += __shfl_xor(psum, 32, 64);
        l_r += psum;

        // PV: A = P[q][key], B = V^T[d][key]
        __builtin_amdgcn_s_setprio(1);
        #pragma unroll
        for (int ch = 0; ch < 2; ++ch) {
            bf16x8 pa = *(const bf16x8*)&Ps[w][c * PST + ch * 32 + g * 8];
            #pragma unroll
            for (int j = 0; j < 4; ++j) {
                bf16x8 vf = *(const bf16x8*)(vB + (j * 16 + c) * 128 + ((ch * 64 + g * 16) ^ swz));
                oa[j] = __builtin_amdgcn_mfma_f32_16x16x32_bf16(pa, vf, oa[j], 0, 0, 0);
            }
        }
        __builtin_amdgcn_s_setprio(0);

        SCHED0();
        SBAR();                              // all waves done reading buf
        if (t + 2 < 16) {
            stage(t + 2, buf);
            VMCNT2();                        // tile t+1 landed; t+2 in flight
        } else if (t + 1 < 16) {
            VMCNT0();
        }
        if (t + 1 < 16) { SCHED0(); SBAR(); }
    }

    float linv[4];
    #pragma unroll
    for (int r = 0; r < 4; ++r)
        linv[r] = 1.f / __shfl(l_r, g * 4 + r, 64);
    #pragma unroll
    for (int j = 0; j < 4; ++j)
        #pragma unroll
        for (int r = 0; r < 4; ++r) {
            int q = q0 + w * 16 + g * 4 + r;
            o[((size_t)(b * S_) + q) * D_ + h * HD_ + j * 16 + c] = (bf16)(oa[j][r] * linv[r]);
        }
}

// ---------------- LayerNorm over D=512, one wave per row ----------------
template<bool OUTB>
__global__ __launch_bounds__(256)
void ln_kernel(const float* __restrict__ in, const float* __restrict__ g,
               const float* __restrict__ be, float* __restrict__ outf,
               bf16* __restrict__ outb)
{
    const int row  = (blockIdx.x << 2) + (threadIdx.x >> 6);
    const int lane = threadIdx.x & 63;
    const float* p = in + (size_t)row * D_;
    f32x4 a  = *(const f32x4*)(p + lane * 4);
    f32x4 b2 = *(const f32x4*)(p + 256 + lane * 4);
    float s  = a[0] + a[1] + a[2] + a[3] + b2[0] + b2[1] + b2[2] + b2[3];
    float s2 = a[0]*a[0] + a[1]*a[1] + a[2]*a[2] + a[3]*a[3]
             + b2[0]*b2[0] + b2[1]*b2[1] + b2[2]*b2[2] + b2[3]*b2[3];
    #pragma unroll
    for (int off = 32; off; off >>= 1) {
        s  += __shfl_xor(s,  off, 64);
        s2 += __shfl_xor(s2, off, 64);
    }
    const float mean = s * (1.f / 512.f);
    const float var  = s2 * (1.f / 512.f) - mean * mean;
    const float rstd = rsqrtf(var + 1e-5f);

    f32x4 g0 = *(const f32x4*)(g + lane * 4);
    f32x4 g1 = *(const f32x4*)(g + 256 + lane * 4);
    f32x4 e0 = *(const f32x4*)(be + lane * 4);
    f32x4 e1 = *(const f32x4*)(be + 256 + lane * 4);
    f32x4 o0, o1;
    #pragma unroll
    for (int u = 0; u < 4; u++) {
        o0[u] = (a[u]  - mean) * rstd * g0[u] + e0[u];
        o1[u] = (b2[u] - mean) * rstd * g1[u] + e1[u];
    }
    float* of = outf + (size_t)row * D_;
    *(f32x4*)(of + lane * 4)       = o0;
    *(f32x4*)(of + 256 + lane * 4) = o1;
    if (OUTB) {
        bf16x4 c0, c1;
        #pragma unroll
        for (int u = 0; u < 4; u++) { c0[u] = (bf16)o0[u]; c1[u] = (bf16)o1[u]; }
        bf16* ob = outb + (size_t)row * D_;
        *(bf16x4*)(ob + lane * 4)       = c0;
        *(bf16x4*)(ob + 256 + lane * 4) = c1;
    }
}

// ---------------- host launcher ----------------
extern "C" void kernel_launch(void* const* d_in, const int* in_sizes, int n_in,
                              void* d_out, int out_size, void* d_ws, size_t ws_size,
                              hipStream_t stream)
{
    const float* x      = (const float*)d_in[0];
    const float* w_in   = (const float*)d_in[1];
    const float* b_in   = (const float*)d_in[2];
    const float* w_qkv  = (const float*)d_in[3];
    const float* b_qkv  = (const float*)d_in[4];
    const float* w_out  = (const float*)d_in[5];
    const float* b_out  = (const float*)d_in[6];
    const float* w_ffn1 = (const float*)d_in[7];
    const float* b_ffn1 = (const float*)d_in[8];
    const float* w_ffn2 = (const float*)d_in[9];
    const float* b_ffn2 = (const float*)d_in[10];
    const float* g1     = (const float*)d_in[11];
    const float* bn1    = (const float*)d_in[12];
    const float* g2     = (const float*)d_in[13];
    const float* bn2    = (const float*)d_in[14];

    char* ws = (char*)d_ws;
    constexpr size_t OFF_XB   = 0;
    constexpr size_t OFF_WIN  = OFF_XB   + 41943040ull;
    constexpr size_t OFF_WQKV = OFF_WIN  + 1310720ull;
    constexpr size_t OFF_WOUT = OFF_WQKV + 1572864ull;
    constexpr size_t OFF_WF1  = OFF_WOUT + 524288ull;
    constexpr size_t OFF_WF2  = OFF_WF1  + 2097152ull;
    constexpr size_t OFF_HF   = OFF_WF2  + 2097152ull;
    constexpr size_t OFF_HB   = OFF_HF   + 33554432ull;   // h bf16; dead after G2 -> vt
    constexpr size_t OFF_QKV  = OFF_HB   + 16777216ull;
    constexpr size_t OFF_OB   = OFF_QKV  + 50331648ull;
    constexpr size_t OFF_H2F  = OFF_OB   + 16777216ull;
    constexpr size_t OFF_H2B  = OFF_H2F  + 33554432ull;
    constexpr size_t OFF_F1   = OFF_H2B  + 16777216ull;
    constexpr size_t OFF_T1   = OFF_XB;
    constexpr size_t OFF_T2   = OFF_QKV;
    constexpr size_t OFF_VT   = OFF_HB;

    bf16*  x_b    = (bf16*)(ws + OFF_XB);
    bf16*  win_t  = (bf16*)(ws + OFF_WIN);
    bf16*  wqkv_t = (bf16*)(ws + OFF_WQKV);
    bf16*  wout_t = (bf16*)(ws + OFF_WOUT);
    bf16*  wf1_t  = (bf16*)(ws + OFF_WF1);
    bf16*  wf2_t  = (bf16*)(ws + OFF_WF2);
    float* h_f    = (float*)(ws + OFF_HF);
    bf16*  h_b    = (bf16*)(ws + OFF_HB);
    bf16*  qkv_b  = (bf16*)(ws + OFF_QKV);
    bf16*  o_b    = (bf16*)(ws + OFF_OB);
    float* h2_f   = (float*)(ws + OFF_H2F);
    bf16*  h2_b   = (bf16*)(ws + OFF_H2B);
    bf16*  f1_b   = (bf16*)(ws + OFF_F1);
    float* t1_f   = (float*)(ws + OFF_T1);
    float* t2_f   = (float*)(ws + OFF_T2);
    bf16*  vt_g   = (bf16*)(ws + OFF_VT);

    {
        int n4 = NROW * CIN / 4;
        cvt_kernel<<<(n4 + 255) / 256, 256, 0, stream>>>(x, x_b, n4);
    }
    tr_cvt_kernel<<<dim3(512/32, 1280/32), 256, 0, stream>>>(w_in,   win_t,  1280, 512);
    tr_cvt_kernel<<<dim3(1536/32, 512/32), 256, 0, stream>>>(w_qkv,  wqkv_t, 512, 1536);
    tr_cvt_kernel<<<dim3(512/32,  512/32), 256, 0, stream>>>(w_out,  wout_t, 512, 512);
    tr_cvt_kernel<<<dim3(2048/32, 512/32), 256, 0, stream>>>(w_ffn1, wf1_t,  512, 2048);
    tr_cvt_kernel<<<dim3(512/32, 2048/32), 256, 0, stream>>>(w_ffn2, wf2_t,  2048, 512);

    // G1: h = x @ w_in + b_in -> f32 + bf16   (256x128 pipelined)
    gemm256_kernel<128,false,false,true,true><<<(NROW/256) * (D_/128), 512, 0, stream>>>(
        x_b, win_t, b_in, nullptr, h_f, h_b, NROW, D_, CIN);
    // G2: qkv = h @ w_qkv + b_qkv -> bf16   (8-phase 256^2)
    gemm8p_kernel<false><<<(NROW/256) * (3*D_/256), 512, 0, stream>>>(
        h_b, wqkv_t, b_qkv, qkv_b, NROW, 3*D_, D_);
    // RoPE in place on q,k
    rope_kernel<<<(NROW * H_ * 32 + 255) / 256, 256, 0, stream>>>(qkv_b);
    // V transpose (h_b dead; vt_g aliases it)
    vtr_kernel<<<dim3(S_/64, B_*H_), 256, 0, stream>>>(qkv_b, vt_g);
    // attention -> o bf16   (8-wave blocks, QBLK=128)
    attn_kernel<<<dim3(B_*H_, S_/128), 512, 0, stream>>>(qkv_b, vt_g, o_b);
    // G3: t1 = o @ w_out + b_out + h -> f32   (128^2, N=512, K=512)
    gemm_kernel<false,true,true,false><<<dim3(D_/128, NROW/128), 256, 0, stream>>>(
        o_b, wout_t, b_out, h_f, t1_f, nullptr, NROW, D_, D_);
    // LN1 -> h2 f32 + bf16
    ln_kernel<true><<<NROW/4, 256, 0, stream>>>(t1_f, g1, bn1, h2_f, h2_b);
    // G4: f1 = relu(h2 @ w_ffn1 + b_ffn1) -> bf16   (8-phase 256^2)
    gemm8p_kernel<true><<<(NROW/256) * (4*D_/256), 512, 0, stream>>>(
        h2_b, wf1_t, b_ffn1, f1_b, NROW, 4*D_, D_);
    // G5: t2 = f1 @ w_ffn2 + b_ffn2 + h2 -> f32   (256x128 pipelined, K=2048)
    gemm256_kernel<128,false,true,true,false><<<(NROW/256) * (D_/128), 512, 0, stream>>>(
        f1_b, wf2_t, b_ffn2, h2_f, t2_f, nullptr, NROW, D_, 4*D_);
    // LN2 -> d_out (f32)
    ln_kernel<false><<<NROW/4, 256, 0, stream>>>(t2_f, g2, bn2, (float*)d_out, nullptr);

    (void)in_sizes; (void)n_in; (void)out_size; (void)ws_size;
}

// Round 6
// 300.718 us; speedup vs baseline: 5.9526x; 1.1200x over previous
//
#include <hip/hip_runtime.h>
#include <hip/hip_bf16.h>
#include <math.h>

// ---------------- problem constants ----------------
#define B_   16
#define S_   1024
#define CIN  1280
#define D_   512
#define H_   8
#define HD_  64
#define NROW (B_ * S_)        // 16384

typedef __bf16 bf16;
typedef float  f32x2  __attribute__((ext_vector_type(2)));
typedef float  f32x4  __attribute__((ext_vector_type(4)));
typedef bf16   bf16x4 __attribute__((ext_vector_type(4)));
typedef bf16   bf16x8 __attribute__((ext_vector_type(8)));

__device__ __forceinline__ void gload_lds16(const bf16* g, bf16* l) {
    __builtin_amdgcn_global_load_lds(
        (const __attribute__((address_space(1))) void*)g,
        (__attribute__((address_space(3))) void*)l, 16, 0, 0);
}

#define SBAR()   __builtin_amdgcn_s_barrier()
#define SCHED0() __builtin_amdgcn_sched_barrier(0)
#define VMCNT8() asm volatile("s_waitcnt vmcnt(8)" ::: "memory")
#define VMCNT6() asm volatile("s_waitcnt vmcnt(6)" ::: "memory")
#define VMCNT2() asm volatile("s_waitcnt vmcnt(2)" ::: "memory")
#define VMCNT0() asm volatile("s_waitcnt vmcnt(0)" ::: "memory")
#define LGKM0()  asm volatile("s_waitcnt lgkmcnt(0)" ::: "memory")

// ---------------- f32 -> bf16 convert ----------------
__global__ void cvt_kernel(const float* __restrict__ in, bf16* __restrict__ out, int n4)
{
    int i = blockIdx.x * blockDim.x + threadIdx.x;
    if (i >= n4) return;
    f32x4 v = *(const f32x4*)(in + (size_t)i * 4);
    bf16x4 o;
    o[0] = (bf16)v[0]; o[1] = (bf16)v[1]; o[2] = (bf16)v[2]; o[3] = (bf16)v[3];
    *(bf16x4*)(out + (size_t)i * 4) = o;
}

// ---------------- f32 [R][C] -> bf16 transposed [C][R] ----------------
__global__ __launch_bounds__(256)
void tr_cvt_kernel(const float* __restrict__ in, bf16* __restrict__ out, int R, int C)
{
    __shared__ float T[32][33];
    const int r0 = blockIdx.y << 5, c0 = blockIdx.x << 5;
    const int t  = threadIdx.x;
    {
        int lr = t >> 3, lc = (t & 7) << 2;
        f32x4 v = *(const f32x4*)(in + (size_t)(r0 + lr) * C + c0 + lc);
        T[lr][lc] = v[0]; T[lr][lc + 1] = v[1]; T[lr][lc + 2] = v[2]; T[lr][lc + 3] = v[3];
    }
    __syncthreads();
    {
        int oc = t >> 3, orr = (t & 7) << 2;
        bf16x4 o;
        o[0] = (bf16)T[orr][oc];     o[1] = (bf16)T[orr + 1][oc];
        o[2] = (bf16)T[orr + 2][oc]; o[3] = (bf16)T[orr + 3][oc];
        *(bf16x4*)(out + (size_t)(c0 + oc) * R + r0 + orr) = o;
    }
}

// ---------------- cos/sin table for RoPE: cs[s][i] = (cos, sin) ----------------
__global__ void cs_kernel(float* __restrict__ cs)
{
    int idx = blockIdx.x * 256 + threadIdx.x;   // 0..32767
    int s = idx >> 5, i = idx & 31;
    float freq = exp2f(-(float)i * (13.287712379549449f / 32.f)); // 10000^(-i/32)
    float sn, c;
    sincosf((float)s * freq, &sn, &c);
    cs[(size_t)idx * 2]     = c;
    cs[(size_t)idx * 2 + 1] = sn;
}

// ---------------- 256xBN BK=64 pipelined GEMM (G1/G3/G5) ----------------
#define ASZ (256 * 64)

template<int BN, bool RELU, bool RES, bool OUTF, bool OUTB>
__global__ __launch_bounds__(512, 2)
void gemm256_kernel(const bf16* __restrict__ A, const bf16* __restrict__ Wt,
                    const float* __restrict__ bias, const bf16* __restrict__ res,
                    float* __restrict__ outf, bf16* __restrict__ outb,
                    int M, int N, int K)
{
    constexpr int BSZ = BN * 64;
    constexpr int NJ  = BN / 64;
    constexpr int BCHV = (BN / 8) / 8;
    __shared__ bf16 lds[2 * ASZ + 2 * BSZ];

    const int tid  = threadIdx.x;
    const int lane = tid & 63;
    const int wid  = tid >> 6;

    const int mTiles = M >> 8;
    const int perX   = mTiles >> 3;
    const int lin    = blockIdx.x;
    const int idx    = lin >> 3;
    const int my     = (lin & 7) * perX + (idx & (perX - 1));
    const int nx     = idx / perX;
    const int m0     = my << 8, n0 = nx * BN;

    const int sRow = lane >> 3;
    const int sK   = ((lane & 7) ^ (lane >> 3)) << 3;

    const int r2 = wid >> 2;
    const int c4 = wid & 3;
    const int cc = lane & 15;
    const int g  = (lane >> 4) & 3;
    const int swz = (cc & 7) << 4;

    f32x4 acc[8][NJ] = {};

    auto stage = [&](int t, int b) {
        const bf16* gA = A  + (size_t)m0 * K + t * 64;
        const bf16* gB = Wt + (size_t)n0 * K + t * 64;
        bf16* lA = lds + b * ASZ;
        bf16* lB = lds + 2 * ASZ + b * BSZ;
        #pragma unroll
        for (int v = 0; v < 4; ++v) {
            const int ch = v * 8 + wid;
            gload_lds16(gA + (size_t)(ch * 8 + sRow) * K + sK, lA + ch * 512);
        }
        #pragma unroll
        for (int v = 0; v < BCHV; ++v) {
            const int ch = v * 8 + wid;
            gload_lds16(gB + (size_t)(ch * 8 + sRow) * K + sK, lB + ch * 512);
        }
    };

    const int T = K >> 6;
    stage(0, 0);
    stage(1, 1);
    if constexpr (BN == 256) VMCNT8(); else VMCNT6();
    SCHED0();
    SBAR();

    for (int t = 0; t < T; ++t) {
        const int b = t & 1;
        const char* lA = (const char*)(lds + b * ASZ);
        const char* lB = (const char*)(lds + 2 * ASZ + b * BSZ);

        #pragma unroll
        for (int ks = 0; ks < 2; ++ks) {
            bf16x8 af[8], bfr[NJ];
            #pragma unroll
            for (int i = 0; i < 8; ++i) {
                const int row = r2 * 128 + i * 16 + cc;
                af[i] = *(const bf16x8*)(lA + row * 128 + ((ks * 64 + g * 16) ^ swz));
            }
            #pragma unroll
            for (int j = 0; j < NJ; ++j) {
                const int row = c4 * (BN / 4) + j * 16 + cc;
                bfr[j] = *(const bf16x8*)(lB + row * 128 + ((ks * 64 + g * 16) ^ swz));
            }
            __builtin_amdgcn_s_setprio(1);
            #pragma unroll
            for (int i = 0; i < 8; ++i)
                #pragma unroll
                for (int j = 0; j < NJ; ++j)
                    acc[i][j] = __builtin_amdgcn_mfma_f32_16x16x32_bf16(af[i], bfr[j], acc[i][j], 0, 0, 0);
            __builtin_amdgcn_s_setprio(0);
        }
        SCHED0();
        SBAR();
        if (t + 2 < T) {
            stage(t + 2, b);
            if constexpr (BN == 256) VMCNT8(); else VMCNT6();
        } else if (t + 1 < T) {
            VMCNT0();
        }
        if (t + 1 < T) { SCHED0(); SBAR(); }
    }

    const int rq = g << 2;
    #pragma unroll
    for (int i = 0; i < 8; ++i) {
        #pragma unroll
        for (int j = 0; j < NJ; ++j) {
            const int gn = n0 + c4 * (BN / 4) + j * 16 + cc;
            const float bv = bias[gn];
            #pragma unroll
            for (int r = 0; r < 4; ++r) {
                const int gm = m0 + r2 * 128 + i * 16 + rq + r;
                float v = acc[i][j][r] + bv;
                if (RES)  v += (float)res[(size_t)gm * N + gn];
                if (RELU) v = fmaxf(v, 0.f);
                if (OUTF) outf[(size_t)gm * N + gn] = v;
                if (OUTB) outb[(size_t)gm * N + gn] = (bf16)v;
            }
        }
    }
}

// ---------------- 256x256 8-phase GEMM (G2/G4) ----------------
// EPI 0: plain bf16 out (+RELU). EPI 1: qkv epilogue — RoPE'd q/k -> outb,
// v -> vt[bh][d][s] transposed (qkv section chosen by block's n-tile).
#define LDA8(I0, BUF) do {                                                         \
    const char* _p = (const char*)ldsA + (BUF) * 32768;                            \
    _Pragma("unroll")                                                              \
    for (int _i = 0; _i < 4; ++_i) {                                               \
        const int _row = r2 * 128 + ((I0) + _i) * 16 + cc;                         \
        _Pragma("unroll")                                                          \
        for (int _k = 0; _k < 2; ++_k)                                             \
            aF[_i][_k] = *(const bf16x8*)(_p + _row * 128 + ((_k * 64 + g16) ^ swz)); \
    }                                                                              \
} while (0)

#define LDB8(J0, BUF) do {                                                         \
    const char* _p = (const char*)ldsB + (BUF) * 32768;                            \
    _Pragma("unroll")                                                              \
    for (int _j = 0; _j < 2; ++_j) {                                               \
        const int _row = c4 * 64 + ((J0) + _j) * 16 + cc;                          \
        _Pragma("unroll")                                                          \
        for (int _k = 0; _k < 2; ++_k)                                             \
            bF[_j][_k] = *(const bf16x8*)(_p + _row * 128 + ((_k * 64 + g16) ^ swz)); \
    }                                                                              \
} while (0)

#define MM8(I0, J0) do {                                                           \
    __builtin_amdgcn_s_setprio(1);                                                 \
    _Pragma("unroll")                                                              \
    for (int _i = 0; _i < 4; ++_i)                                                 \
        _Pragma("unroll")                                                          \
        for (int _j = 0; _j < 2; ++_j)                                             \
            _Pragma("unroll")                                                      \
            for (int _k = 0; _k < 2; ++_k)                                         \
                acc[(I0) + _i][(J0) + _j] = __builtin_amdgcn_mfma_f32_16x16x32_bf16( \
                    aF[_i][_k], bF[_j][_k], acc[(I0) + _i][(J0) + _j], 0, 0, 0);   \
    __builtin_amdgcn_s_setprio(0);                                                 \
} while (0)

template<int EPI, bool RELU>
__global__ __launch_bounds__(512, 2)
void gemm8p_kernel(const bf16* __restrict__ A, const bf16* __restrict__ Wt,
                   const float* __restrict__ bias, bf16* __restrict__ outb,
                   const float* __restrict__ cs, bf16* __restrict__ vt,
                   int M, int N, int K)
{
    __shared__ bf16 ldsA[2 * 256 * 64];
    __shared__ bf16 ldsB[2 * 256 * 64];

    const int tid  = threadIdx.x;
    const int lane = tid & 63;
    const int wid  = tid >> 6;

    const int mTiles = M >> 8;
    const int perX   = mTiles >> 3;
    const int lin    = blockIdx.x;
    const int idx    = lin >> 3;
    const int my     = (lin & 7) * perX + (idx & (perX - 1));
    const int nx     = idx / perX;
    const int m0     = my << 8, n0 = nx << 8;

    const int sRow8 = lane >> 3;
    const int sOff  = ((lane & 7) ^ sRow8) << 3;

    const int r2  = wid >> 2;
    const int c4  = wid & 3;
    const int cc  = lane & 15;
    const int g16 = ((lane >> 4) & 3) << 4;
    const int swz = (cc & 7) << 4;

    f32x4 acc[8][4] = {};
    bf16x8 aF[4][2], bF[2][2];

    const int T = K >> 6;

    auto stA = [&](int t, int half) {
        const bf16* gp = A + (size_t)m0 * K + t * 64;
        bf16* lp = ldsA + (t & 1) * 16384;
        #pragma unroll
        for (int ld = 0; ld < 2; ++ld) {
            const int rb = ld * 128 + half * 64 + wid * 8;
            gload_lds16(gp + (size_t)(rb + sRow8) * K + sOff, lp + rb * 64 + lane * 8);
        }
    };
    auto stB = [&](int t, int half) {
        const bf16* gp = Wt + (size_t)n0 * K + t * 64;
        bf16* lp = ldsB + (t & 1) * 16384;
        #pragma unroll
        for (int ld = 0; ld < 2; ++ld) {
            const int q  = ld * 2 + (wid >> 2);
            const int rb = q * 64 + half * 32 + (wid & 3) * 8;
            gload_lds16(gp + (size_t)(rb + sRow8) * K + sOff, lp + rb * 64 + lane * 8);
        }
    };

    stA(0, 0); stB(0, 1); stA(0, 1); stB(0, 0);
    stA(1, 0); stB(1, 1); stA(1, 1);
    VMCNT6();
    SCHED0();
    SBAR();
    SCHED0();

    for (int t = 0; t < T; ++t) {
        const int b = t & 1;
        LDA8(0, b); LDB8(0, b);
        if (t + 1 < T) stB(t + 1, 0);
        SBAR(); LGKM0(); SCHED0();
        MM8(0, 0);
        SCHED0(); SBAR();
        LDB8(2, b);
        if (t + 2 < T) stA(t + 2, 0);
        SBAR(); LGKM0(); SCHED0();
        MM8(0, 2);
        SCHED0(); SBAR();
        LDA8(4, b);
        if (t + 2 < T) stB(t + 2, 1);
        SBAR(); LGKM0(); SCHED0();
        MM8(4, 2);
        SCHED0(); SBAR();
        LDB8(0, b);
        if (t + 2 < T) stA(t + 2, 1);
        SBAR(); LGKM0(); SCHED0();
        MM8(4, 0);
        SCHED0();
        if (t + 2 < T) { VMCNT6(); } else { VMCNT0(); }
        SBAR();
        SCHED0();
    }

    const int rq = ((lane >> 4) & 3) << 2;
    if constexpr (EPI == 1) {
        if (nx < 4) {
            // q (nx 0,1) / k (nx 2,3): add bias, RoPE pairs (d, d+32) in-lane
            float bj[4];
            #pragma unroll
            for (int j = 0; j < 4; ++j) bj[j] = bias[n0 + c4 * 64 + j * 16 + cc];
            #pragma unroll
            for (int i = 0; i < 8; ++i) {
                #pragma unroll
                for (int r = 0; r < 4; ++r) {
                    const int gm = m0 + r2 * 128 + i * 16 + rq + r;
                    const int s  = gm & (S_ - 1);
                    #pragma unroll
                    for (int jp = 0; jp < 2; ++jp) {
                        const int d = jp * 16 + cc;
                        f32x2 csv = *(const f32x2*)(cs + ((size_t)s * 32 + d) * 2);
                        float x1 = acc[i][jp][r]     + bj[jp];
                        float x2 = acc[i][jp + 2][r] + bj[jp + 2];
                        const size_t o1 = (size_t)gm * N + n0 + c4 * 64 + d;
                        outb[o1]      = (bf16)(x1 * csv[0] - x2 * csv[1]);
                        outb[o1 + 32] = (bf16)(x1 * csv[1] + x2 * csv[0]);
                    }
                }
            }
        } else {
            // v (nx 4,5): write transposed vt[bh][d][s]
            const int hw = (nx - 4) * 4 + c4;
            const int bb = m0 >> 10;
            bf16* vbase = vt + (size_t)(bb * 8 + hw) * (HD_ * S_);
            const int sb0 = (m0 & (S_ - 1)) + r2 * 128 + rq;
            #pragma unroll
            for (int i = 0; i < 8; ++i) {
                #pragma unroll
                for (int j = 0; j < 4; ++j) {
                    const int d = j * 16 + cc;
                    const float bv = bias[n0 + c4 * 64 + d];
                    bf16x4 pk;
                    #pragma unroll
                    for (int r = 0; r < 4; ++r) pk[r] = (bf16)(acc[i][j][r] + bv);
                    *(bf16x4*)(vbase + (size_t)d * S_ + sb0 + i * 16) = pk;
                }
            }
        }
    } else {
        #pragma unroll
        for (int i = 0; i < 8; ++i) {
            #pragma unroll
            for (int j = 0; j < 4; ++j) {
                const int gn = n0 + c4 * 64 + j * 16 + cc;
                const float bv = bias[gn];
                #pragma unroll
                for (int r = 0; r < 4; ++r) {
                    const int gm = m0 + r2 * 128 + i * 16 + rq + r;
                    float v = acc[i][j][r] + bv;
                    if (RELU) v = fmaxf(v, 0.f);
                    outb[(size_t)gm * N + gn] = (bf16)v;
                }
            }
        }
    }
    (void)cs; (void)vt;
}

// ---------------- MFMA flash attention v4: 8 waves, QBLK=128 ----------------
// VALU-trimmed: l via ones-column MFMA (rides the same defer-max rescale as O),
// exp arg as single fma, Ps stride 72 (16B-aligned b128). Defer-max THR=8 lg2.
#define PST 72

__global__ __launch_bounds__(512)
void attn_kernel(const bf16* __restrict__ qkv, const bf16* __restrict__ vtg,
                 bf16* __restrict__ o)
{
    __shared__ bf16 Ks[2][4096];
    __shared__ bf16 Vs[2][4096];
    __shared__ bf16 Ps[8][16 * PST];

    const int bh  = blockIdx.x;
    const int b   = bh >> 3;
    const int h   = bh & 7;
    const int q0  = blockIdx.y << 7;
    const int tid = threadIdx.x;
    const int lane = tid & 63;
    const int w    = tid >> 6;
    const int c    = lane & 15;
    const int g    = lane >> 4;
    const int swz  = (c & 7) << 4;

    const size_t rs = 3 * D_;
    const bf16* qb = qkv + (size_t)b * S_ * rs + h * HD_;
    const bf16* kb = qb + D_;
    const bf16* vt = vtg + (size_t)bh * HD_ * S_;

    const int sRow = tid >> 3;
    const int sOff = ((tid & 7) ^ (sRow & 7)) << 3;

    bf16x8 qf[2];
    {
        const bf16* qrow = qb + (size_t)(q0 + w * 16 + c) * rs + g * 8;
        qf[0] = *(const bf16x8*)(qrow);
        qf[1] = *(const bf16x8*)(qrow + 32);
    }
    SCHED0();

    // ones B-frag: row 0 (cc==0) = 1.0 -> D[q][0] = sum_k P[q][k]
    bf16x8 vones;
    {
        bf16 one = (bf16)(c == 0 ? 1.f : 0.f);
        #pragma unroll
        for (int u = 0; u < 8; ++u) vones[u] = one;
    }

    auto stage = [&](int t, int buf) {
        gload_lds16(kb + (size_t)(t * 64 + sRow) * rs + sOff, &Ks[buf][0] + (size_t)tid * 8);
        gload_lds16(vt + (size_t)sRow * S_ + t * 64 + sOff,   &Vs[buf][0] + (size_t)tid * 8);
    };

    f32x4 oa[4] = {};
    f32x4 oa5 = {};                          // l in col 0 (cc==0 lanes)
    float m_r = -3.0e38f;
    const float CE  = 0.18033688011112042f;  // (1/8)*log2(e)
    const float THR = 44.3614195558365f;     // 8 / CE (raw-score units)

    stage(0, 0);
    stage(1, 1);
    VMCNT2();
    SCHED0();
    SBAR();

    for (int t = 0; t < 16; ++t) {
        const int buf = t & 1;
        const char* kB = (const char*)Ks[buf];
        const char* vB = (const char*)Vs[buf];

        f32x4 sa[4] = {};
        __builtin_amdgcn_s_setprio(1);
        #pragma unroll
        for (int ch = 0; ch < 2; ++ch)
            #pragma unroll
            for (int ks = 0; ks < 4; ++ks) {
                bf16x8 kf = *(const bf16x8*)(kB + (ks * 16 + c) * 128 + ((ch * 64 + g * 16) ^ swz));
                sa[ks] = __builtin_amdgcn_mfma_f32_16x16x32_bf16(kf, qf[ch], sa[ks], 0, 0, 0);
            }
        __builtin_amdgcn_s_setprio(0);

        float pmax = -3.0e38f;
        #pragma unroll
        for (int ks = 0; ks < 4; ++ks)
            pmax = fmaxf(pmax, fmaxf(fmaxf(sa[ks][0], sa[ks][1]), fmaxf(sa[ks][2], sa[ks][3])));
        pmax = fmaxf(pmax, __shfl_xor(pmax, 16, 64));
        pmax = fmaxf(pmax, __shfl_xor(pmax, 32, 64));

        if (!__all(pmax - m_r <= THR)) {
            float mnew = fmaxf(m_r, pmax);
            float sc = __builtin_amdgcn_exp2f((m_r - mnew) * CE);
            #pragma unroll
            for (int r = 0; r < 4; ++r) {
                float scr = __shfl(sc, g * 4 + r, 64);
                #pragma unroll
                for (int j = 0; j < 4; ++j) oa[j][r] *= scr;
                oa5[r] *= scr;
            }
            m_r = mnew;
        }

        const float nmCE = -m_r * CE;
        #pragma unroll
        for (int ks = 0; ks < 4; ++ks) {
            bf16x4 pb;
            #pragma unroll
            for (int r = 0; r < 4; ++r)
                pb[r] = (bf16)__builtin_amdgcn_exp2f(__builtin_fmaf(sa[ks][r], CE, nmCE));
            *(bf16x4*)&Ps[w][c * PST + ks * 16 + g * 4] = pb;
        }

        __builtin_amdgcn_s_setprio(1);
        #pragma unroll
        for (int ch = 0; ch < 2; ++ch) {
            bf16x8 pa = *(const bf16x8*)&Ps[w][c * PST + ch * 32 + g * 8];
            #pragma unroll
            for (int j = 0; j < 4; ++j) {
                bf16x8 vf = *(const bf16x8*)(vB + (j * 16 + c) * 128 + ((ch * 64 + g * 16) ^ swz));
                oa[j] = __builtin_amdgcn_mfma_f32_16x16x32_bf16(pa, vf, oa[j], 0, 0, 0);
            }
            oa5 = __builtin_amdgcn_mfma_f32_16x16x32_bf16(pa, vones, oa5, 0, 0, 0);
        }
        __builtin_amdgcn_s_setprio(0);

        SCHED0();
        SBAR();
        if (t + 2 < 16) {
            stage(t + 2, buf);
            VMCNT2();
        } else if (t + 1 < 16) {
            VMCNT0();
        }
        if (t + 1 < 16) { SCHED0(); SBAR(); }
    }

    float linv[4];
    #pragma unroll
    for (int r = 0; r < 4; ++r)
        linv[r] = 1.f / __shfl(oa5[r], lane & 48, 64);   // l from (cc=0, same g)
    #pragma unroll
    for (int j = 0; j < 4; ++j)
        #pragma unroll
        for (int r = 0; r < 4; ++r) {
            int q = q0 + w * 16 + g * 4 + r;
            o[((size_t)(b * S_) + q) * D_ + h * HD_ + j * 16 + c] = (bf16)(oa[j][r] * linv[r]);
        }
}

// ---------------- LayerNorm over D=512, one wave per row ----------------
template<bool OUTF, bool OUTB>
__global__ __launch_bounds__(256)
void ln_kernel(const float* __restrict__ in, const float* __restrict__ g,
               const float* __restrict__ be, float* __restrict__ outf,
               bf16* __restrict__ outb)
{
    const int row  = (blockIdx.x << 2) + (threadIdx.x >> 6);
    const int lane = threadIdx.x & 63;
    const float* p = in + (size_t)row * D_;
    f32x4 a  = *(const f32x4*)(p + lane * 4);
    f32x4 b2 = *(const f32x4*)(p + 256 + lane * 4);
    float s  = a[0] + a[1] + a[2] + a[3] + b2[0] + b2[1] + b2[2] + b2[3];
    float s2 = a[0]*a[0] + a[1]*a[1] + a[2]*a[2] + a[3]*a[3]
             + b2[0]*b2[0] + b2[1]*b2[1] + b2[2]*b2[2] + b2[3]*b2[3];
    #pragma unroll
    for (int off = 32; off; off >>= 1) {
        s  += __shfl_xor(s,  off, 64);
        s2 += __shfl_xor(s2, off, 64);
    }
    const float mean = s * (1.f / 512.f);
    const float var  = s2 * (1.f / 512.f) - mean * mean;
    const float rstd = rsqrtf(var + 1e-5f);

    f32x4 g0 = *(const f32x4*)(g + lane * 4);
    f32x4 g1 = *(const f32x4*)(g + 256 + lane * 4);
    f32x4 e0 = *(const f32x4*)(be + lane * 4);
    f32x4 e1 = *(const f32x4*)(be + 256 + lane * 4);
    f32x4 o0, o1;
    #pragma unroll
    for (int u = 0; u < 4; u++) {
        o0[u] = (a[u]  - mean) * rstd * g0[u] + e0[u];
        o1[u] = (b2[u] - mean) * rstd * g1[u] + e1[u];
    }
    if (OUTF) {
        float* of = outf + (size_t)row * D_;
        *(f32x4*)(of + lane * 4)       = o0;
        *(f32x4*)(of + 256 + lane * 4) = o1;
    }
    if (OUTB) {
        bf16x4 c0, c1;
        #pragma unroll
        for (int u = 0; u < 4; u++) { c0[u] = (bf16)o0[u]; c1[u] = (bf16)o1[u]; }
        bf16* ob = outb + (size_t)row * D_;
        *(bf16x4*)(ob + lane * 4)       = c0;
        *(bf16x4*)(ob + 256 + lane * 4) = c1;
    }
}

// ---------------- host launcher ----------------
extern "C" void kernel_launch(void* const* d_in, const int* in_sizes, int n_in,
                              void* d_out, int out_size, void* d_ws, size_t ws_size,
                              hipStream_t stream)
{
    const float* x      = (const float*)d_in[0];
    const float* w_in   = (const float*)d_in[1];
    const float* b_in   = (const float*)d_in[2];
    const float* w_qkv  = (const float*)d_in[3];
    const float* b_qkv  = (const float*)d_in[4];
    const float* w_out  = (const float*)d_in[5];
    const float* b_out  = (const float*)d_in[6];
    const float* w_ffn1 = (const float*)d_in[7];
    const float* b_ffn1 = (const float*)d_in[8];
    const float* w_ffn2 = (const float*)d_in[9];
    const float* b_ffn2 = (const float*)d_in[10];
    const float* g1     = (const float*)d_in[11];
    const float* bn1    = (const float*)d_in[12];
    const float* g2     = (const float*)d_in[13];
    const float* bn2    = (const float*)d_in[14];

    char* ws = (char*)d_ws;
    constexpr size_t OFF_XB   = 0;                       // x bf16 (alias t1 f32 later)
    constexpr size_t OFF_WIN  = OFF_XB   + 41943040ull;
    constexpr size_t OFF_WQKV = OFF_WIN  + 1310720ull;
    constexpr size_t OFF_WOUT = OFF_WQKV + 1572864ull;
    constexpr size_t OFF_WF1  = OFF_WOUT + 524288ull;
    constexpr size_t OFF_WF2  = OFF_WF1  + 2097152ull;
    constexpr size_t OFF_CS   = OFF_WF2  + 2097152ull;   // cos/sin table 256KB (in old h_f area)
    constexpr size_t OFF_HB   = OFF_CS   + 33554432ull;  // h bf16 (alive through G3)
    constexpr size_t OFF_QKV  = OFF_HB   + 16777216ull;  // qkv bf16 (alias t2 f32 later)
    constexpr size_t OFF_OB   = OFF_QKV  + 50331648ull;
    constexpr size_t OFF_VT   = OFF_OB   + 16777216ull;  // vt bf16 16MB (old h2_f area)
    constexpr size_t OFF_H2B  = OFF_VT   + 33554432ull;
    constexpr size_t OFF_F1   = OFF_H2B  + 16777216ull;
    constexpr size_t OFF_T1   = OFF_XB;
    constexpr size_t OFF_T2   = OFF_QKV;

    bf16*  x_b    = (bf16*)(ws + OFF_XB);
    bf16*  win_t  = (bf16*)(ws + OFF_WIN);
    bf16*  wqkv_t = (bf16*)(ws + OFF_WQKV);
    bf16*  wout_t = (bf16*)(ws + OFF_WOUT);
    bf16*  wf1_t  = (bf16*)(ws + OFF_WF1);
    bf16*  wf2_t  = (bf16*)(ws + OFF_WF2);
    float* cs_t   = (float*)(ws + OFF_CS);
    bf16*  h_b    = (bf16*)(ws + OFF_HB);
    bf16*  qkv_b  = (bf16*)(ws + OFF_QKV);
    bf16*  o_b    = (bf16*)(ws + OFF_OB);
    bf16*  vt_g   = (bf16*)(ws + OFF_VT);
    bf16*  h2_b   = (bf16*)(ws + OFF_H2B);
    bf16*  f1_b   = (bf16*)(ws + OFF_F1);
    float* t1_f   = (float*)(ws + OFF_T1);
    float* t2_f   = (float*)(ws + OFF_T2);

    {
        int n4 = NROW * CIN / 4;
        cvt_kernel<<<(n4 + 255) / 256, 256, 0, stream>>>(x, x_b, n4);
    }
    tr_cvt_kernel<<<dim3(512/32, 1280/32), 256, 0, stream>>>(w_in,   win_t,  1280, 512);
    tr_cvt_kernel<<<dim3(1536/32, 512/32), 256, 0, stream>>>(w_qkv,  wqkv_t, 512, 1536);
    tr_cvt_kernel<<<dim3(512/32,  512/32), 256, 0, stream>>>(w_out,  wout_t, 512, 512);
    tr_cvt_kernel<<<dim3(2048/32, 512/32), 256, 0, stream>>>(w_ffn1, wf1_t,  512, 2048);
    tr_cvt_kernel<<<dim3(512/32, 2048/32), 256, 0, stream>>>(w_ffn2, wf2_t,  2048, 512);
    cs_kernel<<<128, 256, 0, stream>>>(cs_t);

    // G1: h = x @ w_in + b_in -> bf16 only
    gemm256_kernel<128,false,false,false,true><<<(NROW/256) * (D_/128), 512, 0, stream>>>(
        x_b, win_t, b_in, nullptr, nullptr, h_b, NROW, D_, CIN);
    // G2: qkv = h @ w_qkv + b_qkv; epilogue: RoPE(q,k) -> qkv_b, v -> vt_g
    gemm8p_kernel<1,false><<<(NROW/256) * (3*D_/256), 512, 0, stream>>>(
        h_b, wqkv_t, b_qkv, qkv_b, cs_t, vt_g, NROW, 3*D_, D_);
    // attention -> o bf16
    attn_kernel<<<dim3(B_*H_, S_/128), 512, 0, stream>>>(qkv_b, vt_g, o_b);
    // G3: t1 = o @ w_out + b_out + h(bf16) -> f32
    gemm256_kernel<128,false,true,true,false><<<(NROW/256) * (D_/128), 512, 0, stream>>>(
        o_b, wout_t, b_out, h_b, t1_f, nullptr, NROW, D_, D_);
    // LN1 -> h2 bf16 only
    ln_kernel<false,true><<<NROW/4, 256, 0, stream>>>(t1_f, g1, bn1, nullptr, h2_b);
    // G4: f1 = relu(h2 @ w_ffn1 + b_ffn1) -> bf16
    gemm8p_kernel<0,true><<<(NROW/256) * (4*D_/256), 512, 0, stream>>>(
        h2_b, wf1_t, b_ffn1, f1_b, nullptr, nullptr, NROW, 4*D_, D_);
    // G5: t2 = f1 @ w_ffn2 + b_ffn2 + h2(bf16) -> f32
    gemm256_kernel<128,false,true,true,false><<<(NROW/256) * (D_/128), 512, 0, stream>>>(
        f1_b, wf2_t, b_ffn2, h2_b, t2_f, nullptr, NROW, D_, 4*D_);
    // LN2 -> d_out (f32)
    ln_kernel<true,false><<<NROW/4, 256, 0, stream>>>(t2_f, g2, bn2, (float*)d_out, nullptr);

    (void)in_sizes; (void)n_in; (void)out_size; (void)ws_size;
}

// Round 7
// 275.661 us; speedup vs baseline: 6.4937x; 1.0909x over previous
//
#include <hip/hip_runtime.h>
#include <hip/hip_bf16.h>
#include <math.h>

// ---------------- problem constants ----------------
#define B_   16
#define S_   1024
#define CIN  1280
#define D_   512
#define H_   8
#define HD_  64
#define NROW (B_ * S_)        // 16384

typedef __bf16 bf16;
typedef float  f32x2  __attribute__((ext_vector_type(2)));
typedef float  f32x4  __attribute__((ext_vector_type(4)));
typedef bf16   bf16x4 __attribute__((ext_vector_type(4)));
typedef bf16   bf16x8 __attribute__((ext_vector_type(8)));

__device__ __forceinline__ void gload_lds16(const bf16* g, bf16* l) {
    __builtin_amdgcn_global_load_lds(
        (const __attribute__((address_space(1))) void*)g,
        (__attribute__((address_space(3))) void*)l, 16, 0, 0);
}

#define SBAR()   __builtin_amdgcn_s_barrier()
#define SCHED0() __builtin_amdgcn_sched_barrier(0)
#define VMCNT8() asm volatile("s_waitcnt vmcnt(8)" ::: "memory")
#define VMCNT2() asm volatile("s_waitcnt vmcnt(2)" ::: "memory")
#define VMCNT0() asm volatile("s_waitcnt vmcnt(0)" ::: "memory")

// ---------------- f32 -> bf16 convert ----------------
__global__ void cvt_kernel(const float* __restrict__ in, bf16* __restrict__ out, int n4)
{
    int i = blockIdx.x * blockDim.x + threadIdx.x;
    if (i >= n4) return;
    f32x4 v = *(const f32x4*)(in + (size_t)i * 4);
    bf16x4 o;
    o[0] = (bf16)v[0]; o[1] = (bf16)v[1]; o[2] = (bf16)v[2]; o[3] = (bf16)v[3];
    *(bf16x4*)(out + (size_t)i * 4) = o;
}

// ---------------- f32 [R][C] -> bf16 transposed [C][R] ----------------
__global__ __launch_bounds__(256)
void tr_cvt_kernel(const float* __restrict__ in, bf16* __restrict__ out, int R, int C)
{
    __shared__ float T[32][33];
    const int r0 = blockIdx.y << 5, c0 = blockIdx.x << 5;
    const int t  = threadIdx.x;
    {
        int lr = t >> 3, lc = (t & 7) << 2;
        f32x4 v = *(const f32x4*)(in + (size_t)(r0 + lr) * C + c0 + lc);
        T[lr][lc] = v[0]; T[lr][lc + 1] = v[1]; T[lr][lc + 2] = v[2]; T[lr][lc + 3] = v[3];
    }
    __syncthreads();
    {
        int oc = t >> 3, orr = (t & 7) << 2;
        bf16x4 o;
        o[0] = (bf16)T[orr][oc];     o[1] = (bf16)T[orr + 1][oc];
        o[2] = (bf16)T[orr + 2][oc]; o[3] = (bf16)T[orr + 3][oc];
        *(bf16x4*)(out + (size_t)(c0 + oc) * R + r0 + orr) = o;
    }
}

// ---------------- cos/sin table for RoPE: cs[s][i] = (cos, sin) ----------------
__global__ void cs_kernel(float* __restrict__ cs)
{
    int idx = blockIdx.x * 256 + threadIdx.x;   // 0..32767
    int s = idx >> 5, i = idx & 31;
    float freq = exp2f(-(float)i * (13.287712379549449f / 32.f)); // 10000^(-i/32)
    float sn, c;
    sincosf((float)s * freq, &sn, &c);
    cs[(size_t)idx * 2]     = c;
    cs[(size_t)idx * 2 + 1] = sn;
}

// ---------------- 128x128 BK=64 double-buffered GEMM (ALL five GEMMs) ----------------
// 4 waves (2Mx2N), wave out 64x64 = 4x4 frags. LDS 64 KiB -> 2 resident
// blocks/CU (cross-block overlap, m114). Counted vmcnt(8) double-buffer,
// T2 swizzle byte ^= (row&7)<<4 both sides. Grids are exact multiples of 256.
// EPI 0: bias(+res bf16)(+relu) -> f32 and/or bf16.
// EPI 1: qkv epilogue (N=1536): nx 0-7 -> RoPE'd q/k; nx 8-11 -> vt[bh][d][s].
#define ASZ1 (128 * 64)

template<int EPI, bool RELU, bool RES, bool OUTF, bool OUTB>
__global__ __launch_bounds__(256, 2)
void gemm128_kernel(const bf16* __restrict__ A, const bf16* __restrict__ Wt,
                    const float* __restrict__ bias, const bf16* __restrict__ res,
                    float* __restrict__ outf, bf16* __restrict__ outb,
                    const float* __restrict__ cs, bf16* __restrict__ vt,
                    int M, int N, int K)
{
    __shared__ bf16 lds[4 * ASZ1];   // A dbuf (2) + B dbuf (2), 64 KiB

    const int tid  = threadIdx.x;
    const int lane = tid & 63;
    const int wid  = tid >> 6;

    // XCD-bijective decode over mTiles = M/128 = 128 (divisible by 8)
    const int perX = (M >> 7) >> 3;            // 16
    const int lin  = blockIdx.x;
    const int idx  = lin >> 3;
    const int my   = (lin & 7) * perX + (idx & (perX - 1));
    const int nx   = idx / perX;
    const int m0   = my << 7, n0 = nx << 7;

    const int sRow = lane >> 3;                      // 0..7
    const int sK   = ((lane & 7) ^ sRow) << 3;       // pre-swizzled source col

    const int r2  = wid >> 1;                        // wave M half
    const int c2  = wid & 1;                         // wave N half
    const int cc  = lane & 15;
    const int g   = (lane >> 4) & 3;
    const int swz = (cc & 7) << 4;

    f32x4 acc[4][4] = {};

    auto stage = [&](int t, int b) {
        const bf16* gA = A  + (size_t)m0 * K + t * 64;
        const bf16* gB = Wt + (size_t)n0 * K + t * 64;
        bf16* lA = lds + b * ASZ1;
        bf16* lB = lds + 2 * ASZ1 + b * ASZ1;
        #pragma unroll
        for (int v = 0; v < 4; ++v) {
            const int ch = v * 4 + wid;              // 0..15, wave-uniform
            gload_lds16(gA + (size_t)(ch * 8 + sRow) * K + sK, lA + ch * 512);
            gload_lds16(gB + (size_t)(ch * 8 + sRow) * K + sK, lB + ch * 512);
        }
    };

    const int T = K >> 6;
    stage(0, 0);
    stage(1, 1);
    VMCNT8();                  // tile 0 landed; tile 1's 8 in flight
    SCHED0();
    SBAR();

    for (int t = 0; t < T; ++t) {
        const int b = t & 1;
        const char* lA = (const char*)(lds + b * ASZ1);
        const char* lB = (const char*)(lds + 2 * ASZ1 + b * ASZ1);

        #pragma unroll
        for (int ks = 0; ks < 2; ++ks) {
            bf16x8 af[4], bfr[4];
            #pragma unroll
            for (int i = 0; i < 4; ++i) {
                const int row = r2 * 64 + i * 16 + cc;
                af[i] = *(const bf16x8*)(lA + row * 128 + ((ks * 64 + g * 16) ^ swz));
            }
            #pragma unroll
            for (int j = 0; j < 4; ++j) {
                const int row = c2 * 64 + j * 16 + cc;
                bfr[j] = *(const bf16x8*)(lB + row * 128 + ((ks * 64 + g * 16) ^ swz));
            }
            __builtin_amdgcn_s_setprio(1);
            #pragma unroll
            for (int i = 0; i < 4; ++i)
                #pragma unroll
                for (int j = 0; j < 4; ++j)
                    acc[i][j] = __builtin_amdgcn_mfma_f32_16x16x32_bf16(af[i], bfr[j], acc[i][j], 0, 0, 0);
            __builtin_amdgcn_s_setprio(0);
        }
        SCHED0();
        SBAR();                          // all waves done reading buf b
        if (t + 2 < T) {
            stage(t + 2, b);             // 8 new loads into just-freed buf
            VMCNT8();                    // tile t+1 landed; t+2 in flight
        } else if (t + 1 < T) {
            VMCNT0();
        }
        if (t + 1 < T) { SCHED0(); SBAR(); }
    }

    const int rq = g << 2;
    if constexpr (EPI == 1) {
        const int colb = c2 * 64;                    // wave col base (one head)
        if (nx < 8) {
            // q (nx 0-3) / k (nx 4-7): add bias, RoPE pairs (d, d+32) in-lane
            float bj[4];
            #pragma unroll
            for (int j = 0; j < 4; ++j) bj[j] = bias[n0 + colb + j * 16 + cc];
            #pragma unroll
            for (int i = 0; i < 4; ++i) {
                #pragma unroll
                for (int r = 0; r < 4; ++r) {
                    const int gm = m0 + r2 * 64 + i * 16 + rq + r;
                    const int s  = gm & (S_ - 1);
                    #pragma unroll
                    for (int jp = 0; jp < 2; ++jp) {
                        const int d = jp * 16 + cc;
                        f32x2 csv = *(const f32x2*)(cs + ((size_t)s * 32 + d) * 2);
                        float x1 = acc[i][jp][r]     + bj[jp];
                        float x2 = acc[i][jp + 2][r] + bj[jp + 2];
                        const size_t o1 = (size_t)gm * N + n0 + colb + d;
                        outb[o1]      = (bf16)(x1 * csv[0] - x2 * csv[1]);
                        outb[o1 + 32] = (bf16)(x1 * csv[1] + x2 * csv[0]);
                    }
                }
            }
        } else {
            // v (nx 8-11): write transposed vt[bh][d][s]
            const int col0 = n0 + colb;
            const int hw = (col0 >> 6) & 7;
            const int bb = m0 >> 10;
            bf16* vbase = vt + (size_t)(bb * 8 + hw) * (HD_ * S_);
            const int sb0 = (m0 & (S_ - 1)) + r2 * 64 + rq;
            #pragma unroll
            for (int i = 0; i < 4; ++i) {
                #pragma unroll
                for (int j = 0; j < 4; ++j) {
                    const int d = j * 16 + cc;
                    const float bv = bias[col0 + d];
                    bf16x4 pk;
                    #pragma unroll
                    for (int r = 0; r < 4; ++r) pk[r] = (bf16)(acc[i][j][r] + bv);
                    *(bf16x4*)(vbase + (size_t)d * S_ + sb0 + i * 16) = pk;
                }
            }
        }
    } else {
        #pragma unroll
        for (int i = 0; i < 4; ++i) {
            #pragma unroll
            for (int j = 0; j < 4; ++j) {
                const int gn = n0 + c2 * 64 + j * 16 + cc;
                const float bv = bias[gn];
                #pragma unroll
                for (int r = 0; r < 4; ++r) {
                    const int gm = m0 + r2 * 64 + i * 16 + rq + r;
                    float v = acc[i][j][r] + bv;
                    if (RES)  v += (float)res[(size_t)gm * N + gn];
                    if (RELU) v = fmaxf(v, 0.f);
                    if (OUTF) outf[(size_t)gm * N + gn] = v;
                    if (OUTB) outb[(size_t)gm * N + gn] = (bf16)v;
                }
            }
        }
    }
    (void)cs; (void)vt;
}

// ---------------- MFMA flash attention v4: 8 waves, QBLK=128 ----------------
// l via ones-column MFMA (rides defer-max rescale), fma-folded exp2 arg,
// Ps stride 72. K/V^T gload_lds-staged (XOR swizzle), dbuf, vmcnt(2).
#define PST 72

__global__ __launch_bounds__(512)
void attn_kernel(const bf16* __restrict__ qkv, const bf16* __restrict__ vtg,
                 bf16* __restrict__ o)
{
    __shared__ bf16 Ks[2][4096];
    __shared__ bf16 Vs[2][4096];
    __shared__ bf16 Ps[8][16 * PST];

    const int bh  = blockIdx.x;
    const int b   = bh >> 3;
    const int h   = bh & 7;
    const int q0  = blockIdx.y << 7;
    const int tid = threadIdx.x;
    const int lane = tid & 63;
    const int w    = tid >> 6;
    const int c    = lane & 15;
    const int g    = lane >> 4;
    const int swz  = (c & 7) << 4;

    const size_t rs = 3 * D_;
    const bf16* qb = qkv + (size_t)b * S_ * rs + h * HD_;
    const bf16* kb = qb + D_;
    const bf16* vt = vtg + (size_t)bh * HD_ * S_;

    const int sRow = tid >> 3;
    const int sOff = ((tid & 7) ^ (sRow & 7)) << 3;

    bf16x8 qf[2];
    {
        const bf16* qrow = qb + (size_t)(q0 + w * 16 + c) * rs + g * 8;
        qf[0] = *(const bf16x8*)(qrow);
        qf[1] = *(const bf16x8*)(qrow + 32);
    }
    SCHED0();

    bf16x8 vones;
    {
        bf16 one = (bf16)(c == 0 ? 1.f : 0.f);
        #pragma unroll
        for (int u = 0; u < 8; ++u) vones[u] = one;
    }

    auto stage = [&](int t, int buf) {
        gload_lds16(kb + (size_t)(t * 64 + sRow) * rs + sOff, &Ks[buf][0] + (size_t)tid * 8);
        gload_lds16(vt + (size_t)sRow * S_ + t * 64 + sOff,   &Vs[buf][0] + (size_t)tid * 8);
    };

    f32x4 oa[4] = {};
    f32x4 oa5 = {};
    float m_r = -3.0e38f;
    const float CE  = 0.18033688011112042f;  // (1/8)*log2(e)
    const float THR = 44.3614195558365f;     // 8 / CE

    stage(0, 0);
    stage(1, 1);
    VMCNT2();
    SCHED0();
    SBAR();

    for (int t = 0; t < 16; ++t) {
        const int buf = t & 1;
        const char* kB = (const char*)Ks[buf];
        const char* vB = (const char*)Vs[buf];

        f32x4 sa[4] = {};
        __builtin_amdgcn_s_setprio(1);
        #pragma unroll
        for (int ch = 0; ch < 2; ++ch)
            #pragma unroll
            for (int ks = 0; ks < 4; ++ks) {
                bf16x8 kf = *(const bf16x8*)(kB + (ks * 16 + c) * 128 + ((ch * 64 + g * 16) ^ swz));
                sa[ks] = __builtin_amdgcn_mfma_f32_16x16x32_bf16(kf, qf[ch], sa[ks], 0, 0, 0);
            }
        __builtin_amdgcn_s_setprio(0);

        float pmax = -3.0e38f;
        #pragma unroll
        for (int ks = 0; ks < 4; ++ks)
            pmax = fmaxf(pmax, fmaxf(fmaxf(sa[ks][0], sa[ks][1]), fmaxf(sa[ks][2], sa[ks][3])));
        pmax = fmaxf(pmax, __shfl_xor(pmax, 16, 64));
        pmax = fmaxf(pmax, __shfl_xor(pmax, 32, 64));

        if (!__all(pmax - m_r <= THR)) {
            float mnew = fmaxf(m_r, pmax);
            float sc = __builtin_amdgcn_exp2f((m_r - mnew) * CE);
            #pragma unroll
            for (int r = 0; r < 4; ++r) {
                float scr = __shfl(sc, g * 4 + r, 64);
                #pragma unroll
                for (int j = 0; j < 4; ++j) oa[j][r] *= scr;
                oa5[r] *= scr;
            }
            m_r = mnew;
        }

        const float nmCE = -m_r * CE;
        #pragma unroll
        for (int ks = 0; ks < 4; ++ks) {
            bf16x4 pb;
            #pragma unroll
            for (int r = 0; r < 4; ++r)
                pb[r] = (bf16)__builtin_amdgcn_exp2f(__builtin_fmaf(sa[ks][r], CE, nmCE));
            *(bf16x4*)&Ps[w][c * PST + ks * 16 + g * 4] = pb;
        }

        __builtin_amdgcn_s_setprio(1);
        #pragma unroll
        for (int ch = 0; ch < 2; ++ch) {
            bf16x8 pa = *(const bf16x8*)&Ps[w][c * PST + ch * 32 + g * 8];
            #pragma unroll
            for (int j = 0; j < 4; ++j) {
                bf16x8 vf = *(const bf16x8*)(vB + (j * 16 + c) * 128 + ((ch * 64 + g * 16) ^ swz));
                oa[j] = __builtin_amdgcn_mfma_f32_16x16x32_bf16(pa, vf, oa[j], 0, 0, 0);
            }
            oa5 = __builtin_amdgcn_mfma_f32_16x16x32_bf16(pa, vones, oa5, 0, 0, 0);
        }
        __builtin_amdgcn_s_setprio(0);

        SCHED0();
        SBAR();
        if (t + 2 < 16) {
            stage(t + 2, buf);
            VMCNT2();
        } else if (t + 1 < 16) {
            VMCNT0();
        }
        if (t + 1 < 16) { SCHED0(); SBAR(); }
    }

    float linv[4];
    #pragma unroll
    for (int r = 0; r < 4; ++r)
        linv[r] = 1.f / __shfl(oa5[r], lane & 48, 64);
    #pragma unroll
    for (int j = 0; j < 4; ++j)
        #pragma unroll
        for (int r = 0; r < 4; ++r) {
            int q = q0 + w * 16 + g * 4 + r;
            o[((size_t)(b * S_) + q) * D_ + h * HD_ + j * 16 + c] = (bf16)(oa[j][r] * linv[r]);
        }
}

// ---------------- LayerNorm over D=512, one wave per row ----------------
template<bool OUTF, bool OUTB>
__global__ __launch_bounds__(256)
void ln_kernel(const float* __restrict__ in, const float* __restrict__ g,
               const float* __restrict__ be, float* __restrict__ outf,
               bf16* __restrict__ outb)
{
    const int row  = (blockIdx.x << 2) + (threadIdx.x >> 6);
    const int lane = threadIdx.x & 63;
    const float* p = in + (size_t)row * D_;
    f32x4 a  = *(const f32x4*)(p + lane * 4);
    f32x4 b2 = *(const f32x4*)(p + 256 + lane * 4);
    float s  = a[0] + a[1] + a[2] + a[3] + b2[0] + b2[1] + b2[2] + b2[3];
    float s2 = a[0]*a[0] + a[1]*a[1] + a[2]*a[2] + a[3]*a[3]
             + b2[0]*b2[0] + b2[1]*b2[1] + b2[2]*b2[2] + b2[3]*b2[3];
    #pragma unroll
    for (int off = 32; off; off >>= 1) {
        s  += __shfl_xor(s,  off, 64);
        s2 += __shfl_xor(s2, off, 64);
    }
    const float mean = s * (1.f / 512.f);
    const float var  = s2 * (1.f / 512.f) - mean * mean;
    const float rstd = rsqrtf(var + 1e-5f);

    f32x4 g0 = *(const f32x4*)(g + lane * 4);
    f32x4 g1 = *(const f32x4*)(g + 256 + lane * 4);
    f32x4 e0 = *(const f32x4*)(be + lane * 4);
    f32x4 e1 = *(const f32x4*)(be + 256 + lane * 4);
    f32x4 o0, o1;
    #pragma unroll
    for (int u = 0; u < 4; u++) {
        o0[u] = (a[u]  - mean) * rstd * g0[u] + e0[u];
        o1[u] = (b2[u] - mean) * rstd * g1[u] + e1[u];
    }
    if (OUTF) {
        float* of = outf + (size_t)row * D_;
        *(f32x4*)(of + lane * 4)       = o0;
        *(f32x4*)(of + 256 + lane * 4) = o1;
    }
    if (OUTB) {
        bf16x4 c0, c1;
        #pragma unroll
        for (int u = 0; u < 4; u++) { c0[u] = (bf16)o0[u]; c1[u] = (bf16)o1[u]; }
        bf16* ob = outb + (size_t)row * D_;
        *(bf16x4*)(ob + lane * 4)       = c0;
        *(bf16x4*)(ob + 256 + lane * 4) = c1;
    }
}

// ---------------- host launcher ----------------
extern "C" void kernel_launch(void* const* d_in, const int* in_sizes, int n_in,
                              void* d_out, int out_size, void* d_ws, size_t ws_size,
                              hipStream_t stream)
{
    const float* x      = (const float*)d_in[0];
    const float* w_in   = (const float*)d_in[1];
    const float* b_in   = (const float*)d_in[2];
    const float* w_qkv  = (const float*)d_in[3];
    const float* b_qkv  = (const float*)d_in[4];
    const float* w_out  = (const float*)d_in[5];
    const float* b_out  = (const float*)d_in[6];
    const float* w_ffn1 = (const float*)d_in[7];
    const float* b_ffn1 = (const float*)d_in[8];
    const float* w_ffn2 = (const float*)d_in[9];
    const float* b_ffn2 = (const float*)d_in[10];
    const float* g1     = (const float*)d_in[11];
    const float* bn1    = (const float*)d_in[12];
    const float* g2     = (const float*)d_in[13];
    const float* bn2    = (const float*)d_in[14];

    char* ws = (char*)d_ws;
    constexpr size_t OFF_XB   = 0;
    constexpr size_t OFF_WIN  = OFF_XB   + 41943040ull;
    constexpr size_t OFF_WQKV = OFF_WIN  + 1310720ull;
    constexpr size_t OFF_WOUT = OFF_WQKV + 1572864ull;
    constexpr size_t OFF_WF1  = OFF_WOUT + 524288ull;
    constexpr size_t OFF_WF2  = OFF_WF1  + 2097152ull;
    constexpr size_t OFF_CS   = OFF_WF2  + 2097152ull;
    constexpr size_t OFF_HB   = OFF_CS   + 33554432ull;
    constexpr size_t OFF_QKV  = OFF_HB   + 16777216ull;
    constexpr size_t OFF_OB   = OFF_QKV  + 50331648ull;
    constexpr size_t OFF_VT   = OFF_OB   + 16777216ull;
    constexpr size_t OFF_H2B  = OFF_VT   + 33554432ull;
    constexpr size_t OFF_F1   = OFF_H2B  + 16777216ull;
    constexpr size_t OFF_T1   = OFF_XB;
    constexpr size_t OFF_T2   = OFF_QKV;

    bf16*  x_b    = (bf16*)(ws + OFF_XB);
    bf16*  win_t  = (bf16*)(ws + OFF_WIN);
    bf16*  wqkv_t = (bf16*)(ws + OFF_WQKV);
    bf16*  wout_t = (bf16*)(ws + OFF_WOUT);
    bf16*  wf1_t  = (bf16*)(ws + OFF_WF1);
    bf16*  wf2_t  = (bf16*)(ws + OFF_WF2);
    float* cs_t   = (float*)(ws + OFF_CS);
    bf16*  h_b    = (bf16*)(ws + OFF_HB);
    bf16*  qkv_b  = (bf16*)(ws + OFF_QKV);
    bf16*  o_b    = (bf16*)(ws + OFF_OB);
    bf16*  vt_g   = (bf16*)(ws + OFF_VT);
    bf16*  h2_b   = (bf16*)(ws + OFF_H2B);
    bf16*  f1_b   = (bf16*)(ws + OFF_F1);
    float* t1_f   = (float*)(ws + OFF_T1);
    float* t2_f   = (float*)(ws + OFF_T2);

    {
        int n4 = NROW * CIN / 4;
        cvt_kernel<<<(n4 + 255) / 256, 256, 0, stream>>>(x, x_b, n4);
    }
    tr_cvt_kernel<<<dim3(512/32, 1280/32), 256, 0, stream>>>(w_in,   win_t,  1280, 512);
    tr_cvt_kernel<<<dim3(1536/32, 512/32), 256, 0, stream>>>(w_qkv,  wqkv_t, 512, 1536);
    tr_cvt_kernel<<<dim3(512/32,  512/32), 256, 0, stream>>>(w_out,  wout_t, 512, 512);
    tr_cvt_kernel<<<dim3(2048/32, 512/32), 256, 0, stream>>>(w_ffn1, wf1_t,  512, 2048);
    tr_cvt_kernel<<<dim3(512/32, 2048/32), 256, 0, stream>>>(w_ffn2, wf2_t,  2048, 512);
    cs_kernel<<<128, 256, 0, stream>>>(cs_t);

    // G1: h = x @ w_in + b_in -> bf16            (512 blocks, 2/CU)
    gemm128_kernel<0,false,false,false,true><<<(NROW/128) * (D_/128), 256, 0, stream>>>(
        x_b, win_t, b_in, nullptr, nullptr, h_b, nullptr, nullptr, NROW, D_, CIN);
    // G2: qkv = h @ w_qkv + b_qkv; fused RoPE(q,k)->qkv_b, v->vt_g (1536 blocks)
    gemm128_kernel<1,false,false,false,true><<<(NROW/128) * (3*D_/128), 256, 0, stream>>>(
        h_b, wqkv_t, b_qkv, nullptr, nullptr, qkv_b, cs_t, vt_g, NROW, 3*D_, D_);
    // attention -> o bf16
    attn_kernel<<<dim3(B_*H_, S_/128), 512, 0, stream>>>(qkv_b, vt_g, o_b);
    // G3: t1 = o @ w_out + b_out + h(bf16) -> f32   (512 blocks)
    gemm128_kernel<0,false,true,true,false><<<(NROW/128) * (D_/128), 256, 0, stream>>>(
        o_b, wout_t, b_out, h_b, t1_f, nullptr, nullptr, nullptr, NROW, D_, D_);
    // LN1 -> h2 bf16
    ln_kernel<false,true><<<NROW/4, 256, 0, stream>>>(t1_f, g1, bn1, nullptr, h2_b);
    // G4: f1 = relu(h2 @ w_ffn1 + b_ffn1) -> bf16   (2048 blocks)
    gemm128_kernel<0,true,false,false,true><<<(NROW/128) * (4*D_/128), 256, 0, stream>>>(
        h2_b, wf1_t, b_ffn1, nullptr, nullptr, f1_b, nullptr, nullptr, NROW, 4*D_, D_);
    // G5: t2 = f1 @ w_ffn2 + b_ffn2 + h2(bf16) -> f32   (512 blocks, K=2048)
    gemm128_kernel<0,false,true,true,false><<<(NROW/128) * (D_/128), 256, 0, stream>>>(
        f1_b, wf2_t, b_ffn2, h2_b, t2_f, nullptr, nullptr, nullptr, NROW, D_, 4*D_);
    // LN2 -> d_out (f32)
    ln_kernel<true,false><<<NROW/4, 256, 0, stream>>>(t2_f, g2, bn2, (float*)d_out, nullptr);

    (void)in_sizes; (void)n_in; (void)out_size; (void)ws_size;
}

// Round 8
// 265.079 us; speedup vs baseline: 6.7529x; 1.0399x over previous
//
#include <hip/hip_runtime.h>
#include <hip/hip_bf16.h>
#include <math.h>

// ---------------- problem constants ----------------
#define B_   16
#define S_   1024
#define CIN  1280
#define D_   512
#define H_   8
#define HD_  64
#define NROW (B_ * S_)        // 16384

typedef __bf16 bf16;
typedef float  f32x2  __attribute__((ext_vector_type(2)));
typedef float  f32x4  __attribute__((ext_vector_type(4)));
typedef bf16   bf16x4 __attribute__((ext_vector_type(4)));
typedef bf16   bf16x8 __attribute__((ext_vector_type(8)));

__device__ __forceinline__ void gload_lds16(const bf16* g, bf16* l) {
    __builtin_amdgcn_global_load_lds(
        (const __attribute__((address_space(1))) void*)g,
        (__attribute__((address_space(3))) void*)l, 16, 0, 0);
}

#define SBAR()   __builtin_amdgcn_s_barrier()
#define SCHED0() __builtin_amdgcn_sched_barrier(0)
#define VMCNT8() asm volatile("s_waitcnt vmcnt(8)" ::: "memory")
#define VMCNT2() asm volatile("s_waitcnt vmcnt(2)" ::: "memory")
#define VMCNT0() asm volatile("s_waitcnt vmcnt(0)" ::: "memory")

// ---------------- merged preamble: cvt(x) + 5 weight transposes + cs table ----
// One launch instead of 7. Block ranges: [0,20480) cvt; then tr tiles; then cs.
__device__ __forceinline__ void tr_tile(const float* __restrict__ in,
                                        bf16* __restrict__ out,
                                        int R, int C, int cx, int ry, int t)
{
    __shared__ float T[32][33];
    const int r0 = ry << 5, c0 = cx << 5;
    {
        int lr = t >> 3, lc = (t & 7) << 2;
        f32x4 v = *(const f32x4*)(in + (size_t)(r0 + lr) * C + c0 + lc);
        T[lr][lc] = v[0]; T[lr][lc + 1] = v[1]; T[lr][lc + 2] = v[2]; T[lr][lc + 3] = v[3];
    }
    __syncthreads();
    {
        int oc = t >> 3, orr = (t & 7) << 2;
        bf16x4 o;
        o[0] = (bf16)T[orr][oc];     o[1] = (bf16)T[orr + 1][oc];
        o[2] = (bf16)T[orr + 2][oc]; o[3] = (bf16)T[orr + 3][oc];
        *(bf16x4*)(out + (size_t)(c0 + oc) * R + r0 + orr) = o;
    }
}

#define NCVT (NROW * CIN / 4 / 256)   // 20480 blocks for x cvt

__global__ __launch_bounds__(256)
void prep_kernel(const float* __restrict__ x, bf16* __restrict__ x_b,
                 const float* __restrict__ w_in,   bf16* __restrict__ win_t,
                 const float* __restrict__ w_qkv,  bf16* __restrict__ wqkv_t,
                 const float* __restrict__ w_out,  bf16* __restrict__ wout_t,
                 const float* __restrict__ w_ffn1, bf16* __restrict__ wf1_t,
                 const float* __restrict__ w_ffn2, bf16* __restrict__ wf2_t,
                 float* __restrict__ cs)
{
    const int t   = threadIdx.x;
    int bid = blockIdx.x;
    if (bid < NCVT) {
        int i = bid * 256 + t;
        f32x4 v = *(const f32x4*)(x + (size_t)i * 4);
        bf16x4 o;
        o[0] = (bf16)v[0]; o[1] = (bf16)v[1]; o[2] = (bf16)v[2]; o[3] = (bf16)v[3];
        *(bf16x4*)(x_b + (size_t)i * 4) = o;
        return;
    }
    bid -= NCVT;
    if (bid < 640)  { tr_tile(w_in,   win_t,  1280, 512,  bid % 16, bid / 16, t); return; }
    bid -= 640;
    if (bid < 768)  { tr_tile(w_qkv,  wqkv_t, 512,  1536, bid % 48, bid / 48, t); return; }
    bid -= 768;
    if (bid < 256)  { tr_tile(w_out,  wout_t, 512,  512,  bid % 16, bid / 16, t); return; }
    bid -= 256;
    if (bid < 1024) { tr_tile(w_ffn1, wf1_t,  512,  2048, bid % 64, bid / 64, t); return; }
    bid -= 1024;
    if (bid < 1024) { tr_tile(w_ffn2, wf2_t,  2048, 512,  bid % 16, bid / 16, t); return; }
    bid -= 1024;
    {   // cs table: 128 blocks
        int idx = bid * 256 + t;              // 0..32767
        int s = idx >> 5, i = idx & 31;
        float freq = exp2f(-(float)i * (13.287712379549449f / 32.f));
        float sn, c;
        sincosf((float)s * freq, &sn, &c);
        cs[(size_t)idx * 2]     = c;
        cs[(size_t)idx * 2 + 1] = sn;
    }
}
#define NPREP (NCVT + 640 + 768 + 256 + 1024 + 1024 + 128)

// ---------------- 128x128 BK=64 double-buffered GEMM (ALL five GEMMs) ----------------
#define ASZ1 (128 * 64)

template<int EPI, bool RELU, bool RES, bool OUTF, bool OUTB>
__global__ __launch_bounds__(256, 2)
void gemm128_kernel(const bf16* __restrict__ A, const bf16* __restrict__ Wt,
                    const float* __restrict__ bias, const bf16* __restrict__ res,
                    float* __restrict__ outf, bf16* __restrict__ outb,
                    const float* __restrict__ cs, bf16* __restrict__ vt,
                    int M, int N, int K)
{
    __shared__ bf16 lds[4 * ASZ1];   // A dbuf (2) + B dbuf (2), 64 KiB

    const int tid  = threadIdx.x;
    const int lane = tid & 63;
    const int wid  = tid >> 6;

    const int perX = (M >> 7) >> 3;            // 16
    const int lin  = blockIdx.x;
    const int idx  = lin >> 3;
    const int my   = (lin & 7) * perX + (idx & (perX - 1));
    const int nx   = idx / perX;
    const int m0   = my << 7, n0 = nx << 7;

    const int sRow = lane >> 3;
    const int sK   = ((lane & 7) ^ sRow) << 3;

    const int r2  = wid >> 1;
    const int c2  = wid & 1;
    const int cc  = lane & 15;
    const int g   = (lane >> 4) & 3;
    const int swz = (cc & 7) << 4;

    f32x4 acc[4][4] = {};

    auto stage = [&](int t, int b) {
        const bf16* gA = A  + (size_t)m0 * K + t * 64;
        const bf16* gB = Wt + (size_t)n0 * K + t * 64;
        bf16* lA = lds + b * ASZ1;
        bf16* lB = lds + 2 * ASZ1 + b * ASZ1;
        #pragma unroll
        for (int v = 0; v < 4; ++v) {
            const int ch = v * 4 + wid;
            gload_lds16(gA + (size_t)(ch * 8 + sRow) * K + sK, lA + ch * 512);
            gload_lds16(gB + (size_t)(ch * 8 + sRow) * K + sK, lB + ch * 512);
        }
    };

    const int T = K >> 6;
    stage(0, 0);
    stage(1, 1);
    VMCNT8();
    SCHED0();
    SBAR();

    for (int t = 0; t < T; ++t) {
        const int b = t & 1;
        const char* lA = (const char*)(lds + b * ASZ1);
        const char* lB = (const char*)(lds + 2 * ASZ1 + b * ASZ1);

        #pragma unroll
        for (int ks = 0; ks < 2; ++ks) {
            bf16x8 af[4], bfr[4];
            #pragma unroll
            for (int i = 0; i < 4; ++i) {
                const int row = r2 * 64 + i * 16 + cc;
                af[i] = *(const bf16x8*)(lA + row * 128 + ((ks * 64 + g * 16) ^ swz));
            }
            #pragma unroll
            for (int j = 0; j < 4; ++j) {
                const int row = c2 * 64 + j * 16 + cc;
                bfr[j] = *(const bf16x8*)(lB + row * 128 + ((ks * 64 + g * 16) ^ swz));
            }
            __builtin_amdgcn_s_setprio(1);
            #pragma unroll
            for (int i = 0; i < 4; ++i)
                #pragma unroll
                for (int j = 0; j < 4; ++j)
                    acc[i][j] = __builtin_amdgcn_mfma_f32_16x16x32_bf16(af[i], bfr[j], acc[i][j], 0, 0, 0);
            __builtin_amdgcn_s_setprio(0);
        }
        SCHED0();
        SBAR();
        if (t + 2 < T) {
            stage(t + 2, b);
            VMCNT8();
        } else if (t + 1 < T) {
            VMCNT0();
        }
        if (t + 1 < T) { SCHED0(); SBAR(); }
    }

    const int rq = g << 2;
    if constexpr (EPI == 1) {
        const int colb = c2 * 64;
        if (nx < 8) {
            float bj[4];
            #pragma unroll
            for (int j = 0; j < 4; ++j) bj[j] = bias[n0 + colb + j * 16 + cc];
            #pragma unroll
            for (int i = 0; i < 4; ++i) {
                #pragma unroll
                for (int r = 0; r < 4; ++r) {
                    const int gm = m0 + r2 * 64 + i * 16 + rq + r;
                    const int s  = gm & (S_ - 1);
                    #pragma unroll
                    for (int jp = 0; jp < 2; ++jp) {
                        const int d = jp * 16 + cc;
                        f32x2 csv = *(const f32x2*)(cs + ((size_t)s * 32 + d) * 2);
                        float x1 = acc[i][jp][r]     + bj[jp];
                        float x2 = acc[i][jp + 2][r] + bj[jp + 2];
                        const size_t o1 = (size_t)gm * N + n0 + colb + d;
                        outb[o1]      = (bf16)(x1 * csv[0] - x2 * csv[1]);
                        outb[o1 + 32] = (bf16)(x1 * csv[1] + x2 * csv[0]);
                    }
                }
            }
        } else {
            const int col0 = n0 + colb;
            const int hw = (col0 >> 6) & 7;
            const int bb = m0 >> 10;
            bf16* vbase = vt + (size_t)(bb * 8 + hw) * (HD_ * S_);
            const int sb0 = (m0 & (S_ - 1)) + r2 * 64 + rq;
            #pragma unroll
            for (int i = 0; i < 4; ++i) {
                #pragma unroll
                for (int j = 0; j < 4; ++j) {
                    const int d = j * 16 + cc;
                    const float bv = bias[col0 + d];
                    bf16x4 pk;
                    #pragma unroll
                    for (int r = 0; r < 4; ++r) pk[r] = (bf16)(acc[i][j][r] + bv);
                    *(bf16x4*)(vbase + (size_t)d * S_ + sb0 + i * 16) = pk;
                }
            }
        }
    } else {
        #pragma unroll
        for (int i = 0; i < 4; ++i) {
            #pragma unroll
            for (int j = 0; j < 4; ++j) {
                const int gn = n0 + c2 * 64 + j * 16 + cc;
                const float bv = bias[gn];
                #pragma unroll
                for (int r = 0; r < 4; ++r) {
                    const int gm = m0 + r2 * 64 + i * 16 + rq + r;
                    float v = acc[i][j][r] + bv;
                    if (RES)  v += (float)res[(size_t)gm * N + gn];
                    if (RELU) v = fmaxf(v, 0.f);
                    if (OUTF) outf[(size_t)gm * N + gn] = v;
                    if (OUTB) outb[(size_t)gm * N + gn] = (bf16)v;
                }
            }
        }
    }
    (void)cs; (void)vt;
}

// ---------------- MFMA flash attention v5: 8 waves x 2 q-sets (32 q/wave) ----
// K/V frags loaded once per wave, reused across both q-sets -> LDS bytes/FLOP
// halve. QBLK=256, grid 128x4 = 512 blocks = exactly 2 resident/CU (LDS 70KB).
// l via ones-column MFMA; defer-max THR=8 lg2; fma-folded exp2.
#define PST 72

__global__ __launch_bounds__(512)
void attn_kernel(const bf16* __restrict__ qkv, const bf16* __restrict__ vtg,
                 bf16* __restrict__ o)
{
    __shared__ bf16 Ks[2][4096];
    __shared__ bf16 Vs[2][4096];
    __shared__ bf16 Ps[16][16 * PST];      // [wave*2 + set]

    const int bh  = blockIdx.x;
    const int b   = bh >> 3;
    const int h   = bh & 7;
    const int q0  = blockIdx.y << 8;       // QBLK = 256
    const int tid = threadIdx.x;
    const int lane = tid & 63;
    const int w    = tid >> 6;
    const int c    = lane & 15;
    const int g    = lane >> 4;
    const int swz  = (c & 7) << 4;

    const size_t rs = 3 * D_;
    const bf16* qb = qkv + (size_t)b * S_ * rs + h * HD_;
    const bf16* kb = qb + D_;
    const bf16* vt = vtg + (size_t)bh * HD_ * S_;

    const int sRow = tid >> 3;
    const int sOff = ((tid & 7) ^ (sRow & 7)) << 3;

    bf16x8 qf[2][2];                       // [set][ch]
    #pragma unroll
    for (int s = 0; s < 2; ++s) {
        const bf16* qrow = qb + (size_t)(q0 + s * 128 + w * 16 + c) * rs + g * 8;
        qf[s][0] = *(const bf16x8*)(qrow);
        qf[s][1] = *(const bf16x8*)(qrow + 32);
    }
    SCHED0();

    bf16x8 vones;
    {
        bf16 one = (bf16)(c == 0 ? 1.f : 0.f);
        #pragma unroll
        for (int u = 0; u < 8; ++u) vones[u] = one;
    }

    auto stage = [&](int t, int buf) {
        gload_lds16(kb + (size_t)(t * 64 + sRow) * rs + sOff, &Ks[buf][0] + (size_t)tid * 8);
        gload_lds16(vt + (size_t)sRow * S_ + t * 64 + sOff,   &Vs[buf][0] + (size_t)tid * 8);
    };

    f32x4 oa[2][4] = {};
    f32x4 oa5[2] = {};
    float m_r[2] = {-3.0e38f, -3.0e38f};
    const float CE  = 0.18033688011112042f;  // (1/8)*log2(e)
    const float THR = 44.3614195558365f;     // 8 / CE

    stage(0, 0);
    stage(1, 1);
    VMCNT2();
    SCHED0();
    SBAR();

    for (int t = 0; t < 16; ++t) {
        const int buf = t & 1;
        const char* kB = (const char*)Ks[buf];
        const char* vB = (const char*)Vs[buf];

        // QK^T both sets: each kf feeds 2 MFMAs
        f32x4 sa[2][4] = {};
        __builtin_amdgcn_s_setprio(1);
        #pragma unroll
        for (int ch = 0; ch < 2; ++ch)
            #pragma unroll
            for (int ks = 0; ks < 4; ++ks) {
                bf16x8 kf = *(const bf16x8*)(kB + (ks * 16 + c) * 128 + ((ch * 64 + g * 16) ^ swz));
                sa[0][ks] = __builtin_amdgcn_mfma_f32_16x16x32_bf16(kf, qf[0][ch], sa[0][ks], 0, 0, 0);
                sa[1][ks] = __builtin_amdgcn_mfma_f32_16x16x32_bf16(kf, qf[1][ch], sa[1][ks], 0, 0, 0);
            }
        __builtin_amdgcn_s_setprio(0);

        // softmax per set
        #pragma unroll
        for (int s = 0; s < 2; ++s) {
            float pmax = -3.0e38f;
            #pragma unroll
            for (int ks = 0; ks < 4; ++ks)
                pmax = fmaxf(pmax, fmaxf(fmaxf(sa[s][ks][0], sa[s][ks][1]),
                                         fmaxf(sa[s][ks][2], sa[s][ks][3])));
            pmax = fmaxf(pmax, __shfl_xor(pmax, 16, 64));
            pmax = fmaxf(pmax, __shfl_xor(pmax, 32, 64));

            if (!__all(pmax - m_r[s] <= THR)) {
                float mnew = fmaxf(m_r[s], pmax);
                float sc = __builtin_amdgcn_exp2f((m_r[s] - mnew) * CE);
                #pragma unroll
                for (int r = 0; r < 4; ++r) {
                    float scr = __shfl(sc, g * 4 + r, 64);
                    #pragma unroll
                    for (int j = 0; j < 4; ++j) oa[s][j][r] *= scr;
                    oa5[s][r] *= scr;
                }
                m_r[s] = mnew;
            }

            const float nmCE = -m_r[s] * CE;
            #pragma unroll
            for (int ks = 0; ks < 4; ++ks) {
                bf16x4 pb;
                #pragma unroll
                for (int r = 0; r < 4; ++r)
                    pb[r] = (bf16)__builtin_amdgcn_exp2f(__builtin_fmaf(sa[s][ks][r], CE, nmCE));
                *(bf16x4*)&Ps[w * 2 + s][c * PST + ks * 16 + g * 4] = pb;
            }
        }

        // PV both sets: each vf feeds 2 MFMAs
        __builtin_amdgcn_s_setprio(1);
        #pragma unroll
        for (int ch = 0; ch < 2; ++ch) {
            bf16x8 pa0 = *(const bf16x8*)&Ps[w * 2 + 0][c * PST + ch * 32 + g * 8];
            bf16x8 pa1 = *(const bf16x8*)&Ps[w * 2 + 1][c * PST + ch * 32 + g * 8];
            #pragma unroll
            for (int j = 0; j < 4; ++j) {
                bf16x8 vf = *(const bf16x8*)(vB + (j * 16 + c) * 128 + ((ch * 64 + g * 16) ^ swz));
                oa[0][j] = __builtin_amdgcn_mfma_f32_16x16x32_bf16(pa0, vf, oa[0][j], 0, 0, 0);
                oa[1][j] = __builtin_amdgcn_mfma_f32_16x16x32_bf16(pa1, vf, oa[1][j], 0, 0, 0);
            }
            oa5[0] = __builtin_amdgcn_mfma_f32_16x16x32_bf16(pa0, vones, oa5[0], 0, 0, 0);
            oa5[1] = __builtin_amdgcn_mfma_f32_16x16x32_bf16(pa1, vones, oa5[1], 0, 0, 0);
        }
        __builtin_amdgcn_s_setprio(0);

        SCHED0();
        SBAR();
        if (t + 2 < 16) {
            stage(t + 2, buf);
            VMCNT2();
        } else if (t + 1 < 16) {
            VMCNT0();
        }
        if (t + 1 < 16) { SCHED0(); SBAR(); }
    }

    #pragma unroll
    for (int s = 0; s < 2; ++s) {
        float linv[4];
        #pragma unroll
        for (int r = 0; r < 4; ++r)
            linv[r] = 1.f / __shfl(oa5[s][r], lane & 48, 64);
        #pragma unroll
        for (int j = 0; j < 4; ++j)
            #pragma unroll
            for (int r = 0; r < 4; ++r) {
                int q = q0 + s * 128 + w * 16 + g * 4 + r;
                o[((size_t)(b * S_) + q) * D_ + h * HD_ + j * 16 + c] = (bf16)(oa[s][j][r] * linv[r]);
            }
    }
}

// ---------------- LayerNorm over D=512, one wave per row ----------------
template<bool OUTF, bool OUTB>
__global__ __launch_bounds__(256)
void ln_kernel(const float* __restrict__ in, const float* __restrict__ g,
               const float* __restrict__ be, float* __restrict__ outf,
               bf16* __restrict__ outb)
{
    const int row  = (blockIdx.x << 2) + (threadIdx.x >> 6);
    const int lane = threadIdx.x & 63;
    const float* p = in + (size_t)row * D_;
    f32x4 a  = *(const f32x4*)(p + lane * 4);
    f32x4 b2 = *(const f32x4*)(p + 256 + lane * 4);
    float s  = a[0] + a[1] + a[2] + a[3] + b2[0] + b2[1] + b2[2] + b2[3];
    float s2 = a[0]*a[0] + a[1]*a[1] + a[2]*a[2] + a[3]*a[3]
             + b2[0]*b2[0] + b2[1]*b2[1] + b2[2]*b2[2] + b2[3]*b2[3];
    #pragma unroll
    for (int off = 32; off; off >>= 1) {
        s  += __shfl_xor(s,  off, 64);
        s2 += __shfl_xor(s2, off, 64);
    }
    const float mean = s * (1.f / 512.f);
    const float var  = s2 * (1.f / 512.f) - mean * mean;
    const float rstd = rsqrtf(var + 1e-5f);

    f32x4 g0 = *(const f32x4*)(g + lane * 4);
    f32x4 g1 = *(const f32x4*)(g + 256 + lane * 4);
    f32x4 e0 = *(const f32x4*)(be + lane * 4);
    f32x4 e1 = *(const f32x4*)(be + 256 + lane * 4);
    f32x4 o0, o1;
    #pragma unroll
    for (int u = 0; u < 4; u++) {
        o0[u] = (a[u]  - mean) * rstd * g0[u] + e0[u];
        o1[u] = (b2[u] - mean) * rstd * g1[u] + e1[u];
    }
    if (OUTF) {
        float* of = outf + (size_t)row * D_;
        *(f32x4*)(of + lane * 4)       = o0;
        *(f32x4*)(of + 256 + lane * 4) = o1;
    }
    if (OUTB) {
        bf16x4 c0, c1;
        #pragma unroll
        for (int u = 0; u < 4; u++) { c0[u] = (bf16)o0[u]; c1[u] = (bf16)o1[u]; }
        bf16* ob = outb + (size_t)row * D_;
        *(bf16x4*)(ob + lane * 4)       = c0;
        *(bf16x4*)(ob + 256 + lane * 4) = c1;
    }
}

// ---------------- host launcher ----------------
extern "C" void kernel_launch(void* const* d_in, const int* in_sizes, int n_in,
                              void* d_out, int out_size, void* d_ws, size_t ws_size,
                              hipStream_t stream)
{
    const float* x      = (const float*)d_in[0];
    const float* w_in   = (const float*)d_in[1];
    const float* b_in   = (const float*)d_in[2];
    const float* w_qkv  = (const float*)d_in[3];
    const float* b_qkv  = (const float*)d_in[4];
    const float* w_out  = (const float*)d_in[5];
    const float* b_out  = (const float*)d_in[6];
    const float* w_ffn1 = (const float*)d_in[7];
    const float* b_ffn1 = (const float*)d_in[8];
    const float* w_ffn2 = (const float*)d_in[9];
    const float* b_ffn2 = (const float*)d_in[10];
    const float* g1     = (const float*)d_in[11];
    const float* bn1    = (const float*)d_in[12];
    const float* g2     = (const float*)d_in[13];
    const float* bn2    = (const float*)d_in[14];

    char* ws = (char*)d_ws;
    constexpr size_t OFF_XB   = 0;
    constexpr size_t OFF_WIN  = OFF_XB   + 41943040ull;
    constexpr size_t OFF_WQKV = OFF_WIN  + 1310720ull;
    constexpr size_t OFF_WOUT = OFF_WQKV + 1572864ull;
    constexpr size_t OFF_WF1  = OFF_WOUT + 524288ull;
    constexpr size_t OFF_WF2  = OFF_WF1  + 2097152ull;
    constexpr size_t OFF_CS   = OFF_WF2  + 2097152ull;
    constexpr size_t OFF_HB   = OFF_CS   + 33554432ull;
    constexpr size_t OFF_QKV  = OFF_HB   + 16777216ull;
    constexpr size_t OFF_OB   = OFF_QKV  + 50331648ull;
    constexpr size_t OFF_VT   = OFF_OB   + 16777216ull;
    constexpr size_t OFF_H2B  = OFF_VT   + 33554432ull;
    constexpr size_t OFF_F1   = OFF_H2B  + 16777216ull;
    constexpr size_t OFF_T1   = OFF_XB;
    constexpr size_t OFF_T2   = OFF_QKV;

    bf16*  x_b    = (bf16*)(ws + OFF_XB);
    bf16*  win_t  = (bf16*)(ws + OFF_WIN);
    bf16*  wqkv_t = (bf16*)(ws + OFF_WQKV);
    bf16*  wout_t = (bf16*)(ws + OFF_WOUT);
    bf16*  wf1_t  = (bf16*)(ws + OFF_WF1);
    bf16*  wf2_t  = (bf16*)(ws + OFF_WF2);
    float* cs_t   = (float*)(ws + OFF_CS);
    bf16*  h_b    = (bf16*)(ws + OFF_HB);
    bf16*  qkv_b  = (bf16*)(ws + OFF_QKV);
    bf16*  o_b    = (bf16*)(ws + OFF_OB);
    bf16*  vt_g   = (bf16*)(ws + OFF_VT);
    bf16*  h2_b   = (bf16*)(ws + OFF_H2B);
    bf16*  f1_b   = (bf16*)(ws + OFF_F1);
    float* t1_f   = (float*)(ws + OFF_T1);
    float* t2_f   = (float*)(ws + OFF_T2);

    // merged preamble (1 launch)
    prep_kernel<<<NPREP, 256, 0, stream>>>(x, x_b, w_in, win_t, w_qkv, wqkv_t,
                                           w_out, wout_t, w_ffn1, wf1_t,
                                           w_ffn2, wf2_t, cs_t);

    // G1: h = x @ w_in + b_in -> bf16
    gemm128_kernel<0,false,false,false,true><<<(NROW/128) * (D_/128), 256, 0, stream>>>(
        x_b, win_t, b_in, nullptr, nullptr, h_b, nullptr, nullptr, NROW, D_, CIN);
    // G2: qkv = h @ w_qkv + b_qkv; fused RoPE(q,k)->qkv_b, v->vt_g
    gemm128_kernel<1,false,false,false,true><<<(NROW/128) * (3*D_/128), 256, 0, stream>>>(
        h_b, wqkv_t, b_qkv, nullptr, nullptr, qkv_b, cs_t, vt_g, NROW, 3*D_, D_);
    // attention -> o bf16   (QBLK=256, 512 blocks = 2/CU resident)
    attn_kernel<<<dim3(B_*H_, S_/256), 512, 0, stream>>>(qkv_b, vt_g, o_b);
    // G3: t1 = o @ w_out + b_out + h(bf16) -> f32
    gemm128_kernel<0,false,true,true,false><<<(NROW/128) * (D_/128), 256, 0, stream>>>(
        o_b, wout_t, b_out, h_b, t1_f, nullptr, nullptr, nullptr, NROW, D_, D_);
    // LN1 -> h2 bf16
    ln_kernel<false,true><<<NROW/4, 256, 0, stream>>>(t1_f, g1, bn1, nullptr, h2_b);
    // G4: f1 = relu(h2 @ w_ffn1 + b_ffn1) -> bf16
    gemm128_kernel<0,true,false,false,true><<<(NROW/128) * (4*D_/128), 256, 0, stream>>>(
        h2_b, wf1_t, b_ffn1, nullptr, nullptr, f1_b, nullptr, nullptr, NROW, 4*D_, D_);
    // G5: t2 = f1 @ w_ffn2 + b_ffn2 + h2(bf16) -> f32
    gemm128_kernel<0,false,true,true,false><<<(NROW/128) * (D_/128), 256, 0, stream>>>(
        f1_b, wf2_t, b_ffn2, h2_b, t2_f, nullptr, nullptr, nullptr, NROW, D_, 4*D_);
    // LN2 -> d_out (f32)
    ln_kernel<true,false><<<NROW/4, 256, 0, stream>>>(t2_f, g2, bn2, (float*)d_out, nullptr);

    (void)in_sizes; (void)n_in; (void)out_size; (void)ws_size;
}